// Round 3
// baseline (2662.382 us; speedup 1.0000x reference)
//
#include <hip/hip_runtime.h>
#include <hip/hip_bf16.h>
#include <stdint.h>

#define NN 50000
#define NE 1600000
#define NG 64
#define FIN 256
#define HD 1024
#define EPSV 1e-5f

typedef __bf16 bf16;
typedef __bf16 bf16x4 __attribute__((ext_vector_type(4)));
typedef __bf16 bf16x8 __attribute__((ext_vector_type(8)));
typedef float f32x4 __attribute__((ext_vector_type(4)));
typedef uint32_t u32x4 __attribute__((ext_vector_type(4)));

typedef const __attribute__((address_space(1))) void* gptr_as1;
typedef __attribute__((address_space(3))) void* lptr_as3;

__device__ __forceinline__ void load_g2l_16(const void* g, const void* l) {
  __builtin_amdgcn_global_load_lds((gptr_as1)(uintptr_t)g,
                                   (lptr_as3)(uint32_t)(uintptr_t)l, 16, 0, 0);
}

// ---------------- degree histogram / dinv ----------------
__global__ void hist_kernel(const int* __restrict__ col, int* __restrict__ cnt, int E) {
  int e = blockIdx.x * 256 + threadIdx.x;
  if (e < E) atomicAdd(&cnt[col[e]], 1);
}

__global__ void dinv_kernel(const int* __restrict__ cnt, float* __restrict__ dinv, int n) {
  int i = blockIdx.x * 256 + threadIdx.x;
  if (i < n) dinv[i] = rsqrtf((float)(cnt[i] + 1));  // +1 self-loop
}

// ---------------- exclusive scan (3-phase) ----------------
__global__ void scan_partial_kernel(const int* __restrict__ cnt, int* __restrict__ partial, int n) {
  __shared__ int red[4];
  int i = blockIdx.x * 256 + threadIdx.x;
  int v = (i < n) ? cnt[i] : 0;
  #pragma unroll
  for (int off = 32; off; off >>= 1) v += __shfl_down(v, off, 64);
  if ((threadIdx.x & 63) == 0) red[threadIdx.x >> 6] = v;
  __syncthreads();
  if (threadIdx.x == 0) partial[blockIdx.x] = red[0] + red[1] + red[2] + red[3];
}

__global__ void scan_scan_kernel(int* __restrict__ partial, int nb) {
  __shared__ int s[256];
  int t = threadIdx.x;
  int v = (t < nb) ? partial[t] : 0;
  s[t] = v;
  __syncthreads();
  for (int off = 1; off < 256; off <<= 1) {
    int x = (t >= off) ? s[t - off] : 0;
    __syncthreads();
    s[t] += x;
    __syncthreads();
  }
  if (t < nb) partial[t] = s[t] - v;  // exclusive
}

__global__ void scan_final_kernel(const int* __restrict__ cnt, const int* __restrict__ partial,
                                  int* __restrict__ row_ptr, int n, int E) {
  __shared__ int s[256];
  int t = threadIdx.x;
  int i = blockIdx.x * 256 + t;
  int v = (i < n) ? cnt[i] : 0;
  s[t] = v;
  __syncthreads();
  for (int off = 1; off < 256; off <<= 1) {
    int x = (t >= off) ? s[t - off] : 0;
    __syncthreads();
    s[t] += x;
    __syncthreads();
  }
  if (i < n) row_ptr[i] = partial[blockIdx.x] + s[t] - v;
  if (i == 0) row_ptr[n] = E;
}

// ---------------- CSR scatter ----------------
__global__ void scatter_kernel(const int* __restrict__ rowi, const int* __restrict__ coli,
                               const int* __restrict__ row_ptr, int* __restrict__ fill,
                               const float* __restrict__ dinv,
                               int* __restrict__ csr_src, float* __restrict__ csr_w, int E) {
  int e = blockIdx.x * 256 + threadIdx.x;
  if (e >= E) return;
  int s = rowi[e], d = coli[e];
  int pos = row_ptr[d] + atomicAdd(&fill[d], 1);
  csr_src[pos] = s;
  csr_w[pos] = dinv[s] * dinv[d];
}

// ---------------- f32 -> bf16 convert ----------------
__global__ void cvt_kernel(const float* __restrict__ in, bf16* __restrict__ out, int n4) {
  int i = blockIdx.x * 256 + threadIdx.x;
  if (i >= n4) return;
  float4 v = ((const float4*)in)[i];
  bf16x4 o = { (bf16)v.x, (bf16)v.y, (bf16)v.z, (bf16)v.w };
  ((bf16x4*)out)[i] = o;
}

// ---------------- W [K][N] f32 -> Wt [N][K] bf16 ----------------
__global__ void transpose_w_kernel(const float* __restrict__ W, bf16* __restrict__ Wt,
                                   int K, int N) {
  __shared__ float tile[32][33];
  int n0 = blockIdx.x * 32, k0 = blockIdx.y * 32;
  int tx = threadIdx.x, ty = threadIdx.y;  // 32 x 8
  #pragma unroll
  for (int i = ty; i < 32; i += 8) tile[i][tx] = W[(size_t)(k0 + i) * N + n0 + tx];
  __syncthreads();
  #pragma unroll
  for (int i = ty; i < 32; i += 8) Wt[(size_t)(n0 + i) * K + k0 + tx] = (bf16)tile[tx][i];
}

// ---------------- bf16 MFMA GEMM: C[M][1024] = A[M][K] * Wt[1024][K]^T ----------------
__global__ __launch_bounds__(256, 2) void gemm_bt_kernel(
    const bf16* __restrict__ A, const bf16* __restrict__ Bt,
    bf16* __restrict__ C, int M, int K) {
  __shared__ __align__(16) bf16 As[128 * 32];
  __shared__ __align__(16) bf16 Bs[128 * 32];
  const int tid = threadIdx.x;
  const int w = tid >> 6, l = tid & 63;
  const int m0 = blockIdx.y * 128, n0 = blockIdx.x * 128;
  const int wr = w >> 1, wc = w & 1;  // 2x2 wave grid, each wave 64x64

  f32x4 acc[4][4] = {};

  const int r0 = tid >> 2;            // 0..63
  const int c8 = (tid & 3) * 8;       // k offset within BK=32
  int ar0 = m0 + r0;       if (ar0 >= M) ar0 = M - 1;
  int ar1 = m0 + r0 + 64;  if (ar1 >= M) ar1 = M - 1;
  const bf16* a0 = A + (size_t)ar0 * K + c8;
  const bf16* a1 = A + (size_t)ar1 * K + c8;
  const bf16* b0 = Bt + (size_t)(n0 + r0) * K + c8;
  const bf16* b1 = Bt + (size_t)(n0 + r0 + 64) * K + c8;
  bf16* asw = As + w * 512;   // wave-uniform LDS dest (bytes: w*1024)
  bf16* bsw = Bs + w * 512;

  const int mrow = l & 15;
  const int kch = (l >> 4) * 8;

  for (int k = 0; k < K; k += 32) {
    load_g2l_16(a0 + k, asw);
    load_g2l_16(a1 + k, asw + 2048);
    load_g2l_16(b0 + k, bsw);
    load_g2l_16(b1 + k, bsw + 2048);
    __syncthreads();   // drains vmcnt before barrier (compiler-inserted)
    bf16x8 af[4], bf_[4];
    #pragma unroll
    for (int m = 0; m < 4; m++)
      af[m] = *(const bf16x8*)&As[(wr * 64 + m * 16 + mrow) * 32 + kch];
    #pragma unroll
    for (int n = 0; n < 4; n++)
      bf_[n] = *(const bf16x8*)&Bs[(wc * 64 + n * 16 + mrow) * 32 + kch];
    #pragma unroll
    for (int m = 0; m < 4; m++)
      #pragma unroll
      for (int n = 0; n < 4; n++)
        acc[m][n] = __builtin_amdgcn_mfma_f32_16x16x32_bf16(af[m], bf_[n], acc[m][n], 0, 0, 0);
    __syncthreads();
  }

  #pragma unroll
  for (int m = 0; m < 4; m++) {
    int grow = m0 + wr * 64 + m * 16 + (l >> 4) * 4;
    #pragma unroll
    for (int n = 0; n < 4; n++) {
      int gcol = n0 + wc * 64 + n * 16 + (l & 15);
      #pragma unroll
      for (int r = 0; r < 4; r++) {
        if (grow + r < M) C[(size_t)(grow + r) * HD + gcol] = (bf16)acc[m][n][r];
      }
    }
  }
}

// ---------------- fused aggregate + bias + LayerNorm + ReLU ----------------
// 2 nodes per 256-thread block; each thread covers 8 cols (bf16x8 = 16B loads).
// NT hints: CSR streams (read once) and hout store (never re-read here) bypass
// caches so the 100MB ht gather working set stays resident in L2/LLC.
__global__ __launch_bounds__(256) void agg_ln_kernel(
    const bf16* __restrict__ ht, const int* __restrict__ row_ptr,
    const int* __restrict__ csr_src, const float* __restrict__ csr_w,
    const float* __restrict__ dinv, const float* __restrict__ bias,
    const float* __restrict__ gamma, const float* __restrict__ beta,
    bf16* __restrict__ hout) {
  const int g = threadIdx.x >> 7;           // node-group within block (0/1)
  const int node = blockIdx.x * 2 + g;
  const int tt = threadIdx.x & 127;         // lane within group; cols [tt*8, tt*8+8)
  const int wid = threadIdx.x >> 6;         // wave id 0..3
  __shared__ float red[4];

  // self-loop
  float dn = dinv[node];
  float wself = dn * dn;
  bf16x8 v = ((const bf16x8*)(ht + (size_t)node * HD))[tt];
  float acc[8];
  #pragma unroll
  for (int j = 0; j < 8; j++) acc[j] = wself * (float)v[j];

  int e = row_ptr[node];
  const int e1 = row_ptr[node + 1];
  for (; e + 4 <= e1; e += 4) {
    int s0 = __builtin_nontemporal_load(csr_src + e);
    int s1 = __builtin_nontemporal_load(csr_src + e + 1);
    int s2 = __builtin_nontemporal_load(csr_src + e + 2);
    int s3 = __builtin_nontemporal_load(csr_src + e + 3);
    float w0 = __builtin_nontemporal_load(csr_w + e);
    float w1 = __builtin_nontemporal_load(csr_w + e + 1);
    float w2 = __builtin_nontemporal_load(csr_w + e + 2);
    float w3 = __builtin_nontemporal_load(csr_w + e + 3);
    bf16x8 u0 = ((const bf16x8*)(ht + (size_t)s0 * HD))[tt];
    bf16x8 u1 = ((const bf16x8*)(ht + (size_t)s1 * HD))[tt];
    bf16x8 u2 = ((const bf16x8*)(ht + (size_t)s2 * HD))[tt];
    bf16x8 u3 = ((const bf16x8*)(ht + (size_t)s3 * HD))[tt];
    #pragma unroll
    for (int j = 0; j < 8; j++)
      acc[j] += w0 * (float)u0[j] + w1 * (float)u1[j] + w2 * (float)u2[j] + w3 * (float)u3[j];
  }
  for (; e < e1; e++) {
    int src = __builtin_nontemporal_load(csr_src + e);
    float wgt = __builtin_nontemporal_load(csr_w + e);
    bf16x8 u = ((const bf16x8*)(ht + (size_t)src * HD))[tt];
    #pragma unroll
    for (int j = 0; j < 8; j++) acc[j] += wgt * (float)u[j];
  }

  const float4* bias2 = (const float4*)bias;
  float4 ba = bias2[tt * 2], bb = bias2[tt * 2 + 1];
  acc[0] += ba.x; acc[1] += ba.y; acc[2] += ba.z; acc[3] += ba.w;
  acc[4] += bb.x; acc[5] += bb.y; acc[6] += bb.z; acc[7] += bb.w;

  // mean (reduce over the 128 threads of this node-group: 2 waves)
  float s = 0.f;
  #pragma unroll
  for (int j = 0; j < 8; j++) s += acc[j];
  #pragma unroll
  for (int off = 32; off; off >>= 1) s += __shfl_down(s, off, 64);
  if ((threadIdx.x & 63) == 0) red[wid] = s;
  __syncthreads();
  float mean = (red[g * 2] + red[g * 2 + 1]) * (1.0f / HD);
  __syncthreads();

  float d[8], s2 = 0.f;
  #pragma unroll
  for (int j = 0; j < 8; j++) { d[j] = acc[j] - mean; s2 += d[j] * d[j]; }
  #pragma unroll
  for (int off = 32; off; off >>= 1) s2 += __shfl_down(s2, off, 64);
  if ((threadIdx.x & 63) == 0) red[wid] = s2;
  __syncthreads();
  float var = (red[g * 2] + red[g * 2 + 1]) * (1.0f / HD);
  float rstd = rsqrtf(var + EPSV);

  const float4* gam2 = (const float4*)gamma;
  const float4* bet2 = (const float4*)beta;
  float4 g0 = gam2[tt * 2], g1 = gam2[tt * 2 + 1];
  float4 be0 = bet2[tt * 2], be1 = bet2[tt * 2 + 1];
  float gv[8] = {g0.x, g0.y, g0.z, g0.w, g1.x, g1.y, g1.z, g1.w};
  float bv[8] = {be0.x, be0.y, be0.z, be0.w, be1.x, be1.y, be1.z, be1.w};
  bf16x8 o;
  #pragma unroll
  for (int j = 0; j < 8; j++) o[j] = (bf16)fmaxf(d[j] * rstd * gv[j] + bv[j], 0.0f);
  union { bf16x8 b; u32x4 u; } cv;
  cv.b = o;
  __builtin_nontemporal_store(cv.u, (u32x4*)(hout + (size_t)node * HD) + tt);
}

// ---------------- graph boundaries (batch is sorted) ----------------
__global__ void starts_kernel(const int* __restrict__ batch, int* __restrict__ start,
                              int n, int ngraph) {
  int g = blockIdx.x * blockDim.x + threadIdx.x;
  if (g > ngraph) return;
  int lo = 0, hi = n;
  while (lo < hi) {
    int mid = (lo + hi) >> 1;
    if (batch[mid] < g) lo = mid + 1; else hi = mid;
  }
  start[g] = lo;
}

// ---------------- mean-pool per graph: partial sums + atomics ----------------
#define POOL_CHUNKS 8
__global__ void pool_partial_kernel(const bf16* __restrict__ h, const int* __restrict__ start,
                                    float* __restrict__ out) {
  int g = blockIdx.y, c = blockIdx.x;
  int t = threadIdx.x;
  int s0 = start[g], s1 = start[g + 1];
  int len = s1 - s0;
  int per = (len + POOL_CHUNKS - 1) / POOL_CHUNKS;
  int a = s0 + c * per;
  int b = min(a + per, s1);
  if (a >= b) return;
  f32x4 acc = {0.f, 0.f, 0.f, 0.f};
  for (int n = a; n < b; n++) {
    bf16x4 v = ((const bf16x4*)(h + (size_t)n * HD))[t];
    acc[0] += (float)v[0]; acc[1] += (float)v[1];
    acc[2] += (float)v[2]; acc[3] += (float)v[3];
  }
  float* o = out + (size_t)g * HD + t * 4;
  atomicAdd(o + 0, acc[0]);
  atomicAdd(o + 1, acc[1]);
  atomicAdd(o + 2, acc[2]);
  atomicAdd(o + 3, acc[3]);
}

__global__ void pool_div_kernel(float* __restrict__ out, const int* __restrict__ start) {
  int i = blockIdx.x * 256 + threadIdx.x;
  if (i >= NG * HD) return;
  int g = i >> 10;
  float c = (float)max(start[g + 1] - start[g], 1);
  out[i] = out[i] / c;
}

extern "C" void kernel_launch(void* const* d_in, const int* in_sizes, int n_in,
                              void* d_out, int out_size, void* d_ws, size_t ws_size,
                              hipStream_t stream) {
  const float* x      = (const float*)d_in[0];
  const int*   eidx   = (const int*)d_in[1];
  const int*   batch  = (const int*)d_in[2];
  const float* W0     = (const float*)d_in[3];
  const float* b0     = (const float*)d_in[4];
  const float* Ws     = (const float*)d_in[5];
  const float* bs     = (const float*)d_in[6];
  const float* gammas = (const float*)d_in[7];
  const float* betas  = (const float*)d_in[8];
  float* out = (float*)d_out;

  const int* erow = eidx;        // sources
  const int* ecol = eidx + NE;   // targets (aggregation index)

  char* ws = (char*)d_ws;
  size_t off = 0;
  auto alloc = [&](size_t bytes) {
    void* p = ws + off;
    off = (off + bytes + 255) & ~(size_t)255;
    return p;
  };
  int*   cnt     = (int*)alloc((size_t)NN * 4);
  int*   row_ptr = (int*)alloc((size_t)(NN + 1) * 4);
  int*   fill    = (int*)alloc((size_t)NN * 4);
  int*   partial = (int*)alloc(256 * 4);
  float* dinv    = (float*)alloc((size_t)NN * 4);
  int*   csr_src = (int*)alloc((size_t)NE * 4);
  float* csr_w   = (float*)alloc((size_t)NE * 4);
  bf16*  Wt      = (bf16*)alloc((size_t)HD * HD * 2);
  bf16*  hbuf    = (bf16*)alloc((size_t)NN * HD * 2);
  bf16*  htbuf   = (bf16*)alloc((size_t)NN * HD * 2);
  int*   gstart  = (int*)alloc(65 * 4);

  hipMemsetAsync(cnt, 0, (size_t)NN * 4, stream);
  hipMemsetAsync(fill, 0, (size_t)NN * 4, stream);
  hipMemsetAsync(out, 0, (size_t)NG * HD * 4, stream);

  hist_kernel<<<(NE + 255) / 256, 256, 0, stream>>>(ecol, cnt, NE);
  dinv_kernel<<<(NN + 255) / 256, 256, 0, stream>>>(cnt, dinv, NN);
  int nb = (NN + 255) / 256;  // 196
  scan_partial_kernel<<<nb, 256, 0, stream>>>(cnt, partial, NN);
  scan_scan_kernel<<<1, 256, 0, stream>>>(partial, nb);
  scan_final_kernel<<<nb, 256, 0, stream>>>(cnt, partial, row_ptr, NN, NE);
  scatter_kernel<<<(NE + 255) / 256, 256, 0, stream>>>(erow, ecol, row_ptr, fill, dinv,
                                                       csr_src, csr_w, NE);
  starts_kernel<<<1, 128, 0, stream>>>(batch, gstart, NN, NG);

  cvt_kernel<<<(NN * FIN / 4 + 255) / 256, 256, 0, stream>>>(x, hbuf, NN * FIN / 4);

  for (int L = 0; L < 4; L++) {
    int K = (L == 0) ? FIN : HD;
    const float* W    = (L == 0) ? W0 : Ws + (size_t)(L - 1) * HD * HD;
    const float* bias = (L == 0) ? b0 : bs + (size_t)(L - 1) * HD;
    transpose_w_kernel<<<dim3(HD / 32, K / 32), dim3(32, 8), 0, stream>>>(W, Wt, K, HD);
    gemm_bt_kernel<<<dim3(HD / 128, (NN + 127) / 128), 256, 0, stream>>>(hbuf, Wt, htbuf, NN, K);
    agg_ln_kernel<<<NN / 2, 256, 0, stream>>>(htbuf, row_ptr, csr_src, csr_w, dinv, bias,
                                              gammas + (size_t)L * HD, betas + (size_t)L * HD, hbuf);
  }

  pool_partial_kernel<<<dim3(POOL_CHUNKS, NG), 256, 0, stream>>>(hbuf, gstart, out);
  pool_div_kernel<<<(NG * HD + 255) / 256, 256, 0, stream>>>(out, gstart);
}

// Round 4
// 2560.979 us; speedup vs baseline: 1.0396x; 1.0396x over previous
//
#include <hip/hip_runtime.h>
#include <hip/hip_bf16.h>
#include <stdint.h>

#define NN 50000
#define NE 1600000
#define NG 64
#define FIN 256
#define HD 1024
#define EPSV 1e-5f

typedef __bf16 bf16;
typedef __bf16 bf16x4 __attribute__((ext_vector_type(4)));
typedef __bf16 bf16x8 __attribute__((ext_vector_type(8)));
typedef float f32x4 __attribute__((ext_vector_type(4)));
typedef char c8x8 __attribute__((ext_vector_type(8)));

typedef const __attribute__((address_space(1))) void* gptr_as1;
typedef __attribute__((address_space(3))) void* lptr_as3;

__device__ __forceinline__ void load_g2l_16(const void* g, const void* l) {
  __builtin_amdgcn_global_load_lds((gptr_as1)(uintptr_t)g,
                                   (lptr_as3)(uint32_t)(uintptr_t)l, 16, 0, 0);
}

// ---------------- degree histogram / dinv ----------------
__global__ void hist_kernel(const int* __restrict__ col, int* __restrict__ cnt, int E) {
  int e = blockIdx.x * 256 + threadIdx.x;
  if (e < E) atomicAdd(&cnt[col[e]], 1);
}

__global__ void dinv_kernel(const int* __restrict__ cnt, float* __restrict__ dinv, int n) {
  int i = blockIdx.x * 256 + threadIdx.x;
  if (i < n) dinv[i] = rsqrtf((float)(cnt[i] + 1));  // +1 self-loop
}

// ---------------- exclusive scan (3-phase) ----------------
__global__ void scan_partial_kernel(const int* __restrict__ cnt, int* __restrict__ partial, int n) {
  __shared__ int red[4];
  int i = blockIdx.x * 256 + threadIdx.x;
  int v = (i < n) ? cnt[i] : 0;
  #pragma unroll
  for (int off = 32; off; off >>= 1) v += __shfl_down(v, off, 64);
  if ((threadIdx.x & 63) == 0) red[threadIdx.x >> 6] = v;
  __syncthreads();
  if (threadIdx.x == 0) partial[blockIdx.x] = red[0] + red[1] + red[2] + red[3];
}

__global__ void scan_scan_kernel(int* __restrict__ partial, int nb) {
  __shared__ int s[256];
  int t = threadIdx.x;
  int v = (t < nb) ? partial[t] : 0;
  s[t] = v;
  __syncthreads();
  for (int off = 1; off < 256; off <<= 1) {
    int x = (t >= off) ? s[t - off] : 0;
    __syncthreads();
    s[t] += x;
    __syncthreads();
  }
  if (t < nb) partial[t] = s[t] - v;  // exclusive
}

__global__ void scan_final_kernel(const int* __restrict__ cnt, const int* __restrict__ partial,
                                  int* __restrict__ row_ptr, int n, int E) {
  __shared__ int s[256];
  int t = threadIdx.x;
  int i = blockIdx.x * 256 + t;
  int v = (i < n) ? cnt[i] : 0;
  s[t] = v;
  __syncthreads();
  for (int off = 1; off < 256; off <<= 1) {
    int x = (t >= off) ? s[t - off] : 0;
    __syncthreads();
    s[t] += x;
    __syncthreads();
  }
  if (i < n) row_ptr[i] = partial[blockIdx.x] + s[t] - v;
  if (i == 0) row_ptr[n] = E;
}

// ---------------- CSR scatter ----------------
__global__ void scatter_kernel(const int* __restrict__ rowi, const int* __restrict__ coli,
                               const int* __restrict__ row_ptr, int* __restrict__ fill,
                               const float* __restrict__ dinv,
                               int* __restrict__ csr_src, float* __restrict__ csr_w, int E) {
  int e = blockIdx.x * 256 + threadIdx.x;
  if (e >= E) return;
  int s = rowi[e], d = coli[e];
  int pos = row_ptr[d] + atomicAdd(&fill[d], 1);
  csr_src[pos] = s;
  csr_w[pos] = dinv[s] * dinv[d];
}

// ---------------- f32 -> bf16 convert ----------------
__global__ void cvt_kernel(const float* __restrict__ in, bf16* __restrict__ out, int n4) {
  int i = blockIdx.x * 256 + threadIdx.x;
  if (i >= n4) return;
  float4 v = ((const float4*)in)[i];
  bf16x4 o = { (bf16)v.x, (bf16)v.y, (bf16)v.z, (bf16)v.w };
  ((bf16x4*)out)[i] = o;
}

// ---------------- W [K][N] f32 -> Wt [N][K] bf16 ----------------
__global__ void transpose_w_kernel(const float* __restrict__ W, bf16* __restrict__ Wt,
                                   int K, int N) {
  __shared__ float tile[32][33];
  int n0 = blockIdx.x * 32, k0 = blockIdx.y * 32;
  int tx = threadIdx.x, ty = threadIdx.y;  // 32 x 8
  #pragma unroll
  for (int i = ty; i < 32; i += 8) tile[i][tx] = W[(size_t)(k0 + i) * N + n0 + tx];
  __syncthreads();
  #pragma unroll
  for (int i = ty; i < 32; i += 8) Wt[(size_t)(n0 + i) * K + k0 + tx] = (bf16)tile[tx][i];
}

// ---------------- bf16 MFMA GEMM: C[M][1024] = A[M][K] * Wt[1024][K]^T ----------------
__global__ __launch_bounds__(256, 2) void gemm_bt_kernel(
    const bf16* __restrict__ A, const bf16* __restrict__ Bt,
    bf16* __restrict__ C, int M, int K) {
  __shared__ __align__(16) bf16 As[128 * 32];
  __shared__ __align__(16) bf16 Bs[128 * 32];
  const int tid = threadIdx.x;
  const int w = tid >> 6, l = tid & 63;
  const int m0 = blockIdx.y * 128, n0 = blockIdx.x * 128;
  const int wr = w >> 1, wc = w & 1;  // 2x2 wave grid, each wave 64x64

  f32x4 acc[4][4] = {};

  const int r0 = tid >> 2;            // 0..63
  const int c8 = (tid & 3) * 8;       // k offset within BK=32
  int ar0 = m0 + r0;       if (ar0 >= M) ar0 = M - 1;
  int ar1 = m0 + r0 + 64;  if (ar1 >= M) ar1 = M - 1;
  const bf16* a0 = A + (size_t)ar0 * K + c8;
  const bf16* a1 = A + (size_t)ar1 * K + c8;
  const bf16* b0 = Bt + (size_t)(n0 + r0) * K + c8;
  const bf16* b1 = Bt + (size_t)(n0 + r0 + 64) * K + c8;
  bf16* asw = As + w * 512;   // wave-uniform LDS dest (bytes: w*1024)
  bf16* bsw = Bs + w * 512;

  const int mrow = l & 15;
  const int kch = (l >> 4) * 8;

  for (int k = 0; k < K; k += 32) {
    load_g2l_16(a0 + k, asw);
    load_g2l_16(a1 + k, asw + 2048);
    load_g2l_16(b0 + k, bsw);
    load_g2l_16(b1 + k, bsw + 2048);
    __syncthreads();   // drains vmcnt before barrier (compiler-inserted)
    bf16x8 af[4], bf_[4];
    #pragma unroll
    for (int m = 0; m < 4; m++)
      af[m] = *(const bf16x8*)&As[(wr * 64 + m * 16 + mrow) * 32 + kch];
    #pragma unroll
    for (int n = 0; n < 4; n++)
      bf_[n] = *(const bf16x8*)&Bs[(wc * 64 + n * 16 + mrow) * 32 + kch];
    #pragma unroll
    for (int m = 0; m < 4; m++)
      #pragma unroll
      for (int n = 0; n < 4; n++)
        acc[m][n] = __builtin_amdgcn_mfma_f32_16x16x32_bf16(af[m], bf_[n], acc[m][n], 0, 0, 0);
    __syncthreads();
  }

  #pragma unroll
  for (int m = 0; m < 4; m++) {
    int grow = m0 + wr * 64 + m * 16 + (l >> 4) * 4;
    #pragma unroll
    for (int n = 0; n < 4; n++) {
      int gcol = n0 + wc * 64 + n * 16 + (l & 15);
      #pragma unroll
      for (int r = 0; r < 4; r++) {
        if (grow + r < M) C[(size_t)(grow + r) * HD + gcol] = (bf16)acc[m][n][r];
      }
    }
  }
}

// ---------------- per-row int8 quantization of ht ----------------
// One block per row: amax over 1024 cols -> scale = amax/127 -> int8 row.
__global__ __launch_bounds__(256) void quant_kernel(
    const bf16* __restrict__ ht, char* __restrict__ hti8, float* __restrict__ rowscale) {
  const int row = blockIdx.x;
  const int t = threadIdx.x;
  __shared__ float red[4];
  bf16x4 v = ((const bf16x4*)(ht + (size_t)row * HD))[t];
  float f0 = (float)v[0], f1 = (float)v[1], f2 = (float)v[2], f3 = (float)v[3];
  float m = fmaxf(fmaxf(fabsf(f0), fabsf(f1)), fmaxf(fabsf(f2), fabsf(f3)));
  #pragma unroll
  for (int off = 32; off; off >>= 1) m = fmaxf(m, __shfl_xor(m, off, 64));
  if ((t & 63) == 0) red[t >> 6] = m;
  __syncthreads();
  m = fmaxf(fmaxf(red[0], red[1]), fmaxf(red[2], red[3]));
  float inv = (m > 0.f) ? 127.0f / m : 0.f;
  int q0 = __float2int_rn(f0 * inv), q1 = __float2int_rn(f1 * inv);
  int q2 = __float2int_rn(f2 * inv), q3 = __float2int_rn(f3 * inv);
  uint32_t packed = ((uint32_t)(q0 & 0xff)) | ((uint32_t)(q1 & 0xff) << 8) |
                    ((uint32_t)(q2 & 0xff) << 16) | ((uint32_t)(q3 & 0xff) << 24);
  ((uint32_t*)hti8)[row * 256 + t] = packed;
  if (t == 0) rowscale[row] = (m > 0.f) ? m / 127.0f : 0.f;
}

// ---------------- fused aggregate + bias + LayerNorm + ReLU (int8 gather) ----------------
// 2 nodes per 256-thread block; each lane covers 8 cols (8 int8 = 8B loads).
__global__ __launch_bounds__(256) void agg_ln_i8_kernel(
    const char* __restrict__ hti8, const float* __restrict__ rowscale,
    const int* __restrict__ row_ptr,
    const int* __restrict__ csr_src, const float* __restrict__ csr_w,
    const float* __restrict__ dinv, const float* __restrict__ bias,
    const float* __restrict__ gamma, const float* __restrict__ beta,
    bf16* __restrict__ hout) {
  const int g = threadIdx.x >> 7;
  const int node = blockIdx.x * 2 + g;
  const int tt = threadIdx.x & 127;
  const int wid = threadIdx.x >> 6;
  __shared__ float red[4];

  // self-loop
  float dn = dinv[node];
  float wself = dn * dn * rowscale[node];
  c8x8 v = ((const c8x8*)(hti8 + (size_t)node * HD))[tt];
  float acc[8];
  #pragma unroll
  for (int j = 0; j < 8; j++) acc[j] = wself * (float)v[j];

  int e = row_ptr[node];
  const int e1 = row_ptr[node + 1];
  for (; e + 4 <= e1; e += 4) {
    int s0 = csr_src[e], s1 = csr_src[e + 1], s2 = csr_src[e + 2], s3 = csr_src[e + 3];
    float w0 = csr_w[e] * rowscale[s0];
    float w1 = csr_w[e + 1] * rowscale[s1];
    float w2 = csr_w[e + 2] * rowscale[s2];
    float w3 = csr_w[e + 3] * rowscale[s3];
    c8x8 u0 = ((const c8x8*)(hti8 + (size_t)s0 * HD))[tt];
    c8x8 u1 = ((const c8x8*)(hti8 + (size_t)s1 * HD))[tt];
    c8x8 u2 = ((const c8x8*)(hti8 + (size_t)s2 * HD))[tt];
    c8x8 u3 = ((const c8x8*)(hti8 + (size_t)s3 * HD))[tt];
    #pragma unroll
    for (int j = 0; j < 8; j++)
      acc[j] += w0 * (float)u0[j] + w1 * (float)u1[j] + w2 * (float)u2[j] + w3 * (float)u3[j];
  }
  for (; e < e1; e++) {
    int src = csr_src[e];
    float wgt = csr_w[e] * rowscale[src];
    c8x8 u = ((const c8x8*)(hti8 + (size_t)src * HD))[tt];
    #pragma unroll
    for (int j = 0; j < 8; j++) acc[j] += wgt * (float)u[j];
  }

  const float4* bias2 = (const float4*)bias;
  float4 ba = bias2[tt * 2], bb = bias2[tt * 2 + 1];
  acc[0] += ba.x; acc[1] += ba.y; acc[2] += ba.z; acc[3] += ba.w;
  acc[4] += bb.x; acc[5] += bb.y; acc[6] += bb.z; acc[7] += bb.w;

  float s = 0.f;
  #pragma unroll
  for (int j = 0; j < 8; j++) s += acc[j];
  #pragma unroll
  for (int off = 32; off; off >>= 1) s += __shfl_down(s, off, 64);
  if ((threadIdx.x & 63) == 0) red[wid] = s;
  __syncthreads();
  float mean = (red[g * 2] + red[g * 2 + 1]) * (1.0f / HD);
  __syncthreads();

  float d[8], s2 = 0.f;
  #pragma unroll
  for (int j = 0; j < 8; j++) { d[j] = acc[j] - mean; s2 += d[j] * d[j]; }
  #pragma unroll
  for (int off = 32; off; off >>= 1) s2 += __shfl_down(s2, off, 64);
  if ((threadIdx.x & 63) == 0) red[wid] = s2;
  __syncthreads();
  float var = (red[g * 2] + red[g * 2 + 1]) * (1.0f / HD);
  float rstd = rsqrtf(var + EPSV);

  const float4* gam2 = (const float4*)gamma;
  const float4* bet2 = (const float4*)beta;
  float4 g0 = gam2[tt * 2], g1 = gam2[tt * 2 + 1];
  float4 be0 = bet2[tt * 2], be1 = bet2[tt * 2 + 1];
  float gv[8] = {g0.x, g0.y, g0.z, g0.w, g1.x, g1.y, g1.z, g1.w};
  float bv[8] = {be0.x, be0.y, be0.z, be0.w, be1.x, be1.y, be1.z, be1.w};
  bf16x8 o;
  #pragma unroll
  for (int j = 0; j < 8; j++) o[j] = (bf16)fmaxf(d[j] * rstd * gv[j] + bv[j], 0.0f);
  ((bf16x8*)(hout + (size_t)node * HD))[tt] = o;
}

// ---------------- fallback: bf16 gather (round-2 proven path) ----------------
__global__ __launch_bounds__(256) void agg_ln_kernel(
    const bf16* __restrict__ ht, const int* __restrict__ row_ptr,
    const int* __restrict__ csr_src, const float* __restrict__ csr_w,
    const float* __restrict__ dinv, const float* __restrict__ bias,
    const float* __restrict__ gamma, const float* __restrict__ beta,
    bf16* __restrict__ hout) {
  const int g = threadIdx.x >> 7;
  const int node = blockIdx.x * 2 + g;
  const int tt = threadIdx.x & 127;
  const int wid = threadIdx.x >> 6;
  __shared__ float red[4];

  float dn = dinv[node];
  float wself = dn * dn;
  bf16x8 v = ((const bf16x8*)(ht + (size_t)node * HD))[tt];
  float acc[8];
  #pragma unroll
  for (int j = 0; j < 8; j++) acc[j] = wself * (float)v[j];

  int e = row_ptr[node];
  const int e1 = row_ptr[node + 1];
  for (; e + 4 <= e1; e += 4) {
    int s0 = csr_src[e], s1 = csr_src[e + 1], s2 = csr_src[e + 2], s3 = csr_src[e + 3];
    float w0 = csr_w[e], w1 = csr_w[e + 1], w2 = csr_w[e + 2], w3 = csr_w[e + 3];
    bf16x8 u0 = ((const bf16x8*)(ht + (size_t)s0 * HD))[tt];
    bf16x8 u1 = ((const bf16x8*)(ht + (size_t)s1 * HD))[tt];
    bf16x8 u2 = ((const bf16x8*)(ht + (size_t)s2 * HD))[tt];
    bf16x8 u3 = ((const bf16x8*)(ht + (size_t)s3 * HD))[tt];
    #pragma unroll
    for (int j = 0; j < 8; j++)
      acc[j] += w0 * (float)u0[j] + w1 * (float)u1[j] + w2 * (float)u2[j] + w3 * (float)u3[j];
  }
  for (; e < e1; e++) {
    int src = csr_src[e];
    float wgt = csr_w[e];
    bf16x8 u = ((const bf16x8*)(ht + (size_t)src * HD))[tt];
    #pragma unroll
    for (int j = 0; j < 8; j++) acc[j] += wgt * (float)u[j];
  }

  const float4* bias2 = (const float4*)bias;
  float4 ba = bias2[tt * 2], bb = bias2[tt * 2 + 1];
  acc[0] += ba.x; acc[1] += ba.y; acc[2] += ba.z; acc[3] += ba.w;
  acc[4] += bb.x; acc[5] += bb.y; acc[6] += bb.z; acc[7] += bb.w;

  float s = 0.f;
  #pragma unroll
  for (int j = 0; j < 8; j++) s += acc[j];
  #pragma unroll
  for (int off = 32; off; off >>= 1) s += __shfl_down(s, off, 64);
  if ((threadIdx.x & 63) == 0) red[wid] = s;
  __syncthreads();
  float mean = (red[g * 2] + red[g * 2 + 1]) * (1.0f / HD);
  __syncthreads();

  float d[8], s2 = 0.f;
  #pragma unroll
  for (int j = 0; j < 8; j++) { d[j] = acc[j] - mean; s2 += d[j] * d[j]; }
  #pragma unroll
  for (int off = 32; off; off >>= 1) s2 += __shfl_down(s2, off, 64);
  if ((threadIdx.x & 63) == 0) red[wid] = s2;
  __syncthreads();
  float var = (red[g * 2] + red[g * 2 + 1]) * (1.0f / HD);
  float rstd = rsqrtf(var + EPSV);

  const float4* gam2 = (const float4*)gamma;
  const float4* bet2 = (const float4*)beta;
  float4 g0 = gam2[tt * 2], g1 = gam2[tt * 2 + 1];
  float4 be0 = bet2[tt * 2], be1 = bet2[tt * 2 + 1];
  float gv[8] = {g0.x, g0.y, g0.z, g0.w, g1.x, g1.y, g1.z, g1.w};
  float bv[8] = {be0.x, be0.y, be0.z, be0.w, be1.x, be1.y, be1.z, be1.w};
  bf16x8 o;
  #pragma unroll
  for (int j = 0; j < 8; j++) o[j] = (bf16)fmaxf(d[j] * rstd * gv[j] + bv[j], 0.0f);
  ((bf16x8*)(hout + (size_t)node * HD))[tt] = o;
}

// ---------------- graph boundaries (batch is sorted) ----------------
__global__ void starts_kernel(const int* __restrict__ batch, int* __restrict__ start,
                              int n, int ngraph) {
  int g = blockIdx.x * blockDim.x + threadIdx.x;
  if (g > ngraph) return;
  int lo = 0, hi = n;
  while (lo < hi) {
    int mid = (lo + hi) >> 1;
    if (batch[mid] < g) lo = mid + 1; else hi = mid;
  }
  start[g] = lo;
}

// ---------------- mean-pool per graph: partial sums + atomics ----------------
#define POOL_CHUNKS 8
__global__ void pool_partial_kernel(const bf16* __restrict__ h, const int* __restrict__ start,
                                    float* __restrict__ out) {
  int g = blockIdx.y, c = blockIdx.x;
  int t = threadIdx.x;
  int s0 = start[g], s1 = start[g + 1];
  int len = s1 - s0;
  int per = (len + POOL_CHUNKS - 1) / POOL_CHUNKS;
  int a = s0 + c * per;
  int b = min(a + per, s1);
  if (a >= b) return;
  f32x4 acc = {0.f, 0.f, 0.f, 0.f};
  for (int n = a; n < b; n++) {
    bf16x4 v = ((const bf16x4*)(h + (size_t)n * HD))[t];
    acc[0] += (float)v[0]; acc[1] += (float)v[1];
    acc[2] += (float)v[2]; acc[3] += (float)v[3];
  }
  float* o = out + (size_t)g * HD + t * 4;
  atomicAdd(o + 0, acc[0]);
  atomicAdd(o + 1, acc[1]);
  atomicAdd(o + 2, acc[2]);
  atomicAdd(o + 3, acc[3]);
}

__global__ void pool_div_kernel(float* __restrict__ out, const int* __restrict__ start) {
  int i = blockIdx.x * 256 + threadIdx.x;
  if (i >= NG * HD) return;
  int g = i >> 10;
  float c = (float)max(start[g + 1] - start[g], 1);
  out[i] = out[i] / c;
}

extern "C" void kernel_launch(void* const* d_in, const int* in_sizes, int n_in,
                              void* d_out, int out_size, void* d_ws, size_t ws_size,
                              hipStream_t stream) {
  const float* x      = (const float*)d_in[0];
  const int*   eidx   = (const int*)d_in[1];
  const int*   batch  = (const int*)d_in[2];
  const float* W0     = (const float*)d_in[3];
  const float* b0     = (const float*)d_in[4];
  const float* Ws     = (const float*)d_in[5];
  const float* bs     = (const float*)d_in[6];
  const float* gammas = (const float*)d_in[7];
  const float* betas  = (const float*)d_in[8];
  float* out = (float*)d_out;

  const int* erow = eidx;        // sources
  const int* ecol = eidx + NE;   // targets (aggregation index)

  char* ws = (char*)d_ws;
  size_t off = 0;
  auto alloc = [&](size_t bytes) {
    void* p = ws + off;
    off = (off + bytes + 255) & ~(size_t)255;
    return p;
  };
  int*   cnt     = (int*)alloc((size_t)NN * 4);
  int*   row_ptr = (int*)alloc((size_t)(NN + 1) * 4);
  int*   fill    = (int*)alloc((size_t)NN * 4);
  int*   partial = (int*)alloc(256 * 4);
  float* dinv    = (float*)alloc((size_t)NN * 4);
  int*   csr_src = (int*)alloc((size_t)NE * 4);
  float* csr_w   = (float*)alloc((size_t)NE * 4);
  bf16*  Wt      = (bf16*)alloc((size_t)HD * HD * 2);
  bf16*  hbuf    = (bf16*)alloc((size_t)NN * HD * 2);
  bf16*  htbuf   = (bf16*)alloc((size_t)NN * HD * 2);
  int*   gstart  = (int*)alloc(65 * 4);
  // int8 path extras (gated on ws_size)
  char*  hti8     = (char*)alloc((size_t)NN * HD);
  float* rowscale = (float*)alloc((size_t)NN * 4);
  const bool use_i8 = (off <= ws_size);

  hipMemsetAsync(cnt, 0, (size_t)NN * 4, stream);
  hipMemsetAsync(fill, 0, (size_t)NN * 4, stream);
  hipMemsetAsync(out, 0, (size_t)NG * HD * 4, stream);

  hist_kernel<<<(NE + 255) / 256, 256, 0, stream>>>(ecol, cnt, NE);
  dinv_kernel<<<(NN + 255) / 256, 256, 0, stream>>>(cnt, dinv, NN);
  int nb = (NN + 255) / 256;  // 196
  scan_partial_kernel<<<nb, 256, 0, stream>>>(cnt, partial, NN);
  scan_scan_kernel<<<1, 256, 0, stream>>>(partial, nb);
  scan_final_kernel<<<nb, 256, 0, stream>>>(cnt, partial, row_ptr, NN, NE);
  scatter_kernel<<<(NE + 255) / 256, 256, 0, stream>>>(erow, ecol, row_ptr, fill, dinv,
                                                       csr_src, csr_w, NE);
  starts_kernel<<<1, 128, 0, stream>>>(batch, gstart, NN, NG);

  cvt_kernel<<<(NN * FIN / 4 + 255) / 256, 256, 0, stream>>>(x, hbuf, NN * FIN / 4);

  for (int L = 0; L < 4; L++) {
    int K = (L == 0) ? FIN : HD;
    const float* W    = (L == 0) ? W0 : Ws + (size_t)(L - 1) * HD * HD;
    const float* bias = (L == 0) ? b0 : bs + (size_t)(L - 1) * HD;
    transpose_w_kernel<<<dim3(HD / 32, K / 32), dim3(32, 8), 0, stream>>>(W, Wt, K, HD);
    gemm_bt_kernel<<<dim3(HD / 128, (NN + 127) / 128), 256, 0, stream>>>(hbuf, Wt, htbuf, NN, K);
    if (use_i8) {
      quant_kernel<<<NN, 256, 0, stream>>>(htbuf, hti8, rowscale);
      agg_ln_i8_kernel<<<NN / 2, 256, 0, stream>>>(hti8, rowscale, row_ptr, csr_src, csr_w,
                                                   dinv, bias, gammas + (size_t)L * HD,
                                                   betas + (size_t)L * HD, hbuf);
    } else {
      agg_ln_kernel<<<NN / 2, 256, 0, stream>>>(htbuf, row_ptr, csr_src, csr_w, dinv, bias,
                                                gammas + (size_t)L * HD,
                                                betas + (size_t)L * HD, hbuf);
    }
  }

  pool_partial_kernel<<<dim3(POOL_CHUNKS, NG), 256, 0, stream>>>(hbuf, gstart, out);
  pool_div_kernel<<<(NG * HD + 255) / 256, 256, 0, stream>>>(out, gstart);
}

// Round 5
// 1833.129 us; speedup vs baseline: 1.4524x; 1.3971x over previous
//
#include <hip/hip_runtime.h>
#include <hip/hip_bf16.h>
#include <stdint.h>

#define NN 50000
#define NE 1600000
#define NG 64
#define FIN 256
#define HD 1024
#define EPSV 1e-5f

typedef __bf16 bf16;
typedef __bf16 bf16x4 __attribute__((ext_vector_type(4)));
typedef __bf16 bf16x8 __attribute__((ext_vector_type(8)));
typedef float f32x4 __attribute__((ext_vector_type(4)));
typedef char c8x8 __attribute__((ext_vector_type(8)));

typedef const __attribute__((address_space(1))) void* gptr_as1;
typedef __attribute__((address_space(3))) void* lptr_as3;

__device__ __forceinline__ void load_g2l_16(const void* g, const void* l) {
  __builtin_amdgcn_global_load_lds((gptr_as1)(uintptr_t)g,
                                   (lptr_as3)(uint32_t)(uintptr_t)l, 16, 0, 0);
}

// ---------------- degree histogram / dinv ----------------
__global__ void hist_kernel(const int* __restrict__ col, int* __restrict__ cnt, int E) {
  int e = blockIdx.x * 256 + threadIdx.x;
  if (e < E) atomicAdd(&cnt[col[e]], 1);
}

__global__ void dinv_kernel(const int* __restrict__ cnt, float* __restrict__ dinv, int n) {
  int i = blockIdx.x * 256 + threadIdx.x;
  if (i < n) dinv[i] = rsqrtf((float)(cnt[i] + 1));  // +1 self-loop
}

// ---------------- exclusive scan (3-phase) ----------------
__global__ void scan_partial_kernel(const int* __restrict__ cnt, int* __restrict__ partial, int n) {
  __shared__ int red[4];
  int i = blockIdx.x * 256 + threadIdx.x;
  int v = (i < n) ? cnt[i] : 0;
  #pragma unroll
  for (int off = 32; off; off >>= 1) v += __shfl_down(v, off, 64);
  if ((threadIdx.x & 63) == 0) red[threadIdx.x >> 6] = v;
  __syncthreads();
  if (threadIdx.x == 0) partial[blockIdx.x] = red[0] + red[1] + red[2] + red[3];
}

__global__ void scan_scan_kernel(int* __restrict__ partial, int nb) {
  __shared__ int s[256];
  int t = threadIdx.x;
  int v = (t < nb) ? partial[t] : 0;
  s[t] = v;
  __syncthreads();
  for (int off = 1; off < 256; off <<= 1) {
    int x = (t >= off) ? s[t - off] : 0;
    __syncthreads();
    s[t] += x;
    __syncthreads();
  }
  if (t < nb) partial[t] = s[t] - v;  // exclusive
}

__global__ void scan_final_kernel(const int* __restrict__ cnt, const int* __restrict__ partial,
                                  int* __restrict__ row_ptr, int n, int E) {
  __shared__ int s[256];
  int t = threadIdx.x;
  int i = blockIdx.x * 256 + t;
  int v = (i < n) ? cnt[i] : 0;
  s[t] = v;
  __syncthreads();
  for (int off = 1; off < 256; off <<= 1) {
    int x = (t >= off) ? s[t - off] : 0;
    __syncthreads();
    s[t] += x;
    __syncthreads();
  }
  if (i < n) row_ptr[i] = partial[blockIdx.x] + s[t] - v;
  if (i == 0) row_ptr[n] = E;
}

// ---------------- CSR scatter ----------------
__global__ void scatter_kernel(const int* __restrict__ rowi, const int* __restrict__ coli,
                               const int* __restrict__ row_ptr, int* __restrict__ fill,
                               const float* __restrict__ dinv,
                               int* __restrict__ csr_src, float* __restrict__ csr_w, int E) {
  int e = blockIdx.x * 256 + threadIdx.x;
  if (e >= E) return;
  int s = rowi[e], d = coli[e];
  int pos = row_ptr[d] + atomicAdd(&fill[d], 1);
  csr_src[pos] = s;
  csr_w[pos] = dinv[s] * dinv[d];
}

// ---------------- f32 -> bf16 convert ----------------
__global__ void cvt_kernel(const float* __restrict__ in, bf16* __restrict__ out, int n4) {
  int i = blockIdx.x * 256 + threadIdx.x;
  if (i >= n4) return;
  float4 v = ((const float4*)in)[i];
  bf16x4 o = { (bf16)v.x, (bf16)v.y, (bf16)v.z, (bf16)v.w };
  ((bf16x4*)out)[i] = o;
}

// ---------------- W [K][N] f32 -> Wt [N][K] bf16 ----------------
__global__ void transpose_w_kernel(const float* __restrict__ W, bf16* __restrict__ Wt,
                                   int K, int N) {
  __shared__ float tile[32][33];
  int n0 = blockIdx.x * 32, k0 = blockIdx.y * 32;
  int tx = threadIdx.x, ty = threadIdx.y;  // 32 x 8
  #pragma unroll
  for (int i = ty; i < 32; i += 8) tile[i][tx] = W[(size_t)(k0 + i) * N + n0 + tx];
  __syncthreads();
  #pragma unroll
  for (int i = ty; i < 32; i += 8) Wt[(size_t)(n0 + i) * K + k0 + tx] = (bf16)tile[tx][i];
}

// ---------------- bf16 MFMA GEMM: C[M][1024] = A[M][K] * Wt[1024][K]^T ----------------
__global__ __launch_bounds__(256, 2) void gemm_bt_kernel(
    const bf16* __restrict__ A, const bf16* __restrict__ Bt,
    bf16* __restrict__ C, int M, int K) {
  __shared__ __align__(16) bf16 As[128 * 32];
  __shared__ __align__(16) bf16 Bs[128 * 32];
  const int tid = threadIdx.x;
  const int w = tid >> 6, l = tid & 63;
  const int m0 = blockIdx.y * 128, n0 = blockIdx.x * 128;
  const int wr = w >> 1, wc = w & 1;  // 2x2 wave grid, each wave 64x64

  f32x4 acc[4][4] = {};

  const int r0 = tid >> 2;            // 0..63
  const int c8 = (tid & 3) * 8;       // k offset within BK=32
  int ar0 = m0 + r0;       if (ar0 >= M) ar0 = M - 1;
  int ar1 = m0 + r0 + 64;  if (ar1 >= M) ar1 = M - 1;
  const bf16* a0 = A + (size_t)ar0 * K + c8;
  const bf16* a1 = A + (size_t)ar1 * K + c8;
  const bf16* b0 = Bt + (size_t)(n0 + r0) * K + c8;
  const bf16* b1 = Bt + (size_t)(n0 + r0 + 64) * K + c8;
  bf16* asw = As + w * 512;   // wave-uniform LDS dest (bytes: w*1024)
  bf16* bsw = Bs + w * 512;

  const int mrow = l & 15;
  const int kch = (l >> 4) * 8;

  for (int k = 0; k < K; k += 32) {
    load_g2l_16(a0 + k, asw);
    load_g2l_16(a1 + k, asw + 2048);
    load_g2l_16(b0 + k, bsw);
    load_g2l_16(b1 + k, bsw + 2048);
    __syncthreads();
    bf16x8 af[4], bf_[4];
    #pragma unroll
    for (int m = 0; m < 4; m++)
      af[m] = *(const bf16x8*)&As[(wr * 64 + m * 16 + mrow) * 32 + kch];
    #pragma unroll
    for (int n = 0; n < 4; n++)
      bf_[n] = *(const bf16x8*)&Bs[(wc * 64 + n * 16 + mrow) * 32 + kch];
    #pragma unroll
    for (int m = 0; m < 4; m++)
      #pragma unroll
      for (int n = 0; n < 4; n++)
        acc[m][n] = __builtin_amdgcn_mfma_f32_16x16x32_bf16(af[m], bf_[n], acc[m][n], 0, 0, 0);
    __syncthreads();
  }

  #pragma unroll
  for (int m = 0; m < 4; m++) {
    int grow = m0 + wr * 64 + m * 16 + (l >> 4) * 4;
    #pragma unroll
    for (int n = 0; n < 4; n++) {
      int gcol = n0 + wc * 64 + n * 16 + (l & 15);
      #pragma unroll
      for (int r = 0; r < 4; r++) {
        if (grow + r < M) C[(size_t)(grow + r) * HD + gcol] = (bf16)acc[m][n][r];
      }
    }
  }
}

// ---------------- per-row int8 quantization of ht ----------------
// One block per row: amax over 1024 cols -> scale = amax/127 -> int8 row.
__global__ __launch_bounds__(256) void quant_kernel(
    const bf16* __restrict__ ht, char* __restrict__ hti8, float* __restrict__ rowscale) {
  const int row = blockIdx.x;
  const int t = threadIdx.x;
  __shared__ float red[4];
  bf16x4 v = ((const bf16x4*)(ht + (size_t)row * HD))[t];
  float f0 = (float)v[0], f1 = (float)v[1], f2 = (float)v[2], f3 = (float)v[3];
  float m = fmaxf(fmaxf(fabsf(f0), fabsf(f1)), fmaxf(fabsf(f2), fabsf(f3)));
  #pragma unroll
  for (int off = 32; off; off >>= 1) m = fmaxf(m, __shfl_xor(m, off, 64));
  if ((t & 63) == 0) red[t >> 6] = m;
  __syncthreads();
  m = fmaxf(fmaxf(red[0], red[1]), fmaxf(red[2], red[3]));
  float inv = (m > 0.f) ? 127.0f / m : 0.f;
  int q0 = __float2int_rn(f0 * inv), q1 = __float2int_rn(f1 * inv);
  int q2 = __float2int_rn(f2 * inv), q3 = __float2int_rn(f3 * inv);
  uint32_t packed = ((uint32_t)(q0 & 0xff)) | ((uint32_t)(q1 & 0xff) << 8) |
                    ((uint32_t)(q2 & 0xff) << 16) | ((uint32_t)(q3 & 0xff) << 24);
  ((uint32_t*)hti8)[row * 256 + t] = packed;
  if (t == 0) rowscale[row] = (m > 0.f) ? m / 127.0f : 0.f;
}

// ---------------- fused aggregate + bias + LayerNorm + ReLU (int8 gather) ----------------
// 2 nodes per 256-thread block; each lane covers 8 cols (8 int8 = 8B loads).
__global__ __launch_bounds__(256) void agg_ln_i8_kernel(
    const char* __restrict__ hti8, const float* __restrict__ rowscale,
    const int* __restrict__ row_ptr,
    const int* __restrict__ csr_src, const float* __restrict__ csr_w,
    const float* __restrict__ dinv, const float* __restrict__ bias,
    const float* __restrict__ gamma, const float* __restrict__ beta,
    bf16* __restrict__ hout) {
  const int g = threadIdx.x >> 7;
  const int node = blockIdx.x * 2 + g;
  const int tt = threadIdx.x & 127;
  const int wid = threadIdx.x >> 6;
  __shared__ float red[4];

  // self-loop
  float dn = dinv[node];
  float wself = dn * dn * rowscale[node];
  c8x8 v = ((const c8x8*)(hti8 + (size_t)node * HD))[tt];
  float acc[8];
  #pragma unroll
  for (int j = 0; j < 8; j++) acc[j] = wself * (float)v[j];

  int e = row_ptr[node];
  const int e1 = row_ptr[node + 1];
  for (; e + 4 <= e1; e += 4) {
    int s0 = csr_src[e], s1 = csr_src[e + 1], s2 = csr_src[e + 2], s3 = csr_src[e + 3];
    float w0 = csr_w[e] * rowscale[s0];
    float w1 = csr_w[e + 1] * rowscale[s1];
    float w2 = csr_w[e + 2] * rowscale[s2];
    float w3 = csr_w[e + 3] * rowscale[s3];
    c8x8 u0 = ((const c8x8*)(hti8 + (size_t)s0 * HD))[tt];
    c8x8 u1 = ((const c8x8*)(hti8 + (size_t)s1 * HD))[tt];
    c8x8 u2 = ((const c8x8*)(hti8 + (size_t)s2 * HD))[tt];
    c8x8 u3 = ((const c8x8*)(hti8 + (size_t)s3 * HD))[tt];
    #pragma unroll
    for (int j = 0; j < 8; j++)
      acc[j] += w0 * (float)u0[j] + w1 * (float)u1[j] + w2 * (float)u2[j] + w3 * (float)u3[j];
  }
  for (; e < e1; e++) {
    int src = csr_src[e];
    float wgt = csr_w[e] * rowscale[src];
    c8x8 u = ((const c8x8*)(hti8 + (size_t)src * HD))[tt];
    #pragma unroll
    for (int j = 0; j < 8; j++) acc[j] += wgt * (float)u[j];
  }

  const float4* bias2 = (const float4*)bias;
  float4 ba = bias2[tt * 2], bb = bias2[tt * 2 + 1];
  acc[0] += ba.x; acc[1] += ba.y; acc[2] += ba.z; acc[3] += ba.w;
  acc[4] += bb.x; acc[5] += bb.y; acc[6] += bb.z; acc[7] += bb.w;

  float s = 0.f;
  #pragma unroll
  for (int j = 0; j < 8; j++) s += acc[j];
  #pragma unroll
  for (int off = 32; off; off >>= 1) s += __shfl_down(s, off, 64);
  if ((threadIdx.x & 63) == 0) red[wid] = s;
  __syncthreads();
  float mean = (red[g * 2] + red[g * 2 + 1]) * (1.0f / HD);
  __syncthreads();

  float d[8], s2 = 0.f;
  #pragma unroll
  for (int j = 0; j < 8; j++) { d[j] = acc[j] - mean; s2 += d[j] * d[j]; }
  #pragma unroll
  for (int off = 32; off; off >>= 1) s2 += __shfl_down(s2, off, 64);
  if ((threadIdx.x & 63) == 0) red[wid] = s2;
  __syncthreads();
  float var = (red[g * 2] + red[g * 2 + 1]) * (1.0f / HD);
  float rstd = rsqrtf(var + EPSV);

  const float4* gam2 = (const float4*)gamma;
  const float4* bet2 = (const float4*)beta;
  float4 g0 = gam2[tt * 2], g1 = gam2[tt * 2 + 1];
  float4 be0 = bet2[tt * 2], be1 = bet2[tt * 2 + 1];
  float gv[8] = {g0.x, g0.y, g0.z, g0.w, g1.x, g1.y, g1.z, g1.w};
  float bv[8] = {be0.x, be0.y, be0.z, be0.w, be1.x, be1.y, be1.z, be1.w};
  bf16x8 o;
  #pragma unroll
  for (int j = 0; j < 8; j++) o[j] = (bf16)fmaxf(d[j] * rstd * gv[j] + bv[j], 0.0f);
  ((bf16x8*)(hout + (size_t)node * HD))[tt] = o;
}

// ---------------- graph boundaries (batch is sorted) ----------------
__global__ void starts_kernel(const int* __restrict__ batch, int* __restrict__ start,
                              int n, int ngraph) {
  int g = blockIdx.x * blockDim.x + threadIdx.x;
  if (g > ngraph) return;
  int lo = 0, hi = n;
  while (lo < hi) {
    int mid = (lo + hi) >> 1;
    if (batch[mid] < g) lo = mid + 1; else hi = mid;
  }
  start[g] = lo;
}

// ---------------- mean-pool per graph: partial sums + atomics ----------------
#define POOL_CHUNKS 8
__global__ void pool_partial_kernel(const bf16* __restrict__ h, const int* __restrict__ start,
                                    float* __restrict__ out) {
  int g = blockIdx.y, c = blockIdx.x;
  int t = threadIdx.x;
  int s0 = start[g], s1 = start[g + 1];
  int len = s1 - s0;
  int per = (len + POOL_CHUNKS - 1) / POOL_CHUNKS;
  int a = s0 + c * per;
  int b = min(a + per, s1);
  if (a >= b) return;
  f32x4 acc = {0.f, 0.f, 0.f, 0.f};
  for (int n = a; n < b; n++) {
    bf16x4 v = ((const bf16x4*)(h + (size_t)n * HD))[t];
    acc[0] += (float)v[0]; acc[1] += (float)v[1];
    acc[2] += (float)v[2]; acc[3] += (float)v[3];
  }
  float* o = out + (size_t)g * HD + t * 4;
  atomicAdd(o + 0, acc[0]);
  atomicAdd(o + 1, acc[1]);
  atomicAdd(o + 2, acc[2]);
  atomicAdd(o + 3, acc[3]);
}

__global__ void pool_div_kernel(float* __restrict__ out, const int* __restrict__ start) {
  int i = blockIdx.x * 256 + threadIdx.x;
  if (i >= NG * HD) return;
  int g = i >> 10;
  float c = (float)max(start[g + 1] - start[g], 1);
  out[i] = out[i] / c;
}

extern "C" void kernel_launch(void* const* d_in, const int* in_sizes, int n_in,
                              void* d_out, int out_size, void* d_ws, size_t ws_size,
                              hipStream_t stream) {
  const float* x      = (const float*)d_in[0];
  const int*   eidx   = (const int*)d_in[1];
  const int*   batch  = (const int*)d_in[2];
  const float* W0     = (const float*)d_in[3];
  const float* b0     = (const float*)d_in[4];
  const float* Ws     = (const float*)d_in[5];
  const float* bs     = (const float*)d_in[6];
  const float* gammas = (const float*)d_in[7];
  const float* betas  = (const float*)d_in[8];
  float* out = (float*)d_out;

  const int* erow = eidx;        // sources
  const int* ecol = eidx + NE;   // targets (aggregation index)

  char* ws = (char*)d_ws;
  size_t off = 0;
  auto alloc = [&](size_t bytes) {
    void* p = ws + off;
    off = (off + bytes + 255) & ~(size_t)255;
    return p;
  };
  int*   cnt     = (int*)alloc((size_t)NN * 4);       // dead after scan -> reused as rowscale
  int*   row_ptr = (int*)alloc((size_t)(NN + 1) * 4);
  int*   fill    = (int*)alloc((size_t)NN * 4);
  int*   partial = (int*)alloc(256 * 4);
  float* dinv    = (float*)alloc((size_t)NN * 4);
  int*   csr_src = (int*)alloc((size_t)NE * 4);
  float* csr_w   = (float*)alloc((size_t)NE * 4);
  bf16*  Wt      = (bf16*)alloc((size_t)HD * HD * 2);
  bf16*  hbuf    = (bf16*)alloc((size_t)NN * HD * 2);
  bf16*  htbuf   = (bf16*)alloc((size_t)NN * HD * 2);
  int*   gstart  = (int*)alloc(65 * 4);
  float* rowscale = (float*)cnt;   // alias: cnt is dead once row_ptr is built

  hipMemsetAsync(cnt, 0, (size_t)NN * 4, stream);
  hipMemsetAsync(fill, 0, (size_t)NN * 4, stream);
  hipMemsetAsync(out, 0, (size_t)NG * HD * 4, stream);

  hist_kernel<<<(NE + 255) / 256, 256, 0, stream>>>(ecol, cnt, NE);
  dinv_kernel<<<(NN + 255) / 256, 256, 0, stream>>>(cnt, dinv, NN);
  int nb = (NN + 255) / 256;  // 196
  scan_partial_kernel<<<nb, 256, 0, stream>>>(cnt, partial, NN);
  scan_scan_kernel<<<1, 256, 0, stream>>>(partial, nb);
  scan_final_kernel<<<nb, 256, 0, stream>>>(cnt, partial, row_ptr, NN, NE);
  scatter_kernel<<<(NE + 255) / 256, 256, 0, stream>>>(erow, ecol, row_ptr, fill, dinv,
                                                       csr_src, csr_w, NE);
  starts_kernel<<<1, 128, 0, stream>>>(batch, gstart, NN, NG);

  // Ping-pong buffers: A = layer input (bf16), B = GEMM output (bf16).
  // quant writes i8 into A's region (A bf16 dead after GEMM);
  // agg gathers A_i8 and writes bf16 into B (B bf16 dead after quant);
  // next layer swaps A<->B.
  bf16* A = hbuf;
  bf16* B = htbuf;

  cvt_kernel<<<(NN * FIN / 4 + 255) / 256, 256, 0, stream>>>(x, A, NN * FIN / 4);

  for (int L = 0; L < 4; L++) {
    int K = (L == 0) ? FIN : HD;
    const float* W    = (L == 0) ? W0 : Ws + (size_t)(L - 1) * HD * HD;
    const float* bias = (L == 0) ? b0 : bs + (size_t)(L - 1) * HD;
    transpose_w_kernel<<<dim3(HD / 32, K / 32), dim3(32, 8), 0, stream>>>(W, Wt, K, HD);
    gemm_bt_kernel<<<dim3(HD / 128, (NN + 127) / 128), 256, 0, stream>>>(A, Wt, B, NN, K);
    quant_kernel<<<NN, 256, 0, stream>>>(B, (char*)A, rowscale);
    agg_ln_i8_kernel<<<NN / 2, 256, 0, stream>>>((const char*)A, rowscale, row_ptr,
                                                 csr_src, csr_w, dinv, bias,
                                                 gammas + (size_t)L * HD,
                                                 betas + (size_t)L * HD, B);
    bf16* tmp = A; A = B; B = tmp;
  }

  // final features are in A after the last swap
  pool_partial_kernel<<<dim3(POOL_CHUNKS, NG), 256, 0, stream>>>(A, gstart, out);
  pool_div_kernel<<<(NG * HD + 255) / 256, 256, 0, stream>>>(out, gstart);
}

// Round 6
// 1749.381 us; speedup vs baseline: 1.5219x; 1.0479x over previous
//
#include <hip/hip_runtime.h>
#include <hip/hip_bf16.h>
#include <stdint.h>

#define NN 50000
#define NE 1600000
#define NG 64
#define FIN 256
#define HD 1024
#define EPSV 1e-5f

typedef __bf16 bf16;
typedef __bf16 bf16x4 __attribute__((ext_vector_type(4)));
typedef __bf16 bf16x8 __attribute__((ext_vector_type(8)));
typedef float f32x4 __attribute__((ext_vector_type(4)));

typedef const __attribute__((address_space(1))) void* gptr_as1;
typedef __attribute__((address_space(3))) void* lptr_as3;

__device__ __forceinline__ void load_g2l_16(const void* g, const void* l) {
  __builtin_amdgcn_global_load_lds((gptr_as1)(uintptr_t)g,
                                   (lptr_as3)(uint32_t)(uintptr_t)l, 16, 0, 0);
}

// ---------------- degree histogram / dinv ----------------
__global__ void hist_kernel(const int* __restrict__ col, int* __restrict__ cnt, int E) {
  int e = blockIdx.x * 256 + threadIdx.x;
  if (e < E) atomicAdd(&cnt[col[e]], 1);
}

__global__ void dinv_kernel(const int* __restrict__ cnt, float* __restrict__ dinv, int n) {
  int i = blockIdx.x * 256 + threadIdx.x;
  if (i < n) dinv[i] = rsqrtf((float)(cnt[i] + 1));  // +1 self-loop
}

// ---------------- exclusive scan (3-phase) ----------------
__global__ void scan_partial_kernel(const int* __restrict__ cnt, int* __restrict__ partial, int n) {
  __shared__ int red[4];
  int i = blockIdx.x * 256 + threadIdx.x;
  int v = (i < n) ? cnt[i] : 0;
  #pragma unroll
  for (int off = 32; off; off >>= 1) v += __shfl_down(v, off, 64);
  if ((threadIdx.x & 63) == 0) red[threadIdx.x >> 6] = v;
  __syncthreads();
  if (threadIdx.x == 0) partial[blockIdx.x] = red[0] + red[1] + red[2] + red[3];
}

__global__ void scan_scan_kernel(int* __restrict__ partial, int nb) {
  __shared__ int s[256];
  int t = threadIdx.x;
  int v = (t < nb) ? partial[t] : 0;
  s[t] = v;
  __syncthreads();
  for (int off = 1; off < 256; off <<= 1) {
    int x = (t >= off) ? s[t - off] : 0;
    __syncthreads();
    s[t] += x;
    __syncthreads();
  }
  if (t < nb) partial[t] = s[t] - v;  // exclusive
}

__global__ void scan_final_kernel(const int* __restrict__ cnt, const int* __restrict__ partial,
                                  int* __restrict__ row_ptr, int n, int E) {
  __shared__ int s[256];
  int t = threadIdx.x;
  int i = blockIdx.x * 256 + t;
  int v = (i < n) ? cnt[i] : 0;
  s[t] = v;
  __syncthreads();
  for (int off = 1; off < 256; off <<= 1) {
    int x = (t >= off) ? s[t - off] : 0;
    __syncthreads();
    s[t] += x;
    __syncthreads();
  }
  if (i < n) row_ptr[i] = partial[blockIdx.x] + s[t] - v;
  if (i == 0) row_ptr[n] = E;
}

// ---------------- CSR scatter ----------------
__global__ void scatter_kernel(const int* __restrict__ rowi, const int* __restrict__ coli,
                               const int* __restrict__ row_ptr, int* __restrict__ fill,
                               const float* __restrict__ dinv,
                               int* __restrict__ csr_src, float* __restrict__ csr_w, int E) {
  int e = blockIdx.x * 256 + threadIdx.x;
  if (e >= E) return;
  int s = rowi[e], d = coli[e];
  int pos = row_ptr[d] + atomicAdd(&fill[d], 1);
  csr_src[pos] = s;
  csr_w[pos] = dinv[s] * dinv[d];
}

// ---------------- f32 -> bf16 convert ----------------
__global__ void cvt_kernel(const float* __restrict__ in, bf16* __restrict__ out, int n4) {
  int i = blockIdx.x * 256 + threadIdx.x;
  if (i >= n4) return;
  float4 v = ((const float4*)in)[i];
  bf16x4 o = { (bf16)v.x, (bf16)v.y, (bf16)v.z, (bf16)v.w };
  ((bf16x4*)out)[i] = o;
}

// ---------------- W [K][N] f32 -> Wt [N][K] bf16 ----------------
__global__ void transpose_w_kernel(const float* __restrict__ W, bf16* __restrict__ Wt,
                                   int K, int N) {
  __shared__ float tile[32][33];
  int n0 = blockIdx.x * 32, k0 = blockIdx.y * 32;
  int tx = threadIdx.x, ty = threadIdx.y;  // 32 x 8
  #pragma unroll
  for (int i = ty; i < 32; i += 8) tile[i][tx] = W[(size_t)(k0 + i) * N + n0 + tx];
  __syncthreads();
  #pragma unroll
  for (int i = ty; i < 32; i += 8) Wt[(size_t)(n0 + i) * K + k0 + tx] = (bf16)tile[tx][i];
}

// ---------------- bf16 MFMA GEMM: C[M][1024] = A[M][K] * Wt[1024][K]^T ----------------
// 2-phase prefetch: double-buffered LDS, stage(next) issued before compute(cur),
// ONE barrier per K-step. XCD-aware tile swizzle: each XCD gets a contiguous
// run of m-tiles so the A panel is fetched once per XCD-L2 (not 8x).
__global__ __launch_bounds__(256, 2) void gemm_bt_kernel(
    const bf16* __restrict__ A, const bf16* __restrict__ Bt,
    bf16* __restrict__ C, int M, int K) {
  __shared__ __align__(16) bf16 As[2][128 * 32];
  __shared__ __align__(16) bf16 Bs[2][128 * 32];
  const int tid = threadIdx.x;
  const int w = tid >> 6, l = tid & 63;

  // swizzle: physical o -> logical lid; XCD (o%8) owns lid in [k*nwg/8,(k+1)*nwg/8)
  const int nwg = gridDim.x;            // nmt*8, divisible by 8
  const int o = blockIdx.x;
  const int lid = (o & 7) * (nwg >> 3) + (o >> 3);
  const int m0 = (lid >> 3) * 128, n0 = (lid & 7) * 128;
  const int wr = w >> 1, wc = w & 1;    // 2x2 wave grid, each wave 64x64

  f32x4 acc[4][4] = {};

  const int r0 = tid >> 2;              // 0..63
  const int c8 = (tid & 3) * 8;         // k offset within BK=32
  int ar0 = m0 + r0;       if (ar0 >= M) ar0 = M - 1;
  int ar1 = m0 + r0 + 64;  if (ar1 >= M) ar1 = M - 1;
  const bf16* a0 = A + (size_t)ar0 * K + c8;
  const bf16* a1 = A + (size_t)ar1 * K + c8;
  const bf16* b0 = Bt + (size_t)(n0 + r0) * K + c8;
  const bf16* b1 = Bt + (size_t)(n0 + r0 + 64) * K + c8;

  const int mrow = l & 15;
  const int kch = (l >> 4) * 8;

  auto stage = [&](int b, int k) {
    bf16* asw = &As[b][w * 512];   // wave-uniform base; lane writes base+lane*16B
    bf16* bsw = &Bs[b][w * 512];
    load_g2l_16(a0 + k, asw);
    load_g2l_16(a1 + k, asw + 2048);
    load_g2l_16(b0 + k, bsw);
    load_g2l_16(b1 + k, bsw + 2048);
  };

  const int nit = K >> 5;
  stage(0, 0);
  __syncthreads();                      // drains vmcnt(0): buf0 ready

  int cur = 0;
  for (int t = 0; t < nit; ++t) {
    if (t + 1 < nit) stage(cur ^ 1, (t + 1) << 5);  // prefetch overlaps compute
    bf16x8 af[4], bf_[4];
    #pragma unroll
    for (int m = 0; m < 4; m++)
      af[m] = *(const bf16x8*)&As[cur][(wr * 64 + m * 16 + mrow) * 32 + kch];
    #pragma unroll
    for (int n = 0; n < 4; n++)
      bf_[n] = *(const bf16x8*)&Bs[cur][(wc * 64 + n * 16 + mrow) * 32 + kch];
    #pragma unroll
    for (int m = 0; m < 4; m++)
      #pragma unroll
      for (int n = 0; n < 4; n++)
        acc[m][n] = __builtin_amdgcn_mfma_f32_16x16x32_bf16(af[m], bf_[n], acc[m][n], 0, 0, 0);
    __syncthreads();                    // one barrier/iter: drains vmcnt+lgkm
    cur ^= 1;
  }

  #pragma unroll
  for (int m = 0; m < 4; m++) {
    int grow = m0 + wr * 64 + m * 16 + (l >> 4) * 4;
    #pragma unroll
    for (int n = 0; n < 4; n++) {
      int gcol = n0 + wc * 64 + n * 16 + (l & 15);
      #pragma unroll
      for (int r = 0; r < 4; r++) {
        if (grow + r < M) C[(size_t)(grow + r) * HD + gcol] = (bf16)acc[m][n][r];
      }
    }
  }
}

// ---------------- per-row quantization of ht -> biased uint8 ----------------
// u = round(f/scale) + 128, scale = amax/127. Stored unsigned so the agg kernel
// can use single-inst v_cvt_f32_ubyteN; bias corrected via sum-of-weights.
__global__ __launch_bounds__(256) void quant_kernel(
    const bf16* __restrict__ ht, uint8_t* __restrict__ htu8, float* __restrict__ rowscale) {
  const int row = blockIdx.x;
  const int t = threadIdx.x;
  __shared__ float red[4];
  bf16x4 v = ((const bf16x4*)(ht + (size_t)row * HD))[t];
  float f0 = (float)v[0], f1 = (float)v[1], f2 = (float)v[2], f3 = (float)v[3];
  float m = fmaxf(fmaxf(fabsf(f0), fabsf(f1)), fmaxf(fabsf(f2), fabsf(f3)));
  #pragma unroll
  for (int off = 32; off; off >>= 1) m = fmaxf(m, __shfl_xor(m, off, 64));
  if ((t & 63) == 0) red[t >> 6] = m;
  __syncthreads();
  m = fmaxf(fmaxf(red[0], red[1]), fmaxf(red[2], red[3]));
  float inv = (m > 0.f) ? 127.0f / m : 0.f;
  int q0 = __float2int_rn(f0 * inv) + 128, q1 = __float2int_rn(f1 * inv) + 128;
  int q2 = __float2int_rn(f2 * inv) + 128, q3 = __float2int_rn(f3 * inv) + 128;
  uint32_t packed = ((uint32_t)(q0 & 0xff)) | ((uint32_t)(q1 & 0xff) << 8) |
                    ((uint32_t)(q2 & 0xff) << 16) | ((uint32_t)(q3 & 0xff) << 24);
  ((uint32_t*)htu8)[row * 256 + t] = packed;
  if (t == 0) rowscale[row] = (m > 0.f) ? m / 127.0f : 0.f;
}

// ---------------- fused aggregate + bias + LayerNorm + ReLU (u8 gather) ----------------
// 2 nodes per 256-thread block; each lane covers 8 cols (8B loads).
// sum(w*(u-128)) = sum(w*u) - 128*sum(w): track sw, correct once at the end.
__device__ __forceinline__ void acc_u8(float acc[8], float& sw, float w, uint2 d) {
  sw += w;
  acc[0] += w * (float)(d.x & 0xffu);
  acc[1] += w * (float)((d.x >> 8) & 0xffu);
  acc[2] += w * (float)((d.x >> 16) & 0xffu);
  acc[3] += w * (float)(d.x >> 24);
  acc[4] += w * (float)(d.y & 0xffu);
  acc[5] += w * (float)((d.y >> 8) & 0xffu);
  acc[6] += w * (float)((d.y >> 16) & 0xffu);
  acc[7] += w * (float)(d.y >> 24);
}

__global__ __launch_bounds__(256) void agg_ln_u8_kernel(
    const uint8_t* __restrict__ htu8, const float* __restrict__ rowscale,
    const int* __restrict__ row_ptr,
    const int* __restrict__ csr_src, const float* __restrict__ csr_w,
    const float* __restrict__ dinv, const float* __restrict__ bias,
    const float* __restrict__ gamma, const float* __restrict__ beta,
    bf16* __restrict__ hout) {
  const int g = threadIdx.x >> 7;
  const int node = blockIdx.x * 2 + g;
  const int tt = threadIdx.x & 127;
  const int wid = threadIdx.x >> 6;
  __shared__ float red[4];

  float acc[8] = {};
  float sw = 0.f;

  // self-loop
  float dn = dinv[node];
  float wself = dn * dn * rowscale[node];
  acc_u8(acc, sw, wself, ((const uint2*)(htu8 + (size_t)node * HD))[tt]);

  int e = row_ptr[node];
  const int e1 = row_ptr[node + 1];
  for (; e + 4 <= e1; e += 4) {
    int s0 = csr_src[e], s1 = csr_src[e + 1], s2 = csr_src[e + 2], s3 = csr_src[e + 3];
    float w0 = csr_w[e] * rowscale[s0];
    float w1 = csr_w[e + 1] * rowscale[s1];
    float w2 = csr_w[e + 2] * rowscale[s2];
    float w3 = csr_w[e + 3] * rowscale[s3];
    uint2 d0 = ((const uint2*)(htu8 + (size_t)s0 * HD))[tt];
    uint2 d1 = ((const uint2*)(htu8 + (size_t)s1 * HD))[tt];
    uint2 d2 = ((const uint2*)(htu8 + (size_t)s2 * HD))[tt];
    uint2 d3 = ((const uint2*)(htu8 + (size_t)s3 * HD))[tt];
    acc_u8(acc, sw, w0, d0);
    acc_u8(acc, sw, w1, d1);
    acc_u8(acc, sw, w2, d2);
    acc_u8(acc, sw, w3, d3);
  }
  for (; e < e1; e++) {
    int src = csr_src[e];
    float wgt = csr_w[e] * rowscale[src];
    acc_u8(acc, sw, wgt, ((const uint2*)(htu8 + (size_t)src * HD))[tt]);
  }

  // bias-correction for the +128 offset, then layer bias
  const float4* bias2 = (const float4*)bias;
  float4 ba = bias2[tt * 2], bb = bias2[tt * 2 + 1];
  float c128 = 128.0f * sw;
  acc[0] += ba.x - c128; acc[1] += ba.y - c128; acc[2] += ba.z - c128; acc[3] += ba.w - c128;
  acc[4] += bb.x - c128; acc[5] += bb.y - c128; acc[6] += bb.z - c128; acc[7] += bb.w - c128;

  float s = 0.f;
  #pragma unroll
  for (int j = 0; j < 8; j++) s += acc[j];
  #pragma unroll
  for (int off = 32; off; off >>= 1) s += __shfl_down(s, off, 64);
  if ((threadIdx.x & 63) == 0) red[wid] = s;
  __syncthreads();
  float mean = (red[g * 2] + red[g * 2 + 1]) * (1.0f / HD);
  __syncthreads();

  float d[8], s2 = 0.f;
  #pragma unroll
  for (int j = 0; j < 8; j++) { d[j] = acc[j] - mean; s2 += d[j] * d[j]; }
  #pragma unroll
  for (int off = 32; off; off >>= 1) s2 += __shfl_down(s2, off, 64);
  if ((threadIdx.x & 63) == 0) red[wid] = s2;
  __syncthreads();
  float var = (red[g * 2] + red[g * 2 + 1]) * (1.0f / HD);
  float rstd = rsqrtf(var + EPSV);

  const float4* gam2 = (const float4*)gamma;
  const float4* bet2 = (const float4*)beta;
  float4 g0 = gam2[tt * 2], g1 = gam2[tt * 2 + 1];
  float4 be0 = bet2[tt * 2], be1 = bet2[tt * 2 + 1];
  float gv[8] = {g0.x, g0.y, g0.z, g0.w, g1.x, g1.y, g1.z, g1.w};
  float bv[8] = {be0.x, be0.y, be0.z, be0.w, be1.x, be1.y, be1.z, be1.w};
  bf16x8 o;
  #pragma unroll
  for (int j = 0; j < 8; j++) o[j] = (bf16)fmaxf(d[j] * rstd * gv[j] + bv[j], 0.0f);
  ((bf16x8*)(hout + (size_t)node * HD))[tt] = o;
}

// ---------------- graph boundaries (batch is sorted) ----------------
__global__ void starts_kernel(const int* __restrict__ batch, int* __restrict__ start,
                              int n, int ngraph) {
  int g = blockIdx.x * blockDim.x + threadIdx.x;
  if (g > ngraph) return;
  int lo = 0, hi = n;
  while (lo < hi) {
    int mid = (lo + hi) >> 1;
    if (batch[mid] < g) lo = mid + 1; else hi = mid;
  }
  start[g] = lo;
}

// ---------------- mean-pool per graph: partial sums + atomics ----------------
#define POOL_CHUNKS 8
__global__ void pool_partial_kernel(const bf16* __restrict__ h, const int* __restrict__ start,
                                    float* __restrict__ out) {
  int g = blockIdx.y, c = blockIdx.x;
  int t = threadIdx.x;
  int s0 = start[g], s1 = start[g + 1];
  int len = s1 - s0;
  int per = (len + POOL_CHUNKS - 1) / POOL_CHUNKS;
  int a = s0 + c * per;
  int b = min(a + per, s1);
  if (a >= b) return;
  f32x4 acc = {0.f, 0.f, 0.f, 0.f};
  for (int n = a; n < b; n++) {
    bf16x4 v = ((const bf16x4*)(h + (size_t)n * HD))[t];
    acc[0] += (float)v[0]; acc[1] += (float)v[1];
    acc[2] += (float)v[2]; acc[3] += (float)v[3];
  }
  float* o = out + (size_t)g * HD + t * 4;
  atomicAdd(o + 0, acc[0]);
  atomicAdd(o + 1, acc[1]);
  atomicAdd(o + 2, acc[2]);
  atomicAdd(o + 3, acc[3]);
}

__global__ void pool_div_kernel(float* __restrict__ out, const int* __restrict__ start) {
  int i = blockIdx.x * 256 + threadIdx.x;
  if (i >= NG * HD) return;
  int g = i >> 10;
  float c = (float)max(start[g + 1] - start[g], 1);
  out[i] = out[i] / c;
}

extern "C" void kernel_launch(void* const* d_in, const int* in_sizes, int n_in,
                              void* d_out, int out_size, void* d_ws, size_t ws_size,
                              hipStream_t stream) {
  const float* x      = (const float*)d_in[0];
  const int*   eidx   = (const int*)d_in[1];
  const int*   batch  = (const int*)d_in[2];
  const float* W0     = (const float*)d_in[3];
  const float* b0     = (const float*)d_in[4];
  const float* Ws     = (const float*)d_in[5];
  const float* bs     = (const float*)d_in[6];
  const float* gammas = (const float*)d_in[7];
  const float* betas  = (const float*)d_in[8];
  float* out = (float*)d_out;

  const int* erow = eidx;        // sources
  const int* ecol = eidx + NE;   // targets (aggregation index)

  char* ws = (char*)d_ws;
  size_t off = 0;
  auto alloc = [&](size_t bytes) {
    void* p = ws + off;
    off = (off + bytes + 255) & ~(size_t)255;
    return p;
  };
  int*   cnt     = (int*)alloc((size_t)NN * 4);       // dead after scan -> reused as rowscale
  int*   row_ptr = (int*)alloc((size_t)(NN + 1) * 4);
  int*   fill    = (int*)alloc((size_t)NN * 4);
  int*   partial = (int*)alloc(256 * 4);
  float* dinv    = (float*)alloc((size_t)NN * 4);
  int*   csr_src = (int*)alloc((size_t)NE * 4);
  float* csr_w   = (float*)alloc((size_t)NE * 4);
  bf16*  Wt      = (bf16*)alloc((size_t)HD * HD * 2);
  bf16*  hbuf    = (bf16*)alloc((size_t)NN * HD * 2);
  bf16*  htbuf   = (bf16*)alloc((size_t)NN * HD * 2);
  int*   gstart  = (int*)alloc(65 * 4);
  float* rowscale = (float*)cnt;   // alias: cnt is dead once row_ptr is built

  hipMemsetAsync(cnt, 0, (size_t)NN * 4, stream);
  hipMemsetAsync(fill, 0, (size_t)NN * 4, stream);
  hipMemsetAsync(out, 0, (size_t)NG * HD * 4, stream);

  hist_kernel<<<(NE + 255) / 256, 256, 0, stream>>>(ecol, cnt, NE);
  dinv_kernel<<<(NN + 255) / 256, 256, 0, stream>>>(cnt, dinv, NN);
  int nb = (NN + 255) / 256;  // 196
  scan_partial_kernel<<<nb, 256, 0, stream>>>(cnt, partial, NN);
  scan_scan_kernel<<<1, 256, 0, stream>>>(partial, nb);
  scan_final_kernel<<<nb, 256, 0, stream>>>(cnt, partial, row_ptr, NN, NE);
  scatter_kernel<<<(NE + 255) / 256, 256, 0, stream>>>(erow, ecol, row_ptr, fill, dinv,
                                                       csr_src, csr_w, NE);
  starts_kernel<<<1, 128, 0, stream>>>(batch, gstart, NN, NG);

  // Ping-pong: A = layer input (bf16), B = GEMM output (bf16).
  // quant writes u8 into A's region (A bf16 dead after GEMM);
  // agg gathers A_u8 and writes bf16 into B (B bf16 dead after quant); swap.
  bf16* A = hbuf;
  bf16* B = htbuf;

  cvt_kernel<<<(NN * FIN / 4 + 255) / 256, 256, 0, stream>>>(x, A, NN * FIN / 4);

  const int nmt = (NN + 127) / 128;  // 391 m-tiles
  for (int L = 0; L < 4; L++) {
    int K = (L == 0) ? FIN : HD;
    const float* W    = (L == 0) ? W0 : Ws + (size_t)(L - 1) * HD * HD;
    const float* bias = (L == 0) ? b0 : bs + (size_t)(L - 1) * HD;
    transpose_w_kernel<<<dim3(HD / 32, K / 32), dim3(32, 8), 0, stream>>>(W, Wt, K, HD);
    gemm_bt_kernel<<<nmt * 8, 256, 0, stream>>>(A, Wt, B, NN, K);
    quant_kernel<<<NN, 256, 0, stream>>>(B, (uint8_t*)A, rowscale);
    agg_ln_u8_kernel<<<NN / 2, 256, 0, stream>>>((const uint8_t*)A, rowscale, row_ptr,
                                                 csr_src, csr_w, dinv, bias,
                                                 gammas + (size_t)L * HD,
                                                 betas + (size_t)L * HD, B);
    bf16* tmp = A; A = B; B = tmp;
  }

  // final features are in A after the last swap
  pool_partial_kernel<<<dim3(POOL_CHUNKS, NG), 256, 0, stream>>>(A, gstart, out);
  pool_div_kernel<<<(NG * HD + 255) / 256, 256, 0, stream>>>(out, gstart);
}

// Round 8
// 1681.337 us; speedup vs baseline: 1.5835x; 1.0405x over previous
//
#include <hip/hip_runtime.h>
#include <hip/hip_bf16.h>
#include <stdint.h>

#define NN 50000
#define NE 1600000
#define NG 64
#define FIN 256
#define HD 1024
#define EPSV 1e-5f

typedef __bf16 bf16;
typedef __bf16 bf16x4 __attribute__((ext_vector_type(4)));
typedef __bf16 bf16x8 __attribute__((ext_vector_type(8)));
typedef float f32x4 __attribute__((ext_vector_type(4)));

typedef const __attribute__((address_space(1))) void* gptr_as1;
typedef __attribute__((address_space(3))) void* lptr_as3;

__device__ __forceinline__ void load_g2l_16(const void* g, const void* l) {
  __builtin_amdgcn_global_load_lds((gptr_as1)(uintptr_t)g,
                                   (lptr_as3)(uint32_t)(uintptr_t)l, 16, 0, 0);
}

// ---------------- degree histogram / dinv ----------------
__global__ void hist_kernel(const int* __restrict__ col, int* __restrict__ cnt, int E) {
  int e = blockIdx.x * 256 + threadIdx.x;
  if (e < E) atomicAdd(&cnt[col[e]], 1);
}

__global__ void dinv_kernel(const int* __restrict__ cnt, float* __restrict__ dinv, int n) {
  int i = blockIdx.x * 256 + threadIdx.x;
  if (i < n) dinv[i] = rsqrtf((float)(cnt[i] + 1));  // +1 self-loop
}

// ---------------- exclusive scan (3-phase) ----------------
__global__ void scan_partial_kernel(const int* __restrict__ cnt, int* __restrict__ partial, int n) {
  __shared__ int red[4];
  int i = blockIdx.x * 256 + threadIdx.x;
  int v = (i < n) ? cnt[i] : 0;
  #pragma unroll
  for (int off = 32; off; off >>= 1) v += __shfl_down(v, off, 64);
  if ((threadIdx.x & 63) == 0) red[threadIdx.x >> 6] = v;
  __syncthreads();
  if (threadIdx.x == 0) partial[blockIdx.x] = red[0] + red[1] + red[2] + red[3];
}

__global__ void scan_scan_kernel(int* __restrict__ partial, int nb) {
  __shared__ int s[256];
  int t = threadIdx.x;
  int v = (t < nb) ? partial[t] : 0;
  s[t] = v;
  __syncthreads();
  for (int off = 1; off < 256; off <<= 1) {
    int x = (t >= off) ? s[t - off] : 0;
    __syncthreads();
    s[t] += x;
    __syncthreads();
  }
  if (t < nb) partial[t] = s[t] - v;  // exclusive
}

__global__ void scan_final_kernel(const int* __restrict__ cnt, const int* __restrict__ partial,
                                  int* __restrict__ row_ptr, int n, int E) {
  __shared__ int s[256];
  int t = threadIdx.x;
  int i = blockIdx.x * 256 + t;
  int v = (i < n) ? cnt[i] : 0;
  s[t] = v;
  __syncthreads();
  for (int off = 1; off < 256; off <<= 1) {
    int x = (t >= off) ? s[t - off] : 0;
    __syncthreads();
    s[t] += x;
    __syncthreads();
  }
  if (i < n) row_ptr[i] = partial[blockIdx.x] + s[t] - v;
  if (i == 0) row_ptr[n] = E;
}

// ---------------- CSR scatter ----------------
__global__ void scatter_kernel(const int* __restrict__ rowi, const int* __restrict__ coli,
                               const int* __restrict__ row_ptr, int* __restrict__ fill,
                               const float* __restrict__ dinv,
                               int* __restrict__ csr_src, float* __restrict__ csr_w, int E) {
  int e = blockIdx.x * 256 + threadIdx.x;
  if (e >= E) return;
  int s = rowi[e], d = coli[e];
  int pos = row_ptr[d] + atomicAdd(&fill[d], 1);
  csr_src[pos] = s;
  csr_w[pos] = dinv[s] * dinv[d];
}

// ---------------- f32 -> bf16 convert ----------------
__global__ void cvt_kernel(const float* __restrict__ in, bf16* __restrict__ out, int n4) {
  int i = blockIdx.x * 256 + threadIdx.x;
  if (i >= n4) return;
  float4 v = ((const float4*)in)[i];
  bf16x4 o = { (bf16)v.x, (bf16)v.y, (bf16)v.z, (bf16)v.w };
  ((bf16x4*)out)[i] = o;
}

// ---------------- W [K][N] f32 -> Wt [N][K] bf16 ----------------
__global__ void transpose_w_kernel(const float* __restrict__ W, bf16* __restrict__ Wt,
                                   int K, int N) {
  __shared__ float tile[32][33];
  int n0 = blockIdx.x * 32, k0 = blockIdx.y * 32;
  int tx = threadIdx.x, ty = threadIdx.y;  // 32 x 8
  #pragma unroll
  for (int i = ty; i < 32; i += 8) tile[i][tx] = W[(size_t)(k0 + i) * N + n0 + tx];
  __syncthreads();
  #pragma unroll
  for (int i = ty; i < 32; i += 8) Wt[(size_t)(n0 + i) * K + k0 + tx] = (bf16)tile[tx][i];
}

// ---------------- bf16 MFMA GEMM + fused u8-quant epilogue ----------------
// 2-phase prefetch + XCD swizzle (proven round 6). Epilogue: per (row,
// 128-col-block) amax -> scales[row*8+cb], writes biased-u8 C8 directly
// (no separate bf16 C / quant pass).
__global__ __launch_bounds__(256, 2) void gemm_bt_q8_kernel(
    const bf16* __restrict__ A, const bf16* __restrict__ Bt,
    uint8_t* __restrict__ C8, float* __restrict__ scales, int M, int K) {
  __shared__ __align__(16) bf16 As[2][128 * 32];
  __shared__ __align__(16) bf16 Bs[2][128 * 32];
  __shared__ float smax[2][128];
  const int tid = threadIdx.x;
  const int w = tid >> 6, l = tid & 63;

  const int nwg = gridDim.x;            // nmt*8, divisible by 8
  const int o = blockIdx.x;
  const int lid = (o & 7) * (nwg >> 3) + (o >> 3);
  const int m0 = (lid >> 3) * 128, n0 = (lid & 7) * 128;
  const int cb = lid & 7;               // col-block id (HD/128 = 8)
  const int wr = w >> 1, wc = w & 1;    // 2x2 wave grid, each wave 64x64

  f32x4 acc[4][4] = {};

  const int r0 = tid >> 2;              // 0..63
  const int c8 = (tid & 3) * 8;         // k offset within BK=32
  int ar0 = m0 + r0;       if (ar0 >= M) ar0 = M - 1;
  int ar1 = m0 + r0 + 64;  if (ar1 >= M) ar1 = M - 1;
  const bf16* a0 = A + (size_t)ar0 * K + c8;
  const bf16* a1 = A + (size_t)ar1 * K + c8;
  const bf16* b0 = Bt + (size_t)(n0 + r0) * K + c8;
  const bf16* b1 = Bt + (size_t)(n0 + r0 + 64) * K + c8;

  const int mrow = l & 15;
  const int kch = (l >> 4) * 8;

  auto stage = [&](int b, int k) {
    bf16* asw = &As[b][w * 512];
    bf16* bsw = &Bs[b][w * 512];
    load_g2l_16(a0 + k, asw);
    load_g2l_16(a1 + k, asw + 2048);
    load_g2l_16(b0 + k, bsw);
    load_g2l_16(b1 + k, bsw + 2048);
  };

  const int nit = K >> 5;
  stage(0, 0);
  __syncthreads();

  int cur = 0;
  for (int t = 0; t < nit; ++t) {
    if (t + 1 < nit) stage(cur ^ 1, (t + 1) << 5);
    bf16x8 af[4], bf_[4];
    #pragma unroll
    for (int m = 0; m < 4; m++)
      af[m] = *(const bf16x8*)&As[cur][(wr * 64 + m * 16 + mrow) * 32 + kch];
    #pragma unroll
    for (int n = 0; n < 4; n++)
      bf_[n] = *(const bf16x8*)&Bs[cur][(wc * 64 + n * 16 + mrow) * 32 + kch];
    #pragma unroll
    for (int m = 0; m < 4; m++)
      #pragma unroll
      for (int n = 0; n < 4; n++)
        acc[m][n] = __builtin_amdgcn_mfma_f32_16x16x32_bf16(af[m], bf_[n], acc[m][n], 0, 0, 0);
    __syncthreads();
    cur ^= 1;
  }

  // ---- epilogue: per-row amax over this block's 128 cols ----
  // lane holds rows m*16+(l>>4)*4+r, cols n*16+(l&15) of its wave's 64x64 tile
  float pmax[4][4];
  #pragma unroll
  for (int m = 0; m < 4; m++)
    #pragma unroll
    for (int r = 0; r < 4; r++) {
      float v = 0.f;
      #pragma unroll
      for (int n = 0; n < 4; n++) v = fmaxf(v, fabsf(acc[m][n][r]));
      #pragma unroll
      for (int mask = 1; mask < 16; mask <<= 1) v = fmaxf(v, __shfl_xor(v, mask, 64));
      pmax[m][r] = v;   // max over 64 cols for that row (this wave's half)
    }
  if ((l & 15) == 0) {
    #pragma unroll
    for (int m = 0; m < 4; m++)
      #pragma unroll
      for (int r = 0; r < 4; r++)
        smax[wc][wr * 64 + m * 16 + (l >> 4) * 4 + r] = pmax[m][r];
  }
  __syncthreads();

  #pragma unroll
  for (int m = 0; m < 4; m++) {
    #pragma unroll
    for (int r = 0; r < 4; r++) {
      int rl = wr * 64 + m * 16 + (l >> 4) * 4 + r;
      int grow = m0 + rl;
      float mx = fmaxf(smax[0][rl], smax[1][rl]);
      float inv = (mx > 0.f) ? 127.0f / mx : 0.f;
      if (grow < M) {
        if (wc == 0 && (l & 15) == 0)
          scales[(size_t)grow * 8 + cb] = (mx > 0.f) ? mx / 127.0f : 0.f;
        #pragma unroll
        for (int n = 0; n < 4; n++) {
          int gcol = n0 + wc * 64 + n * 16 + (l & 15);
          int u = __float2int_rn(acc[m][n][r] * inv) + 128;
          C8[(size_t)grow * HD + gcol] = (uint8_t)u;
        }
      }
    }
  }
}

// ---------------- fused aggregate + bias + LayerNorm + ReLU (u8 gather) ----------------
// 2 nodes per 256-thread block; lane covers 8 cols (one uint2 load), all inside
// col-block tt>>4. Per-lane sw tracks sum(w*scale); +128 bias corrected once.
__device__ __forceinline__ void acc_u8(float acc[8], float& sw, float w, uint2 d) {
  sw += w;
  acc[0] += w * (float)(d.x & 0xffu);
  acc[1] += w * (float)((d.x >> 8) & 0xffu);
  acc[2] += w * (float)((d.x >> 16) & 0xffu);
  acc[3] += w * (float)(d.x >> 24);
  acc[4] += w * (float)(d.y & 0xffu);
  acc[5] += w * (float)((d.y >> 8) & 0xffu);
  acc[6] += w * (float)((d.y >> 16) & 0xffu);
  acc[7] += w * (float)(d.y >> 24);
}

__global__ __launch_bounds__(256) void agg_ln_u8_kernel(
    const uint8_t* __restrict__ htu8, const float* __restrict__ scales,
    const int* __restrict__ row_ptr,
    const int* __restrict__ csr_src, const float* __restrict__ csr_w,
    const float* __restrict__ dinv, const float* __restrict__ bias,
    const float* __restrict__ gamma, const float* __restrict__ beta,
    bf16* __restrict__ hout) {
  const int g = threadIdx.x >> 7;
  const int node = blockIdx.x * 2 + g;
  const int tt = threadIdx.x & 127;
  const int cbL = tt >> 4;            // this lane's col-block
  const int wid = threadIdx.x >> 6;
  __shared__ float red[4];

  float acc[8] = {};
  float sw = 0.f;

  // self-loop
  float dn = dinv[node];
  float wself = dn * dn * scales[(size_t)node * 8 + cbL];
  acc_u8(acc, sw, wself, ((const uint2*)(htu8 + (size_t)node * HD))[tt]);

  int e = row_ptr[node];
  const int e1 = row_ptr[node + 1];
  for (; e + 4 <= e1; e += 4) {
    int s0 = csr_src[e], s1 = csr_src[e + 1], s2 = csr_src[e + 2], s3 = csr_src[e + 3];
    float w0 = csr_w[e] * scales[(size_t)s0 * 8 + cbL];
    float w1 = csr_w[e + 1] * scales[(size_t)s1 * 8 + cbL];
    float w2 = csr_w[e + 2] * scales[(size_t)s2 * 8 + cbL];
    float w3 = csr_w[e + 3] * scales[(size_t)s3 * 8 + cbL];
    uint2 d0 = ((const uint2*)(htu8 + (size_t)s0 * HD))[tt];
    uint2 d1 = ((const uint2*)(htu8 + (size_t)s1 * HD))[tt];
    uint2 d2 = ((const uint2*)(htu8 + (size_t)s2 * HD))[tt];
    uint2 d3 = ((const uint2*)(htu8 + (size_t)s3 * HD))[tt];
    acc_u8(acc, sw, w0, d0);
    acc_u8(acc, sw, w1, d1);
    acc_u8(acc, sw, w2, d2);
    acc_u8(acc, sw, w3, d3);
  }
  for (; e < e1; e++) {
    int src = csr_src[e];
    float wgt = csr_w[e] * scales[(size_t)src * 8 + cbL];
    acc_u8(acc, sw, wgt, ((const uint2*)(htu8 + (size_t)src * HD))[tt]);
  }

  // bias-correction for the +128 offset, then layer bias
  const float4* bias2 = (const float4*)bias;
  float4 ba = bias2[tt * 2], bb = bias2[tt * 2 + 1];
  float c128 = 128.0f * sw;
  acc[0] += ba.x - c128; acc[1] += ba.y - c128; acc[2] += ba.z - c128; acc[3] += ba.w - c128;
  acc[4] += bb.x - c128; acc[5] += bb.y - c128; acc[6] += bb.z - c128; acc[7] += bb.w - c128;

  float s = 0.f;
  #pragma unroll
  for (int j = 0; j < 8; j++) s += acc[j];
  #pragma unroll
  for (int off = 32; off; off >>= 1) s += __shfl_down(s, off, 64);
  if ((threadIdx.x & 63) == 0) red[wid] = s;
  __syncthreads();
  float mean = (red[g * 2] + red[g * 2 + 1]) * (1.0f / HD);
  __syncthreads();

  float d[8], s2 = 0.f;
  #pragma unroll
  for (int j = 0; j < 8; j++) { d[j] = acc[j] - mean; s2 += d[j] * d[j]; }
  #pragma unroll
  for (int off = 32; off; off >>= 1) s2 += __shfl_down(s2, off, 64);
  if ((threadIdx.x & 63) == 0) red[wid] = s2;
  __syncthreads();
  float var = (red[g * 2] + red[g * 2 + 1]) * (1.0f / HD);
  float rstd = rsqrtf(var + EPSV);

  const float4* gam2 = (const float4*)gamma;
  const float4* bet2 = (const float4*)beta;
  float4 g0 = gam2[tt * 2], g1 = gam2[tt * 2 + 1];
  float4 be0 = bet2[tt * 2], be1 = bet2[tt * 2 + 1];
  float gv[8] = {g0.x, g0.y, g0.z, g0.w, g1.x, g1.y, g1.z, g1.w};
  float bv[8] = {be0.x, be0.y, be0.z, be0.w, be1.x, be1.y, be1.z, be1.w};
  bf16x8 o;
  #pragma unroll
  for (int j = 0; j < 8; j++) o[j] = (bf16)fmaxf(d[j] * rstd * gv[j] + bv[j], 0.0f);
  ((bf16x8*)(hout + (size_t)node * HD))[tt] = o;
}

// ---------------- graph boundaries (batch is sorted) ----------------
__global__ void starts_kernel(const int* __restrict__ batch, int* __restrict__ start,
                              int n, int ngraph) {
  int g = blockIdx.x * blockDim.x + threadIdx.x;
  if (g > ngraph) return;
  int lo = 0, hi = n;
  while (lo < hi) {
    int mid = (lo + hi) >> 1;
    if (batch[mid] < g) lo = mid + 1; else hi = mid;
  }
  start[g] = lo;
}

// ---------------- mean-pool per graph: partial sums + atomics ----------------
#define POOL_CHUNKS 8
__global__ void pool_partial_kernel(const bf16* __restrict__ h, const int* __restrict__ start,
                                    float* __restrict__ out) {
  int g = blockIdx.y, c = blockIdx.x;
  int t = threadIdx.x;
  int s0 = start[g], s1 = start[g + 1];
  int len = s1 - s0;
  int per = (len + POOL_CHUNKS - 1) / POOL_CHUNKS;
  int a = s0 + c * per;
  int b = min(a + per, s1);
  if (a >= b) return;
  f32x4 acc = {0.f, 0.f, 0.f, 0.f};
  for (int n = a; n < b; n++) {
    bf16x4 v = ((const bf16x4*)(h + (size_t)n * HD))[t];
    acc[0] += (float)v[0]; acc[1] += (float)v[1];
    acc[2] += (float)v[2]; acc[3] += (float)v[3];
  }
  float* o = out + (size_t)g * HD + t * 4;
  atomicAdd(o + 0, acc[0]);
  atomicAdd(o + 1, acc[1]);
  atomicAdd(o + 2, acc[2]);
  atomicAdd(o + 3, acc[3]);
}

__global__ void pool_div_kernel(float* __restrict__ out, const int* __restrict__ start) {
  int i = blockIdx.x * 256 + threadIdx.x;
  if (i >= NG * HD) return;
  int g = i >> 10;
  float c = (float)max(start[g + 1] - start[g], 1);
  out[i] = out[i] / c;
}

extern "C" void kernel_launch(void* const* d_in, const int* in_sizes, int n_in,
                              void* d_out, int out_size, void* d_ws, size_t ws_size,
                              hipStream_t stream) {
  const float* x      = (const float*)d_in[0];
  const int*   eidx   = (const int*)d_in[1];
  const int*   batch  = (const int*)d_in[2];
  const float* W0     = (const float*)d_in[3];
  const float* b0     = (const float*)d_in[4];
  const float* Ws     = (const float*)d_in[5];
  const float* bs     = (const float*)d_in[6];
  const float* gammas = (const float*)d_in[7];
  const float* betas  = (const float*)d_in[8];
  float* out = (float*)d_out;

  const int* erow = eidx;        // sources
  const int* ecol = eidx + NE;   // targets (aggregation index)

  char* ws = (char*)d_ws;
  size_t off = 0;
  auto alloc = [&](size_t bytes) {
    void* p = ws + off;
    off = (off + bytes + 255) & ~(size_t)255;
    return p;
  };
  int*     cnt     = (int*)alloc((size_t)NN * 4);
  int*     row_ptr = (int*)alloc((size_t)(NN + 1) * 4);
  int*     fill    = (int*)alloc((size_t)NN * 4);
  int*     partial = (int*)alloc(256 * 4);
  float*   dinv    = (float*)alloc((size_t)NN * 4);
  int*     csr_src = (int*)alloc((size_t)NE * 4);
  float*   csr_w   = (float*)alloc((size_t)NE * 4);
  bf16*    Wt      = (bf16*)alloc((size_t)HD * HD * 2);
  bf16*    hbuf    = (bf16*)alloc((size_t)NN * HD * 2);   // A: bf16 h (stable)
  uint8_t* ht8     = (uint8_t*)alloc((size_t)NN * HD);    // B: u8 ht
  float*   scales  = (float*)alloc((size_t)NN * 8 * 4);   // per (row, colblock)
  int*     gstart  = (int*)alloc(65 * 4);

  hipMemsetAsync(cnt, 0, (size_t)NN * 4, stream);
  hipMemsetAsync(fill, 0, (size_t)NN * 4, stream);
  hipMemsetAsync(out, 0, (size_t)NG * HD * 4, stream);

  hist_kernel<<<(NE + 255) / 256, 256, 0, stream>>>(ecol, cnt, NE);
  dinv_kernel<<<(NN + 255) / 256, 256, 0, stream>>>(cnt, dinv, NN);
  int nb = (NN + 255) / 256;  // 196
  scan_partial_kernel<<<nb, 256, 0, stream>>>(cnt, partial, NN);
  scan_scan_kernel<<<1, 256, 0, stream>>>(partial, nb);
  scan_final_kernel<<<nb, 256, 0, stream>>>(cnt, partial, row_ptr, NN, NE);
  scatter_kernel<<<(NE + 255) / 256, 256, 0, stream>>>(erow, ecol, row_ptr, fill, dinv,
                                                       csr_src, csr_w, NE);
  starts_kernel<<<1, 128, 0, stream>>>(batch, gstart, NN, NG);

  cvt_kernel<<<(NN * FIN / 4 + 255) / 256, 256, 0, stream>>>(x, hbuf, NN * FIN / 4);

  const int nmt = (NN + 127) / 128;  // 391 m-tiles
  for (int L = 0; L < 4; L++) {
    int K = (L == 0) ? FIN : HD;
    const float* W    = (L == 0) ? W0 : Ws + (size_t)(L - 1) * HD * HD;
    const float* bias = (L == 0) ? b0 : bs + (size_t)(L - 1) * HD;
    transpose_w_kernel<<<dim3(HD / 32, K / 32), dim3(32, 8), 0, stream>>>(W, Wt, K, HD);
    gemm_bt_q8_kernel<<<nmt * 8, 256, 0, stream>>>(hbuf, Wt, ht8, scales, NN, K);
    agg_ln_u8_kernel<<<NN / 2, 256, 0, stream>>>(ht8, scales, row_ptr, csr_src, csr_w,
                                                 dinv, bias, gammas + (size_t)L * HD,
                                                 betas + (size_t)L * HD, hbuf);
  }

  pool_partial_kernel<<<dim3(POOL_CHUNKS, NG), 256, 0, stream>>>(hbuf, gstart, out);
  pool_div_kernel<<<(NG * HD + 255) / 256, 256, 0, stream>>>(out, gstart);
}

// Round 9
// 1581.155 us; speedup vs baseline: 1.6838x; 1.0634x over previous
//
#include <hip/hip_runtime.h>
#include <hip/hip_bf16.h>
#include <stdint.h>

#define NN 50000
#define NE 1600000
#define NG 64
#define FIN 256
#define HD 1024
#define EPSV 1e-5f

typedef __bf16 bf16;
typedef float f32x4 __attribute__((ext_vector_type(4)));
typedef int i32x4 __attribute__((ext_vector_type(4)));

typedef const __attribute__((address_space(1))) void* gptr_as1;
typedef __attribute__((address_space(3))) void* lptr_as3;

__device__ __forceinline__ void load_g2l_16(const void* g, const void* l) {
  __builtin_amdgcn_global_load_lds((gptr_as1)(uintptr_t)g,
                                   (lptr_as3)(uint32_t)(uintptr_t)l, 16, 0, 0);
}

// ---------------- degree histogram / dinv ----------------
__global__ void hist_kernel(const int* __restrict__ col, int* __restrict__ cnt, int E) {
  int e = blockIdx.x * 256 + threadIdx.x;
  if (e < E) atomicAdd(&cnt[col[e]], 1);
}

__global__ void dinv_kernel(const int* __restrict__ cnt, float* __restrict__ dinv, int n) {
  int i = blockIdx.x * 256 + threadIdx.x;
  if (i < n) dinv[i] = rsqrtf((float)(cnt[i] + 1));  // +1 self-loop
}

// ---------------- exclusive scan (3-phase) ----------------
__global__ void scan_partial_kernel(const int* __restrict__ cnt, int* __restrict__ partial, int n) {
  __shared__ int red[4];
  int i = blockIdx.x * 256 + threadIdx.x;
  int v = (i < n) ? cnt[i] : 0;
  #pragma unroll
  for (int off = 32; off; off >>= 1) v += __shfl_down(v, off, 64);
  if ((threadIdx.x & 63) == 0) red[threadIdx.x >> 6] = v;
  __syncthreads();
  if (threadIdx.x == 0) partial[blockIdx.x] = red[0] + red[1] + red[2] + red[3];
}

__global__ void scan_scan_kernel(int* __restrict__ partial, int nb) {
  __shared__ int s[256];
  int t = threadIdx.x;
  int v = (t < nb) ? partial[t] : 0;
  s[t] = v;
  __syncthreads();
  for (int off = 1; off < 256; off <<= 1) {
    int x = (t >= off) ? s[t - off] : 0;
    __syncthreads();
    s[t] += x;
    __syncthreads();
  }
  if (t < nb) partial[t] = s[t] - v;  // exclusive
}

__global__ void scan_final_kernel(const int* __restrict__ cnt, const int* __restrict__ partial,
                                  int* __restrict__ row_ptr, int n, int E) {
  __shared__ int s[256];
  int t = threadIdx.x;
  int i = blockIdx.x * 256 + t;
  int v = (i < n) ? cnt[i] : 0;
  s[t] = v;
  __syncthreads();
  for (int off = 1; off < 256; off <<= 1) {
    int x = (t >= off) ? s[t - off] : 0;
    __syncthreads();
    s[t] += x;
    __syncthreads();
  }
  if (i < n) row_ptr[i] = partial[blockIdx.x] + s[t] - v;
  if (i == 0) row_ptr[n] = E;
}

// ---------------- CSR scatter ----------------
__global__ void scatter_kernel(const int* __restrict__ rowi, const int* __restrict__ coli,
                               const int* __restrict__ row_ptr, int* __restrict__ fill,
                               const float* __restrict__ dinv,
                               int* __restrict__ csr_src, float* __restrict__ csr_w, int E) {
  int e = blockIdx.x * 256 + threadIdx.x;
  if (e >= E) return;
  int s = rowi[e], d = coli[e];
  int pos = row_ptr[d] + atomicAdd(&fill[d], 1);
  csr_src[pos] = s;
  csr_w[pos] = dinv[s] * dinv[d];
}

// ---------------- x f32 -> per-row i8 ----------------
__global__ __launch_bounds__(256) void quant_x_kernel(const float* __restrict__ x,
                                                      int8_t* __restrict__ A8,
                                                      float* __restrict__ hscale) {
  int row = blockIdx.x * 4 + (threadIdx.x >> 6);
  int t = threadIdx.x & 63;
  float4 v = ((const float4*)(x + (size_t)row * FIN))[t];
  float m = fmaxf(fmaxf(fabsf(v.x), fabsf(v.y)), fmaxf(fabsf(v.z), fabsf(v.w)));
  #pragma unroll
  for (int off = 32; off; off >>= 1) m = fmaxf(m, __shfl_xor(m, off, 64));
  float inv = (m > 0.f) ? 127.0f / m : 0.f;
  int q0 = min(127, max(-127, __float2int_rn(v.x * inv)));
  int q1 = min(127, max(-127, __float2int_rn(v.y * inv)));
  int q2 = min(127, max(-127, __float2int_rn(v.z * inv)));
  int q3 = min(127, max(-127, __float2int_rn(v.w * inv)));
  uint32_t p = ((uint32_t)(q0 & 0xff)) | ((uint32_t)(q1 & 0xff) << 8) |
               ((uint32_t)(q2 & 0xff) << 16) | ((uint32_t)(q3 & 0xff) << 24);
  ((uint32_t*)A8)[(size_t)row * 64 + t] = p;
  if (t == 0) hscale[row] = (m > 0.f) ? m / 127.0f : 0.f;
}

// ---------------- per-col amax of W (coalesced, tiled + atomicMax) ----------------
__global__ void wamax_kernel(const float* __restrict__ W, uint32_t* __restrict__ colmax,
                             int K, int N) {
  __shared__ float lds[8][32];
  int n = blockIdx.x * 32 + threadIdx.x;
  int k0 = blockIdx.y * 128;
  int kend = min(k0 + 128, K);
  float m = 0.f;
  for (int k = k0 + threadIdx.y; k < kend; k += 8)
    m = fmaxf(m, fabsf(W[(size_t)k * N + n]));
  lds[threadIdx.y][threadIdx.x] = m;
  __syncthreads();
  if (threadIdx.y == 0) {
    #pragma unroll
    for (int i = 1; i < 8; i++) m = fmaxf(m, lds[i][threadIdx.x]);
    atomicMax(&colmax[n], __float_as_uint(m));   // all values >= 0
  }
}

__global__ void wscale_kernel(const uint32_t* __restrict__ colmax, float* __restrict__ wscale) {
  int n = blockIdx.x * 256 + threadIdx.x;
  if (n < HD) {
    float m = __uint_as_float(colmax[n]);
    wscale[n] = (m > 0.f) ? m / 127.0f : 0.f;
  }
}

// ---------------- W [K][N] f32 -> Wt8 [N][K] i8 (per-col scale) ----------------
__global__ void transpose_wq8_kernel(const float* __restrict__ W,
                                     const uint32_t* __restrict__ colmax,
                                     int8_t* __restrict__ Wt8, int K, int N) {
  __shared__ float tile[32][33];
  int n0 = blockIdx.x * 32, k0 = blockIdx.y * 32;
  int tx = threadIdx.x, ty = threadIdx.y;  // 32 x 8
  #pragma unroll
  for (int i = ty; i < 32; i += 8) tile[i][tx] = W[(size_t)(k0 + i) * N + n0 + tx];
  __syncthreads();
  #pragma unroll
  for (int i = ty; i < 32; i += 8) {
    float cm = __uint_as_float(colmax[n0 + i]);
    float inv = (cm > 0.f) ? 127.0f / cm : 0.f;
    int q = min(127, max(-127, __float2int_rn(tile[tx][i] * inv)));
    Wt8[(size_t)(n0 + i) * K + k0 + tx] = (int8_t)q;
  }
}

// ---------------- i8 MFMA GEMM + fused u8-quant epilogue ----------------
// C_f32[m][n] = acc_i32 * hscale[m] * wscale[n]; then per (row,128-col-block)
// amax -> scales, biased-u8 C8. Byte layout of staging/fragments identical to
// the proven bf16 BK=32 pipeline (64 B per row-step).
__global__ __launch_bounds__(256, 2) void gemm_i8_q8_kernel(
    const int8_t* __restrict__ A8, const float* __restrict__ hscale,
    const int8_t* __restrict__ Wt8, const float* __restrict__ wscale,
    uint8_t* __restrict__ C8, float* __restrict__ scales, int M, int K) {
  __shared__ __align__(16) int8_t As[2][128 * 64];
  __shared__ __align__(16) int8_t Bs[2][128 * 64];
  __shared__ float smax[2][128];
  const int tid = threadIdx.x;
  const int w = tid >> 6, l = tid & 63;

  const int nwg = gridDim.x;            // nmt*8, divisible by 8
  const int o = blockIdx.x;
  const int lid = (o & 7) * (nwg >> 3) + (o >> 3);
  const int m0 = (lid >> 3) * 128, n0 = (lid & 7) * 128;
  const int cb = lid & 7;               // col-block id
  const int wr = w >> 1, wc = w & 1;    // 2x2 wave grid, each wave 64x64

  i32x4 acc[4][4] = {};

  const int r0 = tid >> 2;              // 0..63
  const int c16 = (tid & 3) * 16;       // byte offset within BK=64 row
  int ar0 = m0 + r0;       if (ar0 >= M) ar0 = M - 1;
  int ar1 = m0 + r0 + 64;  if (ar1 >= M) ar1 = M - 1;
  const int8_t* a0 = A8 + (size_t)ar0 * K + c16;
  const int8_t* a1 = A8 + (size_t)ar1 * K + c16;
  const int8_t* b0 = Wt8 + (size_t)(n0 + r0) * K + c16;
  const int8_t* b1 = Wt8 + (size_t)(n0 + r0 + 64) * K + c16;

  const int mrow = l & 15;
  const int kch = (l >> 4) * 16;        // byte offset within row

  auto stage = [&](int b, int k) {
    int8_t* asw = &As[b][w * 1024];
    int8_t* bsw = &Bs[b][w * 1024];
    load_g2l_16(a0 + k, asw);
    load_g2l_16(a1 + k, asw + 4096);
    load_g2l_16(b0 + k, bsw);
    load_g2l_16(b1 + k, bsw + 4096);
  };

  const int nit = K >> 6;
  stage(0, 0);
  __syncthreads();

  int cur = 0;
  for (int t = 0; t < nit; ++t) {
    if (t + 1 < nit) stage(cur ^ 1, (t + 1) << 6);
    i32x4 af[4], bf_[4];
    #pragma unroll
    for (int m = 0; m < 4; m++)
      af[m] = *(const i32x4*)&As[cur][(wr * 64 + m * 16 + mrow) * 64 + kch];
    #pragma unroll
    for (int n = 0; n < 4; n++)
      bf_[n] = *(const i32x4*)&Bs[cur][(wc * 64 + n * 16 + mrow) * 64 + kch];
    #pragma unroll
    for (int m = 0; m < 4; m++)
      #pragma unroll
      for (int n = 0; n < 4; n++)
        acc[m][n] = __builtin_amdgcn_mfma_i32_16x16x64_i8(af[m], bf_[n], acc[m][n], 0, 0, 0);
    __syncthreads();
    cur ^= 1;
  }

  // ---- epilogue: scale to f32, per-row amax over this block's 128 cols ----
  float wsv[4];
  #pragma unroll
  for (int n = 0; n < 4; n++) wsv[n] = wscale[n0 + wc * 64 + n * 16 + (l & 15)];

  float cf[4][4][4];
  #pragma unroll
  for (int m = 0; m < 4; m++) {
    #pragma unroll
    for (int r = 0; r < 4; r++) {
      int rl = wr * 64 + m * 16 + (l >> 4) * 4 + r;
      int grow = m0 + rl; if (grow >= M) grow = M - 1;
      float hs = hscale[grow];
      float v = 0.f;
      #pragma unroll
      for (int n = 0; n < 4; n++) {
        float c = (float)acc[m][n][r] * hs * wsv[n];
        cf[m][n][r] = c;
        v = fmaxf(v, fabsf(c));
      }
      #pragma unroll
      for (int mask = 1; mask < 16; mask <<= 1) v = fmaxf(v, __shfl_xor(v, mask, 64));
      if ((l & 15) == 0) smax[wc][rl] = v;
    }
  }
  __syncthreads();

  #pragma unroll
  for (int m = 0; m < 4; m++) {
    #pragma unroll
    for (int r = 0; r < 4; r++) {
      int rl = wr * 64 + m * 16 + (l >> 4) * 4 + r;
      int grow = m0 + rl;
      float mx = fmaxf(smax[0][rl], smax[1][rl]);
      float inv = (mx > 0.f) ? 127.0f / mx : 0.f;
      if (grow < M) {
        if (wc == 0 && (l & 15) == 0)
          scales[(size_t)grow * 8 + cb] = (mx > 0.f) ? mx / 127.0f : 0.f;
        #pragma unroll
        for (int n = 0; n < 4; n++) {
          int gcol = n0 + wc * 64 + n * 16 + (l & 15);
          int u = __float2int_rn(cf[m][n][r] * inv) + 128;
          C8[(size_t)grow * HD + gcol] = (uint8_t)u;
        }
      }
    }
  }
}

// ---------------- fused aggregate + bias + LayerNorm + ReLU (u8 gather, i8 out) ----------------
__device__ __forceinline__ void acc_u8(float acc[8], float& sw, float w, uint2 d) {
  sw += w;
  acc[0] += w * (float)(d.x & 0xffu);
  acc[1] += w * (float)((d.x >> 8) & 0xffu);
  acc[2] += w * (float)((d.x >> 16) & 0xffu);
  acc[3] += w * (float)(d.x >> 24);
  acc[4] += w * (float)(d.y & 0xffu);
  acc[5] += w * (float)((d.y >> 8) & 0xffu);
  acc[6] += w * (float)((d.y >> 16) & 0xffu);
  acc[7] += w * (float)(d.y >> 24);
}

__global__ __launch_bounds__(256) void agg_ln_u8_kernel(
    const uint8_t* __restrict__ htu8, const float* __restrict__ scales,
    const int* __restrict__ row_ptr,
    const int* __restrict__ csr_src, const float* __restrict__ csr_w,
    const float* __restrict__ dinv, const float* __restrict__ bias,
    const float* __restrict__ gamma, const float* __restrict__ beta,
    int8_t* __restrict__ hq, float* __restrict__ hscale) {
  const int g = threadIdx.x >> 7;
  const int node = blockIdx.x * 2 + g;
  const int tt = threadIdx.x & 127;
  const int cbL = tt >> 4;            // this lane's col-block
  const int wid = threadIdx.x >> 6;
  __shared__ float red[4];

  float acc[8] = {};
  float sw = 0.f;

  // self-loop
  float dn = dinv[node];
  float wself = dn * dn * scales[(size_t)node * 8 + cbL];
  acc_u8(acc, sw, wself, ((const uint2*)(htu8 + (size_t)node * HD))[tt]);

  int e = row_ptr[node];
  const int e1 = row_ptr[node + 1];
  for (; e + 4 <= e1; e += 4) {
    int s0 = csr_src[e], s1 = csr_src[e + 1], s2 = csr_src[e + 2], s3 = csr_src[e + 3];
    float w0 = csr_w[e] * scales[(size_t)s0 * 8 + cbL];
    float w1 = csr_w[e + 1] * scales[(size_t)s1 * 8 + cbL];
    float w2 = csr_w[e + 2] * scales[(size_t)s2 * 8 + cbL];
    float w3 = csr_w[e + 3] * scales[(size_t)s3 * 8 + cbL];
    uint2 d0 = ((const uint2*)(htu8 + (size_t)s0 * HD))[tt];
    uint2 d1 = ((const uint2*)(htu8 + (size_t)s1 * HD))[tt];
    uint2 d2 = ((const uint2*)(htu8 + (size_t)s2 * HD))[tt];
    uint2 d3 = ((const uint2*)(htu8 + (size_t)s3 * HD))[tt];
    acc_u8(acc, sw, w0, d0);
    acc_u8(acc, sw, w1, d1);
    acc_u8(acc, sw, w2, d2);
    acc_u8(acc, sw, w3, d3);
  }
  for (; e < e1; e++) {
    int src = csr_src[e];
    float wgt = csr_w[e] * scales[(size_t)src * 8 + cbL];
    acc_u8(acc, sw, wgt, ((const uint2*)(htu8 + (size_t)src * HD))[tt]);
  }

  // bias-correction for the +128 offset, then layer bias
  const float4* bias2 = (const float4*)bias;
  float4 ba = bias2[tt * 2], bb = bias2[tt * 2 + 1];
  float c128 = 128.0f * sw;
  acc[0] += ba.x - c128; acc[1] += ba.y - c128; acc[2] += ba.z - c128; acc[3] += ba.w - c128;
  acc[4] += bb.x - c128; acc[5] += bb.y - c128; acc[6] += bb.z - c128; acc[7] += bb.w - c128;

  float s = 0.f;
  #pragma unroll
  for (int j = 0; j < 8; j++) s += acc[j];
  #pragma unroll
  for (int off = 32; off; off >>= 1) s += __shfl_down(s, off, 64);
  if ((threadIdx.x & 63) == 0) red[wid] = s;
  __syncthreads();
  float mean = (red[g * 2] + red[g * 2 + 1]) * (1.0f / HD);
  __syncthreads();

  float d[8], s2 = 0.f;
  #pragma unroll
  for (int j = 0; j < 8; j++) { d[j] = acc[j] - mean; s2 += d[j] * d[j]; }
  #pragma unroll
  for (int off = 32; off; off >>= 1) s2 += __shfl_down(s2, off, 64);
  if ((threadIdx.x & 63) == 0) red[wid] = s2;
  __syncthreads();
  float var = (red[g * 2] + red[g * 2 + 1]) * (1.0f / HD);
  float rstd = rsqrtf(var + EPSV);

  const float4* gam2 = (const float4*)gamma;
  const float4* bet2 = (const float4*)beta;
  float4 g0 = gam2[tt * 2], g1 = gam2[tt * 2 + 1];
  float4 be0 = bet2[tt * 2], be1 = bet2[tt * 2 + 1];
  float gv[8] = {g0.x, g0.y, g0.z, g0.w, g1.x, g1.y, g1.z, g1.w};
  float bv[8] = {be0.x, be0.y, be0.z, be0.w, be1.x, be1.y, be1.z, be1.w};
  float o[8];
  float rmax = 0.f;
  #pragma unroll
  for (int j = 0; j < 8; j++) {
    o[j] = fmaxf(d[j] * rstd * gv[j] + bv[j], 0.0f);
    rmax = fmaxf(rmax, o[j]);
  }

  // per-row amax over the 128 lanes of this node-group -> i8 quant
  __syncthreads();                       // red[] reuse
  #pragma unroll
  for (int off = 32; off; off >>= 1) rmax = fmaxf(rmax, __shfl_xor(rmax, off, 64));
  if ((threadIdx.x & 63) == 0) red[wid] = rmax;
  __syncthreads();
  float rm = fmaxf(red[g * 2], red[g * 2 + 1]);
  float qinv = (rm > 0.f) ? 127.0f / rm : 0.f;
  int q[8];
  #pragma unroll
  for (int j = 0; j < 8; j++) q[j] = min(127, __float2int_rn(o[j] * qinv));
  uint32_t p0 = ((uint32_t)q[0]) | ((uint32_t)q[1] << 8) | ((uint32_t)q[2] << 16) | ((uint32_t)q[3] << 24);
  uint32_t p1 = ((uint32_t)q[4]) | ((uint32_t)q[5] << 8) | ((uint32_t)q[6] << 16) | ((uint32_t)q[7] << 24);
  uint2 pk; pk.x = p0; pk.y = p1;
  ((uint2*)(hq + (size_t)node * HD))[tt] = pk;
  if (tt == 0) hscale[node] = (rm > 0.f) ? rm / 127.0f : 0.f;
}

// ---------------- graph boundaries (batch is sorted) ----------------
__global__ void starts_kernel(const int* __restrict__ batch, int* __restrict__ start,
                              int n, int ngraph) {
  int g = blockIdx.x * blockDim.x + threadIdx.x;
  if (g > ngraph) return;
  int lo = 0, hi = n;
  while (lo < hi) {
    int mid = (lo + hi) >> 1;
    if (batch[mid] < g) lo = mid + 1; else hi = mid;
  }
  start[g] = lo;
}

// ---------------- mean-pool per graph (i8 input): partial sums + atomics ----------------
#define POOL_CHUNKS 8
__global__ void pool_partial_kernel(const int8_t* __restrict__ hq,
                                    const float* __restrict__ hscale,
                                    const int* __restrict__ start,
                                    float* __restrict__ out) {
  int g = blockIdx.y, c = blockIdx.x;
  int t = threadIdx.x;
  int s0 = start[g], s1 = start[g + 1];
  int len = s1 - s0;
  int per = (len + POOL_CHUNKS - 1) / POOL_CHUNKS;
  int a = s0 + c * per;
  int b = min(a + per, s1);
  if (a >= b) return;
  f32x4 acc = {0.f, 0.f, 0.f, 0.f};
  for (int n = a; n < b; n++) {
    float hs = hscale[n];
    uint32_t d = ((const uint32_t*)(hq + (size_t)n * HD))[t];   // 4 vals, 0..127
    acc[0] += hs * (float)(d & 0xffu);
    acc[1] += hs * (float)((d >> 8) & 0xffu);
    acc[2] += hs * (float)((d >> 16) & 0xffu);
    acc[3] += hs * (float)(d >> 24);
  }
  float* o = out + (size_t)g * HD + t * 4;
  atomicAdd(o + 0, acc[0]);
  atomicAdd(o + 1, acc[1]);
  atomicAdd(o + 2, acc[2]);
  atomicAdd(o + 3, acc[3]);
}

__global__ void pool_div_kernel(float* __restrict__ out, const int* __restrict__ start) {
  int i = blockIdx.x * 256 + threadIdx.x;
  if (i >= NG * HD) return;
  int g = i >> 10;
  float c = (float)max(start[g + 1] - start[g], 1);
  out[i] = out[i] / c;
}

extern "C" void kernel_launch(void* const* d_in, const int* in_sizes, int n_in,
                              void* d_out, int out_size, void* d_ws, size_t ws_size,
                              hipStream_t stream) {
  const float* x      = (const float*)d_in[0];
  const int*   eidx   = (const int*)d_in[1];
  const int*   batch  = (const int*)d_in[2];
  const float* W0     = (const float*)d_in[3];
  const float* b0     = (const float*)d_in[4];
  const float* Ws     = (const float*)d_in[5];
  const float* bs     = (const float*)d_in[6];
  const float* gammas = (const float*)d_in[7];
  const float* betas  = (const float*)d_in[8];
  float* out = (float*)d_out;

  const int* erow = eidx;        // sources
  const int* ecol = eidx + NE;   // targets (aggregation index)

  char* ws = (char*)d_ws;
  size_t off = 0;
  auto alloc = [&](size_t bytes) {
    void* p = ws + off;
    off = (off + bytes + 255) & ~(size_t)255;
    return p;
  };
  int*     cnt     = (int*)alloc((size_t)NN * 4);      // later: wscale[0:1024] + colmax[1024:2048]
  int*     row_ptr = (int*)alloc((size_t)(NN + 1) * 4);
  int*     fill    = (int*)alloc((size_t)NN * 4);      // later: hscale (NN floats)
  int*     partial = (int*)alloc(256 * 4);
  float*   dinv    = (float*)alloc((size_t)NN * 4);
  int*     csr_src = (int*)alloc((size_t)NE * 4);
  float*   csr_w   = (float*)alloc((size_t)NE * 4);
  int8_t*  Wt8     = (int8_t*)alloc((size_t)HD * HD);
  int8_t*  A8      = (int8_t*)alloc((size_t)NN * HD);  // i8 activations (L0 pitch 256)
  uint8_t* ht8     = (uint8_t*)alloc((size_t)NN * HD); // u8 GEMM output
  float*   scales  = (float*)alloc((size_t)NN * 8 * 4);
  int*     gstart  = (int*)alloc(65 * 4);

  float*    wscale = (float*)cnt;                 // cnt dead after scan/dinv
  uint32_t* colmax = (uint32_t*)cnt + 1024;
  float*    hscale = (float*)fill;                // fill dead after scatter

  hipMemsetAsync(cnt, 0, (size_t)NN * 4, stream);
  hipMemsetAsync(fill, 0, (size_t)NN * 4, stream);
  hipMemsetAsync(out, 0, (size_t)NG * HD * 4, stream);

  hist_kernel<<<(NE + 255) / 256, 256, 0, stream>>>(ecol, cnt, NE);
  dinv_kernel<<<(NN + 255) / 256, 256, 0, stream>>>(cnt, dinv, NN);
  int nb = (NN + 255) / 256;  // 196
  scan_partial_kernel<<<nb, 256, 0, stream>>>(cnt, partial, NN);
  scan_scan_kernel<<<1, 256, 0, stream>>>(partial, nb);
  scan_final_kernel<<<nb, 256, 0, stream>>>(cnt, partial, row_ptr, NN, NE);
  scatter_kernel<<<(NE + 255) / 256, 256, 0, stream>>>(erow, ecol, row_ptr, fill, dinv,
                                                       csr_src, csr_w, NE);
  starts_kernel<<<1, 128, 0, stream>>>(batch, gstart, NN, NG);

  // x -> i8 activations (after scatter: hscale aliases fill)
  quant_x_kernel<<<NN / 4, 256, 0, stream>>>(x, A8, hscale);

  const int nmt = (NN + 127) / 128;  // 391 m-tiles
  for (int L = 0; L < 4; L++) {
    int K = (L == 0) ? FIN : HD;
    const float* W    = (L == 0) ? W0 : Ws + (size_t)(L - 1) * HD * HD;
    const float* bias = (L == 0) ? b0 : bs + (size_t)(L - 1) * HD;
    hipMemsetAsync(colmax, 0, HD * 4, stream);
    wamax_kernel<<<dim3(HD / 32, (K + 127) / 128), dim3(32, 8), 0, stream>>>(W, colmax, K, HD);
    wscale_kernel<<<HD / 256, 256, 0, stream>>>(colmax, wscale);
    transpose_wq8_kernel<<<dim3(HD / 32, K / 32), dim3(32, 8), 0, stream>>>(W, colmax, Wt8, K, HD);
    gemm_i8_q8_kernel<<<nmt * 8, 256, 0, stream>>>(A8, hscale, Wt8, wscale, ht8, scales, NN, K);
    agg_ln_u8_kernel<<<NN / 2, 256, 0, stream>>>(ht8, scales, row_ptr, csr_src, csr_w,
                                                 dinv, bias, gammas + (size_t)L * HD,
                                                 betas + (size_t)L * HD, A8, hscale);
  }

  pool_partial_kernel<<<dim3(POOL_CHUNKS, NG), 256, 0, stream>>>(A8, hscale, gstart, out);
  pool_div_kernel<<<(NG * HD + 255) / 256, 256, 0, stream>>>(out, gstart);
}

// Round 10
// 1544.327 us; speedup vs baseline: 1.7240x; 1.0238x over previous
//
#include <hip/hip_runtime.h>
#include <hip/hip_bf16.h>
#include <stdint.h>

#define NN 50000
#define NE 1600000
#define NG 64
#define FIN 256
#define HD 1024
#define EPSV 1e-5f

typedef __bf16 bf16;
typedef float f32x4 __attribute__((ext_vector_type(4)));
typedef float f32x2 __attribute__((ext_vector_type(2)));
typedef int i32x4 __attribute__((ext_vector_type(4)));

typedef const __attribute__((address_space(1))) void* gptr_as1;
typedef __attribute__((address_space(3))) void* lptr_as3;

__device__ __forceinline__ void load_g2l_16(const void* g, const void* l) {
  __builtin_amdgcn_global_load_lds((gptr_as1)(uintptr_t)g,
                                   (lptr_as3)(uint32_t)(uintptr_t)l, 16, 0, 0);
}

// ---------------- degree histogram / dinv ----------------
__global__ void hist_kernel(const int* __restrict__ col, int* __restrict__ cnt, int E) {
  int e = blockIdx.x * 256 + threadIdx.x;
  if (e < E) atomicAdd(&cnt[col[e]], 1);
}

__global__ void dinv_kernel(const int* __restrict__ cnt, float* __restrict__ dinv, int n) {
  int i = blockIdx.x * 256 + threadIdx.x;
  if (i < n) dinv[i] = rsqrtf((float)(cnt[i] + 1));  // +1 self-loop
}

// ---------------- exclusive scan (3-phase) ----------------
__global__ void scan_partial_kernel(const int* __restrict__ cnt, int* __restrict__ partial, int n) {
  __shared__ int red[4];
  int i = blockIdx.x * 256 + threadIdx.x;
  int v = (i < n) ? cnt[i] : 0;
  #pragma unroll
  for (int off = 32; off; off >>= 1) v += __shfl_down(v, off, 64);
  if ((threadIdx.x & 63) == 0) red[threadIdx.x >> 6] = v;
  __syncthreads();
  if (threadIdx.x == 0) partial[blockIdx.x] = red[0] + red[1] + red[2] + red[3];
}

__global__ void scan_scan_kernel(int* __restrict__ partial, int nb) {
  __shared__ int s[256];
  int t = threadIdx.x;
  int v = (t < nb) ? partial[t] : 0;
  s[t] = v;
  __syncthreads();
  for (int off = 1; off < 256; off <<= 1) {
    int x = (t >= off) ? s[t - off] : 0;
    __syncthreads();
    s[t] += x;
    __syncthreads();
  }
  if (t < nb) partial[t] = s[t] - v;  // exclusive
}

__global__ void scan_final_kernel(const int* __restrict__ cnt, const int* __restrict__ partial,
                                  int* __restrict__ row_ptr, int n, int E) {
  __shared__ int s[256];
  int t = threadIdx.x;
  int i = blockIdx.x * 256 + t;
  int v = (i < n) ? cnt[i] : 0;
  s[t] = v;
  __syncthreads();
  for (int off = 1; off < 256; off <<= 1) {
    int x = (t >= off) ? s[t - off] : 0;
    __syncthreads();
    s[t] += x;
    __syncthreads();
  }
  if (i < n) row_ptr[i] = partial[blockIdx.x] + s[t] - v;
  if (i == 0) row_ptr[n] = E;
}

// ---------------- CSR scatter (packed {src, w_bits}) ----------------
__global__ void scatter_kernel(const int* __restrict__ rowi, const int* __restrict__ coli,
                               const int* __restrict__ row_ptr, int* __restrict__ fill,
                               const float* __restrict__ dinv,
                               int2* __restrict__ csr_sw, int E) {
  int e = blockIdx.x * 256 + threadIdx.x;
  if (e >= E) return;
  int s = rowi[e], d = coli[e];
  int pos = row_ptr[d] + atomicAdd(&fill[d], 1);
  int2 p;
  p.x = s;
  p.y = __float_as_int(dinv[s] * dinv[d]);
  csr_sw[pos] = p;
}

// ---------------- x f32 -> per-row i8 ----------------
__global__ __launch_bounds__(256) void quant_x_kernel(const float* __restrict__ x,
                                                      int8_t* __restrict__ A8,
                                                      float* __restrict__ hscale) {
  int row = blockIdx.x * 4 + (threadIdx.x >> 6);
  int t = threadIdx.x & 63;
  float4 v = ((const float4*)(x + (size_t)row * FIN))[t];
  float m = fmaxf(fmaxf(fabsf(v.x), fabsf(v.y)), fmaxf(fabsf(v.z), fabsf(v.w)));
  #pragma unroll
  for (int off = 32; off; off >>= 1) m = fmaxf(m, __shfl_xor(m, off, 64));
  float inv = (m > 0.f) ? 127.0f / m : 0.f;
  int q0 = min(127, max(-127, __float2int_rn(v.x * inv)));
  int q1 = min(127, max(-127, __float2int_rn(v.y * inv)));
  int q2 = min(127, max(-127, __float2int_rn(v.z * inv)));
  int q3 = min(127, max(-127, __float2int_rn(v.w * inv)));
  uint32_t p = ((uint32_t)(q0 & 0xff)) | ((uint32_t)(q1 & 0xff) << 8) |
               ((uint32_t)(q2 & 0xff) << 16) | ((uint32_t)(q3 & 0xff) << 24);
  ((uint32_t*)A8)[(size_t)row * 64 + t] = p;
  if (t == 0) hscale[row] = (m > 0.f) ? m / 127.0f : 0.f;
}

// ---------------- batched weight prep (all 4 layers, hoisted) ----------------
__device__ __forceinline__ const float* layer_W(const float* W0, const float* Ws, int L) {
  return (L == 0) ? W0 : Ws + (size_t)(L - 1) * HD * HD;
}

__global__ void wamax_all_kernel(const float* __restrict__ W0, const float* __restrict__ Ws,
                                 uint32_t* __restrict__ colmax) {
  __shared__ float lds[8][32];
  int L = blockIdx.z;
  int K = (L == 0) ? FIN : HD;
  int k0 = blockIdx.y * 128;
  if (k0 >= K) return;
  const float* W = layer_W(W0, Ws, L);
  int n = blockIdx.x * 32 + threadIdx.x;
  int kend = min(k0 + 128, K);
  float m = 0.f;
  for (int k = k0 + threadIdx.y; k < kend; k += 8)
    m = fmaxf(m, fabsf(W[(size_t)k * HD + n]));
  lds[threadIdx.y][threadIdx.x] = m;
  __syncthreads();
  if (threadIdx.y == 0) {
    #pragma unroll
    for (int i = 1; i < 8; i++) m = fmaxf(m, lds[i][threadIdx.x]);
    atomicMax(&colmax[L * HD + n], __float_as_uint(m));   // all values >= 0
  }
}

__global__ void wscale_all_kernel(const uint32_t* __restrict__ colmax,
                                  float* __restrict__ wscale) {
  int i = blockIdx.x * 256 + threadIdx.x;
  if (i < 4 * HD) {
    float m = __uint_as_float(colmax[i]);
    wscale[i] = (m > 0.f) ? m / 127.0f : 0.f;
  }
}

// Wt8_all layout: L0 at off 0 (HD rows x 256), L1.. at FIN*HD + (L-1)*HD*HD (HD rows x 1024)
__global__ void transpose_wq8_all_kernel(const float* __restrict__ W0,
                                         const float* __restrict__ Ws,
                                         const uint32_t* __restrict__ colmax,
                                         int8_t* __restrict__ Wt8_all) {
  __shared__ float tile[32][33];
  int L = blockIdx.z;
  int K = (L == 0) ? FIN : HD;
  int k0 = blockIdx.y * 32;
  if (k0 >= K) return;
  const float* W = layer_W(W0, Ws, L);
  int8_t* Wt8 = Wt8_all + ((L == 0) ? 0 : (size_t)FIN * HD + (size_t)(L - 1) * HD * HD);
  int n0 = blockIdx.x * 32;
  int tx = threadIdx.x, ty = threadIdx.y;  // 32 x 8
  #pragma unroll
  for (int i = ty; i < 32; i += 8) tile[i][tx] = W[(size_t)(k0 + i) * HD + n0 + tx];
  __syncthreads();
  #pragma unroll
  for (int i = ty; i < 32; i += 8) {
    float cm = __uint_as_float(colmax[L * HD + n0 + i]);
    float inv = (cm > 0.f) ? 127.0f / cm : 0.f;
    int q = min(127, max(-127, __float2int_rn(tile[tx][i] * inv)));
    Wt8[(size_t)(n0 + i) * K + k0 + tx] = (int8_t)q;
  }
}

// ---------------- i8 MFMA GEMM + fused u8-quant epilogue ----------------
// 2-phase prefetch + XCD swizzle; 4 blocks/CU; epilogue recomputes c (no cf
// cache) to stay <=128 VGPR.
__global__ __launch_bounds__(256, 4) void gemm_i8_q8_kernel(
    const int8_t* __restrict__ A8, const float* __restrict__ hscale,
    const int8_t* __restrict__ Wt8, const float* __restrict__ wscale,
    uint8_t* __restrict__ C8, float* __restrict__ scales, int M, int K) {
  __shared__ __align__(16) int8_t As[2][128 * 64];
  __shared__ __align__(16) int8_t Bs[2][128 * 64];
  __shared__ float smax[2][128];
  const int tid = threadIdx.x;
  const int w = tid >> 6, l = tid & 63;

  const int nwg = gridDim.x;            // nmt*8, divisible by 8
  const int o = blockIdx.x;
  const int lid = (o & 7) * (nwg >> 3) + (o >> 3);
  const int m0 = (lid >> 3) * 128, n0 = (lid & 7) * 128;
  const int cb = lid & 7;               // col-block id
  const int wr = w >> 1, wc = w & 1;    // 2x2 wave grid, each wave 64x64

  i32x4 acc[4][4] = {};

  const int r0 = tid >> 2;              // 0..63
  const int c16 = (tid & 3) * 16;       // byte offset within BK=64 row
  int ar0 = m0 + r0;       if (ar0 >= M) ar0 = M - 1;
  int ar1 = m0 + r0 + 64;  if (ar1 >= M) ar1 = M - 1;
  const int8_t* a0 = A8 + (size_t)ar0 * K + c16;
  const int8_t* a1 = A8 + (size_t)ar1 * K + c16;
  const int8_t* b0 = Wt8 + (size_t)(n0 + r0) * K + c16;
  const int8_t* b1 = Wt8 + (size_t)(n0 + r0 + 64) * K + c16;

  const int mrow = l & 15;
  const int kch = (l >> 4) * 16;        // byte offset within row

  auto stage = [&](int b, int k) {
    int8_t* asw = &As[b][w * 1024];
    int8_t* bsw = &Bs[b][w * 1024];
    load_g2l_16(a0 + k, asw);
    load_g2l_16(a1 + k, asw + 4096);
    load_g2l_16(b0 + k, bsw);
    load_g2l_16(b1 + k, bsw + 4096);
  };

  const int nit = K >> 6;
  stage(0, 0);
  __syncthreads();

  int cur = 0;
  for (int t = 0; t < nit; ++t) {
    if (t + 1 < nit) stage(cur ^ 1, (t + 1) << 6);
    i32x4 af[4], bf_[4];
    #pragma unroll
    for (int m = 0; m < 4; m++)
      af[m] = *(const i32x4*)&As[cur][(wr * 64 + m * 16 + mrow) * 64 + kch];
    #pragma unroll
    for (int n = 0; n < 4; n++)
      bf_[n] = *(const i32x4*)&Bs[cur][(wc * 64 + n * 16 + mrow) * 64 + kch];
    #pragma unroll
    for (int m = 0; m < 4; m++)
      #pragma unroll
      for (int n = 0; n < 4; n++)
        acc[m][n] = __builtin_amdgcn_mfma_i32_16x16x64_i8(af[m], bf_[n], acc[m][n], 0, 0, 0);
    __syncthreads();
    cur ^= 1;
  }

  // ---- epilogue: per-row amax over this block's 128 cols (pass 1), quant (pass 2) ----
  float wsv[4];
  #pragma unroll
  for (int n = 0; n < 4; n++) wsv[n] = wscale[n0 + wc * 64 + n * 16 + (l & 15)];

  #pragma unroll
  for (int m = 0; m < 4; m++) {
    #pragma unroll
    for (int r = 0; r < 4; r++) {
      int rl = wr * 64 + m * 16 + (l >> 4) * 4 + r;
      int grow = m0 + rl; if (grow >= M) grow = M - 1;
      float v = 0.f;
      #pragma unroll
      for (int n = 0; n < 4; n++)
        v = fmaxf(v, fabsf((float)acc[m][n][r] * wsv[n]));
      v *= hscale[grow];   // hs >= 0: factor out of the max
      #pragma unroll
      for (int mask = 1; mask < 16; mask <<= 1) v = fmaxf(v, __shfl_xor(v, mask, 64));
      if ((l & 15) == 0) smax[wc][rl] = v;
    }
  }
  __syncthreads();

  #pragma unroll
  for (int m = 0; m < 4; m++) {
    #pragma unroll
    for (int r = 0; r < 4; r++) {
      int rl = wr * 64 + m * 16 + (l >> 4) * 4 + r;
      int grow = m0 + rl;
      float mx = fmaxf(smax[0][rl], smax[1][rl]);
      float inv = (mx > 0.f) ? 127.0f / mx : 0.f;
      if (grow < M) {
        float hs = hscale[grow];
        if (wc == 0 && (l & 15) == 0)
          scales[(size_t)grow * 8 + cb] = (mx > 0.f) ? mx / 127.0f : 0.f;
        #pragma unroll
        for (int n = 0; n < 4; n++) {
          int gcol = n0 + wc * 64 + n * 16 + (l & 15);
          int u = __float2int_rn((float)acc[m][n][r] * hs * wsv[n] * inv) + 128;
          C8[(size_t)grow * HD + gcol] = (uint8_t)u;
        }
      }
    }
  }
}

// ---------------- fused aggregate + bias + LayerNorm + ReLU (u8 gather, i8 out) ----------------
__device__ __forceinline__ void acc_u8p(f32x2 a[4], float& sw, float w, uint2 d) {
  sw += w;
  f32x2 w2 = {w, w};
  f32x2 v0 = {(float)(d.x & 0xffu), (float)((d.x >> 8) & 0xffu)};
  f32x2 v1 = {(float)((d.x >> 16) & 0xffu), (float)(d.x >> 24)};
  f32x2 v2 = {(float)(d.y & 0xffu), (float)((d.y >> 8) & 0xffu)};
  f32x2 v3 = {(float)((d.y >> 16) & 0xffu), (float)(d.y >> 24)};
  a[0] += w2 * v0;
  a[1] += w2 * v1;
  a[2] += w2 * v2;
  a[3] += w2 * v3;
}

__global__ __launch_bounds__(256) void agg_ln_u8_kernel(
    const uint8_t* __restrict__ htu8, const float* __restrict__ scales,
    const int* __restrict__ row_ptr, const int2* __restrict__ csr_sw,
    const float* __restrict__ dinv, const float* __restrict__ bias,
    const float* __restrict__ gamma, const float* __restrict__ beta,
    int8_t* __restrict__ hq, float* __restrict__ hscale) {
  const int g = threadIdx.x >> 7;
  const int node = blockIdx.x * 2 + g;
  const int tt = threadIdx.x & 127;
  const int cbL = tt >> 4;            // this lane's col-block
  const int wid = threadIdx.x >> 6;
  __shared__ float red[4];

  f32x2 acc2[4] = {};
  float sw = 0.f;

  // self-loop
  float dn = dinv[node];
  float wself = dn * dn * scales[(size_t)node * 8 + cbL];
  acc_u8p(acc2, sw, wself, ((const uint2*)(htu8 + (size_t)node * HD))[tt]);

  int e = row_ptr[node];
  const int e1 = row_ptr[node + 1];
  for (; e + 4 <= e1; e += 4) {
    int2 p0 = csr_sw[e], p1 = csr_sw[e + 1], p2 = csr_sw[e + 2], p3 = csr_sw[e + 3];
    float w0 = __int_as_float(p0.y) * scales[(size_t)p0.x * 8 + cbL];
    float w1 = __int_as_float(p1.y) * scales[(size_t)p1.x * 8 + cbL];
    float w2 = __int_as_float(p2.y) * scales[(size_t)p2.x * 8 + cbL];
    float w3 = __int_as_float(p3.y) * scales[(size_t)p3.x * 8 + cbL];
    uint2 d0 = ((const uint2*)(htu8 + (size_t)p0.x * HD))[tt];
    uint2 d1 = ((const uint2*)(htu8 + (size_t)p1.x * HD))[tt];
    uint2 d2 = ((const uint2*)(htu8 + (size_t)p2.x * HD))[tt];
    uint2 d3 = ((const uint2*)(htu8 + (size_t)p3.x * HD))[tt];
    acc_u8p(acc2, sw, w0, d0);
    acc_u8p(acc2, sw, w1, d1);
    acc_u8p(acc2, sw, w2, d2);
    acc_u8p(acc2, sw, w3, d3);
  }
  for (; e < e1; e++) {
    int2 p = csr_sw[e];
    float wgt = __int_as_float(p.y) * scales[(size_t)p.x * 8 + cbL];
    acc_u8p(acc2, sw, wgt, ((const uint2*)(htu8 + (size_t)p.x * HD))[tt]);
  }

  float acc[8] = {acc2[0][0], acc2[0][1], acc2[1][0], acc2[1][1],
                  acc2[2][0], acc2[2][1], acc2[3][0], acc2[3][1]};

  // bias-correction for the +128 offset, then layer bias
  const float4* bias2 = (const float4*)bias;
  float4 ba = bias2[tt * 2], bb = bias2[tt * 2 + 1];
  float c128 = 128.0f * sw;
  acc[0] += ba.x - c128; acc[1] += ba.y - c128; acc[2] += ba.z - c128; acc[3] += ba.w - c128;
  acc[4] += bb.x - c128; acc[5] += bb.y - c128; acc[6] += bb.z - c128; acc[7] += bb.w - c128;

  float s = 0.f;
  #pragma unroll
  for (int j = 0; j < 8; j++) s += acc[j];
  #pragma unroll
  for (int off = 32; off; off >>= 1) s += __shfl_down(s, off, 64);
  if ((threadIdx.x & 63) == 0) red[wid] = s;
  __syncthreads();
  float mean = (red[g * 2] + red[g * 2 + 1]) * (1.0f / HD);
  __syncthreads();

  float d[8], s2 = 0.f;
  #pragma unroll
  for (int j = 0; j < 8; j++) { d[j] = acc[j] - mean; s2 += d[j] * d[j]; }
  #pragma unroll
  for (int off = 32; off; off >>= 1) s2 += __shfl_down(s2, off, 64);
  if ((threadIdx.x & 63) == 0) red[wid] = s2;
  __syncthreads();
  float var = (red[g * 2] + red[g * 2 + 1]) * (1.0f / HD);
  float rstd = rsqrtf(var + EPSV);

  const float4* gam2 = (const float4*)gamma;
  const float4* bet2 = (const float4*)beta;
  float4 g0 = gam2[tt * 2], g1 = gam2[tt * 2 + 1];
  float4 be0 = bet2[tt * 2], be1 = bet2[tt * 2 + 1];
  float gv[8] = {g0.x, g0.y, g0.z, g0.w, g1.x, g1.y, g1.z, g1.w};
  float bv[8] = {be0.x, be0.y, be0.z, be0.w, be1.x, be1.y, be1.z, be1.w};
  float o[8];
  float rmax = 0.f;
  #pragma unroll
  for (int j = 0; j < 8; j++) {
    o[j] = fmaxf(d[j] * rstd * gv[j] + bv[j], 0.0f);
    rmax = fmaxf(rmax, o[j]);
  }

  // per-row amax over the 128 lanes of this node-group -> i8 quant
  __syncthreads();                       // red[] reuse
  #pragma unroll
  for (int off = 32; off; off >>= 1) rmax = fmaxf(rmax, __shfl_xor(rmax, off, 64));
  if ((threadIdx.x & 63) == 0) red[wid] = rmax;
  __syncthreads();
  float rm = fmaxf(red[g * 2], red[g * 2 + 1]);
  float qinv = (rm > 0.f) ? 127.0f / rm : 0.f;
  int q[8];
  #pragma unroll
  for (int j = 0; j < 8; j++) q[j] = min(127, __float2int_rn(o[j] * qinv));
  uint32_t p0 = ((uint32_t)q[0]) | ((uint32_t)q[1] << 8) | ((uint32_t)q[2] << 16) | ((uint32_t)q[3] << 24);
  uint32_t p1 = ((uint32_t)q[4]) | ((uint32_t)q[5] << 8) | ((uint32_t)q[6] << 16) | ((uint32_t)q[7] << 24);
  uint2 pk; pk.x = p0; pk.y = p1;
  ((uint2*)(hq + (size_t)node * HD))[tt] = pk;
  if (tt == 0) hscale[node] = (rm > 0.f) ? rm / 127.0f : 0.f;
}

// ---------------- graph boundaries (batch is sorted) ----------------
__global__ void starts_kernel(const int* __restrict__ batch, int* __restrict__ start,
                              int n, int ngraph) {
  int g = blockIdx.x * blockDim.x + threadIdx.x;
  if (g > ngraph) return;
  int lo = 0, hi = n;
  while (lo < hi) {
    int mid = (lo + hi) >> 1;
    if (batch[mid] < g) lo = mid + 1; else hi = mid;
  }
  start[g] = lo;
}

// ---------------- mean-pool per graph (i8 input): partial sums + atomics ----------------
#define POOL_CHUNKS 8
__global__ void pool_partial_kernel(const int8_t* __restrict__ hq,
                                    const float* __restrict__ hscale,
                                    const int* __restrict__ start,
                                    float* __restrict__ out) {
  int g = blockIdx.y, c = blockIdx.x;
  int t = threadIdx.x;
  int s0 = start[g], s1 = start[g + 1];
  int len = s1 - s0;
  int per = (len + POOL_CHUNKS - 1) / POOL_CHUNKS;
  int a = s0 + c * per;
  int b = min(a + per, s1);
  if (a >= b) return;
  f32x4 acc = {0.f, 0.f, 0.f, 0.f};
  for (int n = a; n < b; n++) {
    float hs = hscale[n];
    uint32_t d = ((const uint32_t*)(hq + (size_t)n * HD))[t];   // 4 vals, 0..127
    acc[0] += hs * (float)(d & 0xffu);
    acc[1] += hs * (float)((d >> 8) & 0xffu);
    acc[2] += hs * (float)((d >> 16) & 0xffu);
    acc[3] += hs * (float)(d >> 24);
  }
  float* o = out + (size_t)g * HD + t * 4;
  atomicAdd(o + 0, acc[0]);
  atomicAdd(o + 1, acc[1]);
  atomicAdd(o + 2, acc[2]);
  atomicAdd(o + 3, acc[3]);
}

__global__ void pool_div_kernel(float* __restrict__ out, const int* __restrict__ start) {
  int i = blockIdx.x * 256 + threadIdx.x;
  if (i >= NG * HD) return;
  int g = i >> 10;
  float c = (float)max(start[g + 1] - start[g], 1);
  out[i] = out[i] / c;
}

extern "C" void kernel_launch(void* const* d_in, const int* in_sizes, int n_in,
                              void* d_out, int out_size, void* d_ws, size_t ws_size,
                              hipStream_t stream) {
  const float* x      = (const float*)d_in[0];
  const int*   eidx   = (const int*)d_in[1];
  const int*   batch  = (const int*)d_in[2];
  const float* W0     = (const float*)d_in[3];
  const float* b0     = (const float*)d_in[4];
  const float* Ws     = (const float*)d_in[5];
  const float* bs     = (const float*)d_in[6];
  const float* gammas = (const float*)d_in[7];
  const float* betas  = (const float*)d_in[8];
  float* out = (float*)d_out;

  const int* erow = eidx;        // sources
  const int* ecol = eidx + NE;   // targets (aggregation index)

  char* ws = (char*)d_ws;
  size_t off = 0;
  auto alloc = [&](size_t bytes) {
    void* p = ws + off;
    off = (off + bytes + 255) & ~(size_t)255;
    return p;
  };
  int*     cnt     = (int*)alloc((size_t)NN * 4);      // later: wscale[4K] + colmax[4K]
  int*     row_ptr = (int*)alloc((size_t)(NN + 1) * 4);
  int*     fill    = (int*)alloc((size_t)NN * 4);      // later: hscale (NN floats)
  int*     partial = (int*)alloc(256 * 4);
  float*   dinv    = (float*)alloc((size_t)NN * 4);
  int2*    csr_sw  = (int2*)alloc((size_t)NE * 8);
  int8_t*  Wt8     = (int8_t*)alloc((size_t)FIN * HD + 3 * (size_t)HD * HD);
  int8_t*  A8      = (int8_t*)alloc((size_t)NN * HD);  // i8 activations (L0 pitch 256)
  uint8_t* ht8     = (uint8_t*)alloc((size_t)NN * HD); // u8 GEMM output
  float*   scales  = (float*)alloc((size_t)NN * 8 * 4);
  int*     gstart  = (int*)alloc(65 * 4);

  float*    wscale = (float*)cnt;                 // cnt dead after scans
  uint32_t* colmax = (uint32_t*)cnt + 4096;
  float*    hscale = (float*)fill;                // fill dead after scatter

  hipMemsetAsync(cnt, 0, (size_t)NN * 4, stream);
  hipMemsetAsync(fill, 0, (size_t)NN * 4, stream);
  hipMemsetAsync(out, 0, (size_t)NG * HD * 4, stream);

  hist_kernel<<<(NE + 255) / 256, 256, 0, stream>>>(ecol, cnt, NE);
  dinv_kernel<<<(NN + 255) / 256, 256, 0, stream>>>(cnt, dinv, NN);
  int nb = (NN + 255) / 256;  // 196
  scan_partial_kernel<<<nb, 256, 0, stream>>>(cnt, partial, NN);
  scan_scan_kernel<<<1, 256, 0, stream>>>(partial, nb);
  scan_final_kernel<<<nb, 256, 0, stream>>>(cnt, partial, row_ptr, NN, NE);
  scatter_kernel<<<(NE + 255) / 256, 256, 0, stream>>>(erow, ecol, row_ptr, fill, dinv,
                                                       csr_sw, NE);
  starts_kernel<<<1, 128, 0, stream>>>(batch, gstart, NN, NG);

  // x -> i8 activations (hscale aliases fill: after scatter)
  quant_x_kernel<<<NN / 4, 256, 0, stream>>>(x, A8, hscale);

  // batched weight prep for all 4 layers (cnt region dead after scans)
  hipMemsetAsync(colmax, 0, 4 * HD * 4, stream);
  wamax_all_kernel<<<dim3(HD / 32, 8, 4), dim3(32, 8), 0, stream>>>(W0, Ws, colmax);
  wscale_all_kernel<<<(4 * HD) / 256, 256, 0, stream>>>(colmax, wscale);
  transpose_wq8_all_kernel<<<dim3(HD / 32, HD / 32, 4), dim3(32, 8), 0, stream>>>(
      W0, Ws, colmax, Wt8);

  const int nmt = (NN + 127) / 128;  // 391 m-tiles
  for (int L = 0; L < 4; L++) {
    int K = (L == 0) ? FIN : HD;
    const int8_t* WtL = Wt8 + ((L == 0) ? 0 : (size_t)FIN * HD + (size_t)(L - 1) * HD * HD);
    const float* bias = (L == 0) ? b0 : bs + (size_t)(L - 1) * HD;
    gemm_i8_q8_kernel<<<nmt * 8, 256, 0, stream>>>(A8, hscale, WtL, wscale + L * HD,
                                                   ht8, scales, NN, K);
    agg_ln_u8_kernel<<<NN / 2, 256, 0, stream>>>(ht8, scales, row_ptr, csr_sw,
                                                 dinv, bias, gammas + (size_t)L * HD,
                                                 betas + (size_t)L * HD, A8, hscale);
  }

  pool_partial_kernel<<<dim3(POOL_CHUNKS, NG), 256, 0, stream>>>(A8, hscale, gstart, out);
  pool_div_kernel<<<(NG * HD + 255) / 256, 256, 0, stream>>>(out, gstart);
}

// Round 11
// 1410.660 us; speedup vs baseline: 1.8873x; 1.0948x over previous
//
#include <hip/hip_runtime.h>
#include <hip/hip_bf16.h>
#include <stdint.h>

#define NN 50000
#define NE 1600000
#define NG 64
#define FIN 256
#define HD 1024
#define EPSV 1e-5f

typedef __bf16 bf16;
typedef float f32x4 __attribute__((ext_vector_type(4)));
typedef float f32x2 __attribute__((ext_vector_type(2)));
typedef int i32x4 __attribute__((ext_vector_type(4)));

typedef const __attribute__((address_space(1))) void* gptr_as1;
typedef __attribute__((address_space(3))) void* lptr_as3;

__device__ __forceinline__ void load_g2l_16(const void* g, const void* l) {
  __builtin_amdgcn_global_load_lds((gptr_as1)(uintptr_t)g,
                                   (lptr_as3)(uint32_t)(uintptr_t)l, 16, 0, 0);
}

// ---------------- degree histogram / dinv ----------------
__global__ void hist_kernel(const int* __restrict__ col, int* __restrict__ cnt, int E) {
  int e = blockIdx.x * 256 + threadIdx.x;
  if (e < E) atomicAdd(&cnt[col[e]], 1);
}

__global__ void dinv_kernel(const int* __restrict__ cnt, float* __restrict__ dinv, int n) {
  int i = blockIdx.x * 256 + threadIdx.x;
  if (i < n) dinv[i] = rsqrtf((float)(cnt[i] + 1));  // +1 self-loop
}

// ---------------- exclusive scan (3-phase) ----------------
__global__ void scan_partial_kernel(const int* __restrict__ cnt, int* __restrict__ partial, int n) {
  __shared__ int red[4];
  int i = blockIdx.x * 256 + threadIdx.x;
  int v = (i < n) ? cnt[i] : 0;
  #pragma unroll
  for (int off = 32; off; off >>= 1) v += __shfl_down(v, off, 64);
  if ((threadIdx.x & 63) == 0) red[threadIdx.x >> 6] = v;
  __syncthreads();
  if (threadIdx.x == 0) partial[blockIdx.x] = red[0] + red[1] + red[2] + red[3];
}

__global__ void scan_scan_kernel(int* __restrict__ partial, int nb) {
  __shared__ int s[256];
  int t = threadIdx.x;
  int v = (t < nb) ? partial[t] : 0;
  s[t] = v;
  __syncthreads();
  for (int off = 1; off < 256; off <<= 1) {
    int x = (t >= off) ? s[t - off] : 0;
    __syncthreads();
    s[t] += x;
    __syncthreads();
  }
  if (t < nb) partial[t] = s[t] - v;  // exclusive
}

__global__ void scan_final_kernel(const int* __restrict__ cnt, const int* __restrict__ partial,
                                  int* __restrict__ row_ptr, int n, int E) {
  __shared__ int s[256];
  int t = threadIdx.x;
  int i = blockIdx.x * 256 + t;
  int v = (i < n) ? cnt[i] : 0;
  s[t] = v;
  __syncthreads();
  for (int off = 1; off < 256; off <<= 1) {
    int x = (t >= off) ? s[t - off] : 0;
    __syncthreads();
    s[t] += x;
    __syncthreads();
  }
  if (i < n) row_ptr[i] = partial[blockIdx.x] + s[t] - v;
  if (i == 0) row_ptr[n] = E;
}

// ---------------- CSR scatter (packed {src, w_bits}) ----------------
__global__ void scatter_kernel(const int* __restrict__ rowi, const int* __restrict__ coli,
                               const int* __restrict__ row_ptr, int* __restrict__ fill,
                               const float* __restrict__ dinv,
                               int2* __restrict__ csr_sw, int E) {
  int e = blockIdx.x * 256 + threadIdx.x;
  if (e >= E) return;
  int s = rowi[e], d = coli[e];
  int pos = row_ptr[d] + atomicAdd(&fill[d], 1);
  int2 p;
  p.x = s;
  p.y = __float_as_int(dinv[s] * dinv[d]);
  csr_sw[pos] = p;
}

// ---------------- x f32 -> per-row biased u8 (for agg0 gather) ----------------
__global__ __launch_bounds__(256) void quant_x_kernel(const float* __restrict__ x,
                                                      uint8_t* __restrict__ X8,
                                                      float* __restrict__ xscale) {
  int row = blockIdx.x * 4 + (threadIdx.x >> 6);
  int t = threadIdx.x & 63;
  float4 v = ((const float4*)(x + (size_t)row * FIN))[t];
  float m = fmaxf(fmaxf(fabsf(v.x), fabsf(v.y)), fmaxf(fabsf(v.z), fabsf(v.w)));
  #pragma unroll
  for (int off = 32; off; off >>= 1) m = fmaxf(m, __shfl_xor(m, off, 64));
  float inv = (m > 0.f) ? 127.0f / m : 0.f;
  int q0 = min(127, max(-127, __float2int_rn(v.x * inv))) + 128;
  int q1 = min(127, max(-127, __float2int_rn(v.y * inv))) + 128;
  int q2 = min(127, max(-127, __float2int_rn(v.z * inv))) + 128;
  int q3 = min(127, max(-127, __float2int_rn(v.w * inv))) + 128;
  uint32_t p = ((uint32_t)q0) | ((uint32_t)q1 << 8) |
               ((uint32_t)q2 << 16) | ((uint32_t)q3 << 24);
  ((uint32_t*)X8)[(size_t)row * 64 + t] = p;
  if (t == 0) xscale[row] = (m > 0.f) ? m / 127.0f : 0.f;
}

// ---------------- L0 aggregate-first: AX = A-hat * x (256-d gather) ----------------
// 4 nodes per block, one 64-lane wave each; lane covers 4 cols (one u32 load).
// Output: per-row i8 + axscale (feeds GEMM0 directly).
__global__ __launch_bounds__(256) void agg0_kernel(
    const uint8_t* __restrict__ X8, const float* __restrict__ xscale,
    const int* __restrict__ row_ptr, const int2* __restrict__ csr_sw,
    const float* __restrict__ dinv,
    int8_t* __restrict__ AX8, float* __restrict__ axscale) {
  const int node = blockIdx.x * 4 + (threadIdx.x >> 6);
  const int t = threadIdx.x & 63;

  float acc[4] = {};
  float sw = 0.f;

  float dn = dinv[node];
  float wself = dn * dn * xscale[node];
  {
    uint32_t d = ((const uint32_t*)X8)[(size_t)node * 64 + t];
    sw += wself;
    acc[0] += wself * (float)(d & 0xffu);
    acc[1] += wself * (float)((d >> 8) & 0xffu);
    acc[2] += wself * (float)((d >> 16) & 0xffu);
    acc[3] += wself * (float)(d >> 24);
  }

  int e = row_ptr[node];
  const int e1 = row_ptr[node + 1];
  for (; e + 4 <= e1; e += 4) {
    int2 p0 = csr_sw[e], p1 = csr_sw[e + 1], p2 = csr_sw[e + 2], p3 = csr_sw[e + 3];
    float w0 = __int_as_float(p0.y) * xscale[p0.x];
    float w1 = __int_as_float(p1.y) * xscale[p1.x];
    float w2 = __int_as_float(p2.y) * xscale[p2.x];
    float w3 = __int_as_float(p3.y) * xscale[p3.x];
    uint32_t d0 = ((const uint32_t*)X8)[(size_t)p0.x * 64 + t];
    uint32_t d1 = ((const uint32_t*)X8)[(size_t)p1.x * 64 + t];
    uint32_t d2 = ((const uint32_t*)X8)[(size_t)p2.x * 64 + t];
    uint32_t d3 = ((const uint32_t*)X8)[(size_t)p3.x * 64 + t];
    sw += w0 + w1 + w2 + w3;
    acc[0] += w0 * (float)(d0 & 0xffu) + w1 * (float)(d1 & 0xffu)
            + w2 * (float)(d2 & 0xffu) + w3 * (float)(d3 & 0xffu);
    acc[1] += w0 * (float)((d0 >> 8) & 0xffu) + w1 * (float)((d1 >> 8) & 0xffu)
            + w2 * (float)((d2 >> 8) & 0xffu) + w3 * (float)((d3 >> 8) & 0xffu);
    acc[2] += w0 * (float)((d0 >> 16) & 0xffu) + w1 * (float)((d1 >> 16) & 0xffu)
            + w2 * (float)((d2 >> 16) & 0xffu) + w3 * (float)((d3 >> 16) & 0xffu);
    acc[3] += w0 * (float)(d0 >> 24) + w1 * (float)(d1 >> 24)
            + w2 * (float)(d2 >> 24) + w3 * (float)(d3 >> 24);
  }
  for (; e < e1; e++) {
    int2 p = csr_sw[e];
    float w = __int_as_float(p.y) * xscale[p.x];
    uint32_t d = ((const uint32_t*)X8)[(size_t)p.x * 64 + t];
    sw += w;
    acc[0] += w * (float)(d & 0xffu);
    acc[1] += w * (float)((d >> 8) & 0xffu);
    acc[2] += w * (float)((d >> 16) & 0xffu);
    acc[3] += w * (float)(d >> 24);
  }

  // remove the +128 bias
  float c = 128.0f * sw;
  #pragma unroll
  for (int j = 0; j < 4; j++) acc[j] -= c;

  // per-row amax over this wave -> signed i8 quant
  float rm = fmaxf(fmaxf(fabsf(acc[0]), fabsf(acc[1])), fmaxf(fabsf(acc[2]), fabsf(acc[3])));
  #pragma unroll
  for (int off = 32; off; off >>= 1) rm = fmaxf(rm, __shfl_xor(rm, off, 64));
  float qinv = (rm > 0.f) ? 127.0f / rm : 0.f;
  int q0 = min(127, max(-127, __float2int_rn(acc[0] * qinv)));
  int q1 = min(127, max(-127, __float2int_rn(acc[1] * qinv)));
  int q2 = min(127, max(-127, __float2int_rn(acc[2] * qinv)));
  int q3 = min(127, max(-127, __float2int_rn(acc[3] * qinv)));
  uint32_t p = ((uint32_t)(q0 & 0xff)) | ((uint32_t)(q1 & 0xff) << 8) |
               ((uint32_t)(q2 & 0xff) << 16) | ((uint32_t)(q3 & 0xff) << 24);
  ((uint32_t*)AX8)[(size_t)node * 64 + t] = p;
  if (t == 0) axscale[node] = (rm > 0.f) ? rm / 127.0f : 0.f;
}

// ---------------- L0 post-GEMM: dequant + bias + LayerNorm + ReLU + i8 quant ----------------
__global__ __launch_bounds__(256) void ln0_kernel(
    const uint8_t* __restrict__ htu8, const float* __restrict__ scales,
    const float* __restrict__ bias, const float* __restrict__ gamma,
    const float* __restrict__ beta,
    int8_t* __restrict__ hq, float* __restrict__ hscale) {
  const int g = threadIdx.x >> 7;
  const int node = blockIdx.x * 2 + g;
  const int tt = threadIdx.x & 127;
  const int cbL = tt >> 4;
  const int wid = threadIdx.x >> 6;
  __shared__ float red[4];

  float sc = scales[(size_t)node * 8 + cbL];
  uint2 dd = ((const uint2*)(htu8 + (size_t)node * HD))[tt];
  float acc[8];
  acc[0] = sc * ((float)(dd.x & 0xffu) - 128.f);
  acc[1] = sc * ((float)((dd.x >> 8) & 0xffu) - 128.f);
  acc[2] = sc * ((float)((dd.x >> 16) & 0xffu) - 128.f);
  acc[3] = sc * ((float)(dd.x >> 24) - 128.f);
  acc[4] = sc * ((float)(dd.y & 0xffu) - 128.f);
  acc[5] = sc * ((float)((dd.y >> 8) & 0xffu) - 128.f);
  acc[6] = sc * ((float)((dd.y >> 16) & 0xffu) - 128.f);
  acc[7] = sc * ((float)(dd.y >> 24) - 128.f);

  const float4* bias2 = (const float4*)bias;
  float4 ba = bias2[tt * 2], bb = bias2[tt * 2 + 1];
  acc[0] += ba.x; acc[1] += ba.y; acc[2] += ba.z; acc[3] += ba.w;
  acc[4] += bb.x; acc[5] += bb.y; acc[6] += bb.z; acc[7] += bb.w;

  float s = 0.f;
  #pragma unroll
  for (int j = 0; j < 8; j++) s += acc[j];
  #pragma unroll
  for (int off = 32; off; off >>= 1) s += __shfl_down(s, off, 64);
  if ((threadIdx.x & 63) == 0) red[wid] = s;
  __syncthreads();
  float mean = (red[g * 2] + red[g * 2 + 1]) * (1.0f / HD);
  __syncthreads();

  float d[8], s2 = 0.f;
  #pragma unroll
  for (int j = 0; j < 8; j++) { d[j] = acc[j] - mean; s2 += d[j] * d[j]; }
  #pragma unroll
  for (int off = 32; off; off >>= 1) s2 += __shfl_down(s2, off, 64);
  if ((threadIdx.x & 63) == 0) red[wid] = s2;
  __syncthreads();
  float var = (red[g * 2] + red[g * 2 + 1]) * (1.0f / HD);
  float rstd = rsqrtf(var + EPSV);

  const float4* gam2 = (const float4*)gamma;
  const float4* bet2 = (const float4*)beta;
  float4 g0 = gam2[tt * 2], g1 = gam2[tt * 2 + 1];
  float4 be0 = bet2[tt * 2], be1 = bet2[tt * 2 + 1];
  float gv[8] = {g0.x, g0.y, g0.z, g0.w, g1.x, g1.y, g1.z, g1.w};
  float bv[8] = {be0.x, be0.y, be0.z, be0.w, be1.x, be1.y, be1.z, be1.w};
  float o[8];
  float rmax = 0.f;
  #pragma unroll
  for (int j = 0; j < 8; j++) {
    o[j] = fmaxf(d[j] * rstd * gv[j] + bv[j], 0.0f);
    rmax = fmaxf(rmax, o[j]);
  }

  __syncthreads();
  #pragma unroll
  for (int off = 32; off; off >>= 1) rmax = fmaxf(rmax, __shfl_xor(rmax, off, 64));
  if ((threadIdx.x & 63) == 0) red[wid] = rmax;
  __syncthreads();
  float rm = fmaxf(red[g * 2], red[g * 2 + 1]);
  float qinv = (rm > 0.f) ? 127.0f / rm : 0.f;
  int q[8];
  #pragma unroll
  for (int j = 0; j < 8; j++) q[j] = min(127, __float2int_rn(o[j] * qinv));
  uint32_t p0 = ((uint32_t)q[0]) | ((uint32_t)q[1] << 8) | ((uint32_t)q[2] << 16) | ((uint32_t)q[3] << 24);
  uint32_t p1 = ((uint32_t)q[4]) | ((uint32_t)q[5] << 8) | ((uint32_t)q[6] << 16) | ((uint32_t)q[7] << 24);
  uint2 pk; pk.x = p0; pk.y = p1;
  ((uint2*)(hq + (size_t)node * HD))[tt] = pk;
  if (tt == 0) hscale[node] = (rm > 0.f) ? rm / 127.0f : 0.f;
}

// ---------------- batched weight prep (all 4 layers, hoisted) ----------------
__device__ __forceinline__ const float* layer_W(const float* W0, const float* Ws, int L) {
  return (L == 0) ? W0 : Ws + (size_t)(L - 1) * HD * HD;
}

__global__ void wamax_all_kernel(const float* __restrict__ W0, const float* __restrict__ Ws,
                                 uint32_t* __restrict__ colmax) {
  __shared__ float lds[8][32];
  int L = blockIdx.z;
  int K = (L == 0) ? FIN : HD;
  int k0 = blockIdx.y * 128;
  if (k0 >= K) return;
  const float* W = layer_W(W0, Ws, L);
  int n = blockIdx.x * 32 + threadIdx.x;
  int kend = min(k0 + 128, K);
  float m = 0.f;
  for (int k = k0 + threadIdx.y; k < kend; k += 8)
    m = fmaxf(m, fabsf(W[(size_t)k * HD + n]));
  lds[threadIdx.y][threadIdx.x] = m;
  __syncthreads();
  if (threadIdx.y == 0) {
    #pragma unroll
    for (int i = 1; i < 8; i++) m = fmaxf(m, lds[i][threadIdx.x]);
    atomicMax(&colmax[L * HD + n], __float_as_uint(m));   // all values >= 0
  }
}

__global__ void wscale_all_kernel(const uint32_t* __restrict__ colmax,
                                  float* __restrict__ wscale) {
  int i = blockIdx.x * 256 + threadIdx.x;
  if (i < 4 * HD) {
    float m = __uint_as_float(colmax[i]);
    wscale[i] = (m > 0.f) ? m / 127.0f : 0.f;
  }
}

// Wt8_all layout: L0 at off 0 (HD rows x 256), L1.. at FIN*HD + (L-1)*HD*HD (HD rows x 1024)
__global__ void transpose_wq8_all_kernel(const float* __restrict__ W0,
                                         const float* __restrict__ Ws,
                                         const uint32_t* __restrict__ colmax,
                                         int8_t* __restrict__ Wt8_all) {
  __shared__ float tile[32][33];
  int L = blockIdx.z;
  int K = (L == 0) ? FIN : HD;
  int k0 = blockIdx.y * 32;
  if (k0 >= K) return;
  const float* W = layer_W(W0, Ws, L);
  int8_t* Wt8 = Wt8_all + ((L == 0) ? 0 : (size_t)FIN * HD + (size_t)(L - 1) * HD * HD);
  int n0 = blockIdx.x * 32;
  int tx = threadIdx.x, ty = threadIdx.y;  // 32 x 8
  #pragma unroll
  for (int i = ty; i < 32; i += 8) tile[i][tx] = W[(size_t)(k0 + i) * HD + n0 + tx];
  __syncthreads();
  #pragma unroll
  for (int i = ty; i < 32; i += 8) {
    float cm = __uint_as_float(colmax[L * HD + n0 + i]);
    float inv = (cm > 0.f) ? 127.0f / cm : 0.f;
    int q = min(127, max(-127, __float2int_rn(tile[tx][i] * inv)));
    Wt8[(size_t)(n0 + i) * K + k0 + tx] = (int8_t)q;
  }
}

// ---------------- i8 MFMA GEMM + fused u8-quant epilogue ----------------
__global__ __launch_bounds__(256, 4) void gemm_i8_q8_kernel(
    const int8_t* __restrict__ A8, const float* __restrict__ hscale,
    const int8_t* __restrict__ Wt8, const float* __restrict__ wscale,
    uint8_t* __restrict__ C8, float* __restrict__ scales, int M, int K) {
  __shared__ __align__(16) int8_t As[2][128 * 64];
  __shared__ __align__(16) int8_t Bs[2][128 * 64];
  __shared__ float smax[2][128];
  const int tid = threadIdx.x;
  const int w = tid >> 6, l = tid & 63;

  const int nwg = gridDim.x;            // nmt*8, divisible by 8
  const int o = blockIdx.x;
  const int lid = (o & 7) * (nwg >> 3) + (o >> 3);
  const int m0 = (lid >> 3) * 128, n0 = (lid & 7) * 128;
  const int cb = lid & 7;               // col-block id
  const int wr = w >> 1, wc = w & 1;    // 2x2 wave grid, each wave 64x64

  i32x4 acc[4][4] = {};

  const int r0 = tid >> 2;              // 0..63
  const int c16 = (tid & 3) * 16;       // byte offset within BK=64 row
  int ar0 = m0 + r0;       if (ar0 >= M) ar0 = M - 1;
  int ar1 = m0 + r0 + 64;  if (ar1 >= M) ar1 = M - 1;
  const int8_t* a0 = A8 + (size_t)ar0 * K + c16;
  const int8_t* a1 = A8 + (size_t)ar1 * K + c16;
  const int8_t* b0 = Wt8 + (size_t)(n0 + r0) * K + c16;
  const int8_t* b1 = Wt8 + (size_t)(n0 + r0 + 64) * K + c16;

  const int mrow = l & 15;
  const int kch = (l >> 4) * 16;        // byte offset within row

  auto stage = [&](int b, int k) {
    int8_t* asw = &As[b][w * 1024];
    int8_t* bsw = &Bs[b][w * 1024];
    load_g2l_16(a0 + k, asw);
    load_g2l_16(a1 + k, asw + 4096);
    load_g2l_16(b0 + k, bsw);
    load_g2l_16(b1 + k, bsw + 4096);
  };

  const int nit = K >> 6;
  stage(0, 0);
  __syncthreads();

  int cur = 0;
  for (int t = 0; t < nit; ++t) {
    if (t + 1 < nit) stage(cur ^ 1, (t + 1) << 6);
    i32x4 af[4], bf_[4];
    #pragma unroll
    for (int m = 0; m < 4; m++)
      af[m] = *(const i32x4*)&As[cur][(wr * 64 + m * 16 + mrow) * 64 + kch];
    #pragma unroll
    for (int n = 0; n < 4; n++)
      bf_[n] = *(const i32x4*)&Bs[cur][(wc * 64 + n * 16 + mrow) * 64 + kch];
    #pragma unroll
    for (int m = 0; m < 4; m++)
      #pragma unroll
      for (int n = 0; n < 4; n++)
        acc[m][n] = __builtin_amdgcn_mfma_i32_16x16x64_i8(af[m], bf_[n], acc[m][n], 0, 0, 0);
    __syncthreads();
    cur ^= 1;
  }

  // ---- epilogue: per-row amax over this block's 128 cols (pass 1), quant (pass 2) ----
  float wsv[4];
  #pragma unroll
  for (int n = 0; n < 4; n++) wsv[n] = wscale[n0 + wc * 64 + n * 16 + (l & 15)];

  #pragma unroll
  for (int m = 0; m < 4; m++) {
    #pragma unroll
    for (int r = 0; r < 4; r++) {
      int rl = wr * 64 + m * 16 + (l >> 4) * 4 + r;
      int grow = m0 + rl; if (grow >= M) grow = M - 1;
      float v = 0.f;
      #pragma unroll
      for (int n = 0; n < 4; n++)
        v = fmaxf(v, fabsf((float)acc[m][n][r] * wsv[n]));
      v *= hscale[grow];   // hs >= 0: factor out of the max
      #pragma unroll
      for (int mask = 1; mask < 16; mask <<= 1) v = fmaxf(v, __shfl_xor(v, mask, 64));
      if ((l & 15) == 0) smax[wc][rl] = v;
    }
  }
  __syncthreads();

  #pragma unroll
  for (int m = 0; m < 4; m++) {
    #pragma unroll
    for (int r = 0; r < 4; r++) {
      int rl = wr * 64 + m * 16 + (l >> 4) * 4 + r;
      int grow = m0 + rl;
      float mx = fmaxf(smax[0][rl], smax[1][rl]);
      float inv = (mx > 0.f) ? 127.0f / mx : 0.f;
      if (grow < M) {
        float hs = hscale[grow];
        if (wc == 0 && (l & 15) == 0)
          scales[(size_t)grow * 8 + cb] = (mx > 0.f) ? mx / 127.0f : 0.f;
        #pragma unroll
        for (int n = 0; n < 4; n++) {
          int gcol = n0 + wc * 64 + n * 16 + (l & 15);
          int u = __float2int_rn((float)acc[m][n][r] * hs * wsv[n] * inv) + 128;
          C8[(size_t)grow * HD + gcol] = (uint8_t)u;
        }
      }
    }
  }
}

// ---------------- fused aggregate + bias + LayerNorm + ReLU (u8 gather, i8 out) ----------------
__device__ __forceinline__ void acc_u8p(f32x2 a[4], float& sw, float w, uint2 d) {
  sw += w;
  f32x2 w2 = {w, w};
  f32x2 v0 = {(float)(d.x & 0xffu), (float)((d.x >> 8) & 0xffu)};
  f32x2 v1 = {(float)((d.x >> 16) & 0xffu), (float)(d.x >> 24)};
  f32x2 v2 = {(float)(d.y & 0xffu), (float)((d.y >> 8) & 0xffu)};
  f32x2 v3 = {(float)((d.y >> 16) & 0xffu), (float)(d.y >> 24)};
  a[0] += w2 * v0;
  a[1] += w2 * v1;
  a[2] += w2 * v2;
  a[3] += w2 * v3;
}

__global__ __launch_bounds__(256) void agg_ln_u8_kernel(
    const uint8_t* __restrict__ htu8, const float* __restrict__ scales,
    const int* __restrict__ row_ptr, const int2* __restrict__ csr_sw,
    const float* __restrict__ dinv, const float* __restrict__ bias,
    const float* __restrict__ gamma, const float* __restrict__ beta,
    int8_t* __restrict__ hq, float* __restrict__ hscale) {
  const int g = threadIdx.x >> 7;
  const int node = blockIdx.x * 2 + g;
  const int tt = threadIdx.x & 127;
  const int cbL = tt >> 4;            // this lane's col-block
  const int wid = threadIdx.x >> 6;
  __shared__ float red[4];

  f32x2 acc2[4] = {};
  float sw = 0.f;

  // self-loop
  float dn = dinv[node];
  float wself = dn * dn * scales[(size_t)node * 8 + cbL];
  acc_u8p(acc2, sw, wself, ((const uint2*)(htu8 + (size_t)node * HD))[tt]);

  int e = row_ptr[node];
  const int e1 = row_ptr[node + 1];
  for (; e + 4 <= e1; e += 4) {
    int2 p0 = csr_sw[e], p1 = csr_sw[e + 1], p2 = csr_sw[e + 2], p3 = csr_sw[e + 3];
    float w0 = __int_as_float(p0.y) * scales[(size_t)p0.x * 8 + cbL];
    float w1 = __int_as_float(p1.y) * scales[(size_t)p1.x * 8 + cbL];
    float w2 = __int_as_float(p2.y) * scales[(size_t)p2.x * 8 + cbL];
    float w3 = __int_as_float(p3.y) * scales[(size_t)p3.x * 8 + cbL];
    uint2 d0 = ((const uint2*)(htu8 + (size_t)p0.x * HD))[tt];
    uint2 d1 = ((const uint2*)(htu8 + (size_t)p1.x * HD))[tt];
    uint2 d2 = ((const uint2*)(htu8 + (size_t)p2.x * HD))[tt];
    uint2 d3 = ((const uint2*)(htu8 + (size_t)p3.x * HD))[tt];
    acc_u8p(acc2, sw, w0, d0);
    acc_u8p(acc2, sw, w1, d1);
    acc_u8p(acc2, sw, w2, d2);
    acc_u8p(acc2, sw, w3, d3);
  }
  for (; e < e1; e++) {
    int2 p = csr_sw[e];
    float wgt = __int_as_float(p.y) * scales[(size_t)p.x * 8 + cbL];
    acc_u8p(acc2, sw, wgt, ((const uint2*)(htu8 + (size_t)p.x * HD))[tt]);
  }

  float acc[8] = {acc2[0][0], acc2[0][1], acc2[1][0], acc2[1][1],
                  acc2[2][0], acc2[2][1], acc2[3][0], acc2[3][1]};

  // bias-correction for the +128 offset, then layer bias
  const float4* bias2 = (const float4*)bias;
  float4 ba = bias2[tt * 2], bb = bias2[tt * 2 + 1];
  float c128 = 128.0f * sw;
  acc[0] += ba.x - c128; acc[1] += ba.y - c128; acc[2] += ba.z - c128; acc[3] += ba.w - c128;
  acc[4] += bb.x - c128; acc[5] += bb.y - c128; acc[6] += bb.z - c128; acc[7] += bb.w - c128;

  float s = 0.f;
  #pragma unroll
  for (int j = 0; j < 8; j++) s += acc[j];
  #pragma unroll
  for (int off = 32; off; off >>= 1) s += __shfl_down(s, off, 64);
  if ((threadIdx.x & 63) == 0) red[wid] = s;
  __syncthreads();
  float mean = (red[g * 2] + red[g * 2 + 1]) * (1.0f / HD);
  __syncthreads();

  float d[8], s2 = 0.f;
  #pragma unroll
  for (int j = 0; j < 8; j++) { d[j] = acc[j] - mean; s2 += d[j] * d[j]; }
  #pragma unroll
  for (int off = 32; off; off >>= 1) s2 += __shfl_down(s2, off, 64);
  if ((threadIdx.x & 63) == 0) red[wid] = s2;
  __syncthreads();
  float var = (red[g * 2] + red[g * 2 + 1]) * (1.0f / HD);
  float rstd = rsqrtf(var + EPSV);

  const float4* gam2 = (const float4*)gamma;
  const float4* bet2 = (const float4*)beta;
  float4 g0 = gam2[tt * 2], g1 = gam2[tt * 2 + 1];
  float4 be0 = bet2[tt * 2], be1 = bet2[tt * 2 + 1];
  float gv[8] = {g0.x, g0.y, g0.z, g0.w, g1.x, g1.y, g1.z, g1.w};
  float bv[8] = {be0.x, be0.y, be0.z, be0.w, be1.x, be1.y, be1.z, be1.w};
  float o[8];
  float rmax = 0.f;
  #pragma unroll
  for (int j = 0; j < 8; j++) {
    o[j] = fmaxf(d[j] * rstd * gv[j] + bv[j], 0.0f);
    rmax = fmaxf(rmax, o[j]);
  }

  // per-row amax over the 128 lanes of this node-group -> i8 quant
  __syncthreads();                       // red[] reuse
  #pragma unroll
  for (int off = 32; off; off >>= 1) rmax = fmaxf(rmax, __shfl_xor(rmax, off, 64));
  if ((threadIdx.x & 63) == 0) red[wid] = rmax;
  __syncthreads();
  float rm = fmaxf(red[g * 2], red[g * 2 + 1]);
  float qinv = (rm > 0.f) ? 127.0f / rm : 0.f;
  int q[8];
  #pragma unroll
  for (int j = 0; j < 8; j++) q[j] = min(127, __float2int_rn(o[j] * qinv));
  uint32_t p0 = ((uint32_t)q[0]) | ((uint32_t)q[1] << 8) | ((uint32_t)q[2] << 16) | ((uint32_t)q[3] << 24);
  uint32_t p1 = ((uint32_t)q[4]) | ((uint32_t)q[5] << 8) | ((uint32_t)q[6] << 16) | ((uint32_t)q[7] << 24);
  uint2 pk; pk.x = p0; pk.y = p1;
  ((uint2*)(hq + (size_t)node * HD))[tt] = pk;
  if (tt == 0) hscale[node] = (rm > 0.f) ? rm / 127.0f : 0.f;
}

// ---------------- graph boundaries (batch is sorted) ----------------
__global__ void starts_kernel(const int* __restrict__ batch, int* __restrict__ start,
                              int n, int ngraph) {
  int g = blockIdx.x * blockDim.x + threadIdx.x;
  if (g > ngraph) return;
  int lo = 0, hi = n;
  while (lo < hi) {
    int mid = (lo + hi) >> 1;
    if (batch[mid] < g) lo = mid + 1; else hi = mid;
  }
  start[g] = lo;
}

// ---------------- mean-pool per graph (i8 input): partial sums + atomics ----------------
#define POOL_CHUNKS 8
__global__ void pool_partial_kernel(const int8_t* __restrict__ hq,
                                    const float* __restrict__ hscale,
                                    const int* __restrict__ start,
                                    float* __restrict__ out) {
  int g = blockIdx.y, c = blockIdx.x;
  int t = threadIdx.x;
  int s0 = start[g], s1 = start[g + 1];
  int len = s1 - s0;
  int per = (len + POOL_CHUNKS - 1) / POOL_CHUNKS;
  int a = s0 + c * per;
  int b = min(a + per, s1);
  if (a >= b) return;
  f32x4 acc = {0.f, 0.f, 0.f, 0.f};
  for (int n = a; n < b; n++) {
    float hs = hscale[n];
    uint32_t d = ((const uint32_t*)(hq + (size_t)n * HD))[t];   // 4 vals, 0..127
    acc[0] += hs * (float)(d & 0xffu);
    acc[1] += hs * (float)((d >> 8) & 0xffu);
    acc[2] += hs * (float)((d >> 16) & 0xffu);
    acc[3] += hs * (float)(d >> 24);
  }
  float* o = out + (size_t)g * HD + t * 4;
  atomicAdd(o + 0, acc[0]);
  atomicAdd(o + 1, acc[1]);
  atomicAdd(o + 2, acc[2]);
  atomicAdd(o + 3, acc[3]);
}

__global__ void pool_div_kernel(float* __restrict__ out, const int* __restrict__ start) {
  int i = blockIdx.x * 256 + threadIdx.x;
  if (i >= NG * HD) return;
  int g = i >> 10;
  float c = (float)max(start[g + 1] - start[g], 1);
  out[i] = out[i] / c;
}

extern "C" void kernel_launch(void* const* d_in, const int* in_sizes, int n_in,
                              void* d_out, int out_size, void* d_ws, size_t ws_size,
                              hipStream_t stream) {
  const float* x      = (const float*)d_in[0];
  const int*   eidx   = (const int*)d_in[1];
  const int*   batch  = (const int*)d_in[2];
  const float* W0     = (const float*)d_in[3];
  const float* b0     = (const float*)d_in[4];
  const float* Ws     = (const float*)d_in[5];
  const float* bs     = (const float*)d_in[6];
  const float* gammas = (const float*)d_in[7];
  const float* betas  = (const float*)d_in[8];
  float* out = (float*)d_out;

  const int* erow = eidx;        // sources
  const int* ecol = eidx + NE;   // targets (aggregation index)

  char* ws = (char*)d_ws;
  size_t off = 0;
  auto alloc = [&](size_t bytes) {
    void* p = ws + off;
    off = (off + bytes + 255) & ~(size_t)255;
    return p;
  };
  int*     cnt     = (int*)alloc((size_t)NN * 4);      // later: wscale[4K] + colmax[4K]
  int*     row_ptr = (int*)alloc((size_t)(NN + 1) * 4);
  int*     fill    = (int*)alloc((size_t)NN * 4);      // later: hscale (NN floats)
  int*     partial = (int*)alloc(256 * 4);
  float*   dinv    = (float*)alloc((size_t)NN * 4);
  int2*    csr_sw  = (int2*)alloc((size_t)NE * 8);
  int8_t*  Wt8     = (int8_t*)alloc((size_t)FIN * HD + 3 * (size_t)HD * HD);
  int8_t*  A8      = (int8_t*)alloc((size_t)NN * HD);  // i8 activations (pitch 1024)
  uint8_t* ht8     = (uint8_t*)alloc((size_t)NN * HD); // u8 GEMM output
  float*   scales  = (float*)alloc((size_t)NN * 8 * 4);
  uint8_t* X8      = (uint8_t*)alloc((size_t)NN * FIN); // biased-u8 x (L0 gather)
  int8_t*  AX8     = (int8_t*)alloc((size_t)NN * FIN);  // i8 aggregated x (GEMM0 input)
  float*   xscale  = (float*)alloc((size_t)NN * 4);
  float*   axscale = (float*)alloc((size_t)NN * 4);
  int*     gstart  = (int*)alloc(65 * 4);

  float*    wscale = (float*)cnt;                 // cnt dead after scans
  uint32_t* colmax = (uint32_t*)cnt + 4096;
  float*    hscale = (float*)fill;                // fill dead after scatter

  hipMemsetAsync(cnt, 0, (size_t)NN * 4, stream);
  hipMemsetAsync(fill, 0, (size_t)NN * 4, stream);
  hipMemsetAsync(out, 0, (size_t)NG * HD * 4, stream);

  hist_kernel<<<(NE + 255) / 256, 256, 0, stream>>>(ecol, cnt, NE);
  dinv_kernel<<<(NN + 255) / 256, 256, 0, stream>>>(cnt, dinv, NN);
  int nb = (NN + 255) / 256;  // 196
  scan_partial_kernel<<<nb, 256, 0, stream>>>(cnt, partial, NN);
  scan_scan_kernel<<<1, 256, 0, stream>>>(partial, nb);
  scan_final_kernel<<<nb, 256, 0, stream>>>(cnt, partial, row_ptr, NN, NE);
  scatter_kernel<<<(NE + 255) / 256, 256, 0, stream>>>(erow, ecol, row_ptr, fill, dinv,
                                                       csr_sw, NE);
  starts_kernel<<<1, 128, 0, stream>>>(batch, gstart, NN, NG);

  // x -> biased u8 (for agg0's gather)
  quant_x_kernel<<<NN / 4, 256, 0, stream>>>(x, X8, xscale);

  // batched weight prep for all 4 layers (cnt region dead after scans)
  hipMemsetAsync(colmax, 0, 4 * HD * 4, stream);
  wamax_all_kernel<<<dim3(HD / 32, 8, 4), dim3(32, 8), 0, stream>>>(W0, Ws, colmax);
  wscale_all_kernel<<<(4 * HD) / 256, 256, 0, stream>>>(colmax, wscale);
  transpose_wq8_all_kernel<<<dim3(HD / 32, HD / 32, 4), dim3(32, 8), 0, stream>>>(
      W0, Ws, colmax, Wt8);

  const int nmt = (NN + 127) / 128;  // 391 m-tiles

  // ---- L0: aggregate-first (A-hat x is a 256-d gather: 4x fewer bytes) ----
  agg0_kernel<<<NN / 4, 256, 0, stream>>>(X8, xscale, row_ptr, csr_sw, dinv, AX8, axscale);
  gemm_i8_q8_kernel<<<nmt * 8, 256, 0, stream>>>(AX8, axscale, Wt8, wscale,
                                                 ht8, scales, NN, FIN);
  ln0_kernel<<<NN / 2, 256, 0, stream>>>(ht8, scales, b0, gammas, betas, A8, hscale);

  // ---- L1-3: GEMM then fused aggregate+LN ----
  for (int L = 1; L < 4; L++) {
    const int8_t* WtL = Wt8 + (size_t)FIN * HD + (size_t)(L - 1) * HD * HD;
    const float* bias = bs + (size_t)(L - 1) * HD;
    gemm_i8_q8_kernel<<<nmt * 8, 256, 0, stream>>>(A8, hscale, WtL, wscale + L * HD,
                                                   ht8, scales, NN, HD);
    agg_ln_u8_kernel<<<NN / 2, 256, 0, stream>>>(ht8, scales, row_ptr, csr_sw,
                                                 dinv, bias, gammas + (size_t)L * HD,
                                                 betas + (size_t)L * HD, A8, hscale);
  }

  pool_partial_kernel<<<dim3(POOL_CHUNKS, NG), 256, 0, stream>>>(A8, hscale, gstart, out);
  pool_div_kernel<<<(NG * HD + 255) / 256, 256, 0, stream>>>(out, gstart);
}